// Round 2
// baseline (222.827 us; speedup 1.0000x reference)
//
#include <hip/hip_runtime.h>
#include <cstdint>
#include <cstddef>

#define HIDS 1024
#define NHEAD 16
#define HDIM 64
#define LSEQ 2048
#define BBATCH 2
#define NROW (BBATCH * LSEQ)  // 4096
#define CHUNK 64
#define NCHUNK (LSEQ / CHUNK)  // 32
#define RANK 16

typedef short short8 __attribute__((ext_vector_type(8)));
typedef float floatx4 __attribute__((ext_vector_type(4)));

__device__ __forceinline__ ushort f2bf(float f) {
  uint32_t u = __float_as_uint(f);
  uint32_t r = (u + 0x7fffu + ((u >> 16) & 1u)) >> 16;  // RNE
  return (ushort)r;
}
__device__ __forceinline__ float bf2f(ushort u) {
  return __uint_as_float(((uint32_t)u) << 16);
}
// log_sigmoid(z)/16 via native exp/log (arg of log in (1,2] -> accurate)
__device__ __forceinline__ float logsig16(float z) {
  return (fminf(z, 0.f) - __logf(1.f + __expf(-fabsf(z)))) * (1.f / 16.f);
}

__device__ __forceinline__ void async_copy16(const void* g, void* l) {
  __builtin_amdgcn_global_load_lds(
      (const __attribute__((address_space(1))) void*)g,
      (__attribute__((address_space(3))) void*)l, 16, 0, 0);
}

// ---------------------------------------------------------------------------
// prep: fused cvt_x (blocks 0..4095) + transpose_w (4096..5375).
// ---------------------------------------------------------------------------
__global__ __launch_bounds__(256) void prep_kernel(
    const float* __restrict__ x, ushort* __restrict__ xbf,
    const float* __restrict__ W0, const float* __restrict__ W1,
    const float* __restrict__ W2, const float* __restrict__ W3,
    const float* __restrict__ W4, ushort* __restrict__ T0,
    ushort* __restrict__ T1, ushort* __restrict__ T2, ushort* __restrict__ T3,
    ushort* __restrict__ T4) {
  __shared__ float sbuf[64 * 65];
  const int bid = blockIdx.x;
  const int tid = threadIdx.x;

  if (bid < 4096) {  // ---- cvt_x
    const int i = bid * 256 + tid;
    float4 f = *(const float4*)(x + (size_t)i * 4);
    ushort4 o;
    o.x = f2bf(f.x); o.y = f2bf(f.y); o.z = f2bf(f.z); o.w = f2bf(f.w);
    *(ushort4*)(xbf + (size_t)i * 4) = o;
  } else {  // ---- transpose_w
    const int w = bid - 4096;
    const int z = w >> 8, rem = w & 255;
    const float* W = (z == 0) ? W0 : (z == 1) ? W1 : (z == 2) ? W2
                     : (z == 3) ? W3 : W4;
    ushort* T = (z == 0) ? T0 : (z == 1) ? T1 : (z == 2) ? T2
                : (z == 3) ? T3 : T4;
    const int k0 = (rem >> 4) * 64, n0 = (rem & 15) * 64;
    const int r = tid >> 2, c4 = (tid & 3) * 16;
#pragma unroll
    for (int i = 0; i < 4; ++i) {
      float4 f = *(const float4*)(W + (size_t)(k0 + r) * HIDS + n0 + c4 + i * 4);
      sbuf[r * 65 + c4 + i * 4 + 0] = f.x;
      sbuf[r * 65 + c4 + i * 4 + 1] = f.y;
      sbuf[r * 65 + c4 + i * 4 + 2] = f.z;
      sbuf[r * 65 + c4 + i * 4 + 3] = f.w;
    }
    __syncthreads();
    const int n = tid >> 2, kc = (tid & 3) * 16;
#pragma unroll
    for (int i = 0; i < 4; ++i) {
      int kk = kc + i * 4;
      ushort4 o;
      o.x = f2bf(sbuf[(kk + 0) * 65 + n]);
      o.y = f2bf(sbuf[(kk + 1) * 65 + n]);
      o.z = f2bf(sbuf[(kk + 2) * 65 + n]);
      o.w = f2bf(sbuf[(kk + 3) * 65 + n]);
      *(ushort4*)(T + (size_t)(n0 + n) * HIDS + k0 + kk) = o;
    }
  }
}

// ---------------------------------------------------------------------------
// xr = xbf @ Wgk1 : [4096,1024] x [1024,16] -> f32 [4096,16]. 16 rows/block.
// W1 kept f32 in LDS (precision); x tile padded (stride 1040 ushorts) for
// conflict-free b128 reads across the 4 row-groups of a wave.
// ---------------------------------------------------------------------------
#define XSTR 1040
__global__ __launch_bounds__(256) void xr_kernel(
    const ushort* __restrict__ xbf, const float* __restrict__ Wgk1,
    float* __restrict__ xr) {
  __shared__ float sW1[HIDS * RANK];       // 64 KB, layout [k][16]
  __shared__ ushort sX[16 * XSTR];         // 16 rows, padded
  const int tid = threadIdx.x;
  const int r0 = blockIdx.x * 16;
#pragma unroll
  for (int j = 0; j < 16; ++j) {
    const int idx = j * 1024 + tid * 4;
    *(float4*)&sW1[idx] = *(const float4*)(Wgk1 + idx);
  }
#pragma unroll
  for (int j = 0; j < 8; ++j) {
    const int e = j * 2048 + tid * 8;
    const int rr = e >> 10, kk = e & 1023;
    *(short8*)&sX[rr * XSTR + kk] =
        *(const short8*)(xbf + (size_t)(r0 + rr) * HIDS + kk);
  }
  __syncthreads();
  const int r = tid >> 4, n = tid & 15;
  float acc = 0.f;
  for (int k8 = 0; k8 < HIDS; k8 += 8) {
    short8 xv = *(const short8*)&sX[r * XSTR + k8];
#pragma unroll
    for (int i = 0; i < 8; ++i)
      acc = fmaf(bf2f((ushort)xv[i]), sW1[(k8 + i) * RANK + n], acc);
  }
  xr[(size_t)(r0 + r) * RANK + n] = acc;
}

// ---------------------------------------------------------------------------
// proj4: 128x128 bf16 MFMA GEMM over {Wq,Wk,Wv,Wg}, BK=64, XOR-swizzled LDS
// staging, z fastest-varying for L2-hot A reads, uniform bf16 epilogue.
// ---------------------------------------------------------------------------
__global__ __launch_bounds__(256) void proj4_kernel(
    const ushort* __restrict__ xbf, const ushort* __restrict__ Wtq,
    const ushort* __restrict__ Wtk, const ushort* __restrict__ Wtv,
    const ushort* __restrict__ Wtg, ushort* __restrict__ qb,
    ushort* __restrict__ kb, ushort* __restrict__ vb, ushort* __restrict__ gb) {
  const int bxz = blockIdx.x;
  const int z = bxz & 3;       // fastest-varying
  const int bx = bxz >> 2;
  const ushort* Bt = (z == 0) ? Wtq : (z == 1) ? Wtk : (z == 2) ? Wtv : Wtg;
  ushort* C = (z == 0) ? qb : (z == 1) ? kb : (z == 2) ? vb : gb;
  __shared__ ushort As[2][128 * 32];
  __shared__ ushort Bs[2][128 * 32];
  const int tid = threadIdx.x;
  const int wave = tid >> 6, lane = tid & 63;
  const int wm = (wave >> 1) * 64, wn = (wave & 1) * 64;
  const int bm = blockIdx.y * 128, bn = bx * 128;
  const int lrow = tid >> 2;
  const int lk8 = ((((tid & 3) - ((tid >> 3) & 3)) & 3)) * 8;
  const ushort* Ag = xbf + (size_t)(bm + lrow) * HIDS + lk8;
  const ushort* Bg = Bt + (size_t)(bn + lrow) * HIDS + lk8;
  char* A0 = (char*)&As[0][0] + tid * 16;
  char* A1 = (char*)&As[1][0] + tid * 16;
  char* B0 = (char*)&Bs[0][0] + tid * 16;
  char* B1 = (char*)&Bs[1][0] + tid * 16;

  floatx4 acc[4][4];
#pragma unroll
  for (int i = 0; i < 4; ++i)
#pragma unroll
    for (int j = 0; j < 4; ++j) acc[i][j] = (floatx4){0.f, 0.f, 0.f, 0.f};

  const int fm = lane & 15, quad = lane >> 4;
  const int sq8 = ((quad + (fm >> 1)) & 3) * 8;  // swizzled read slot

  for (int k0 = 0; k0 < HIDS; k0 += 64) {
    __syncthreads();
    async_copy16(Ag + k0, A0);
    async_copy16(Ag + (size_t)64 * HIDS + k0, A0 + 4096);
    async_copy16(Ag + k0 + 32, A1);
    async_copy16(Ag + (size_t)64 * HIDS + k0 + 32, A1 + 4096);
    async_copy16(Bg + k0, B0);
    async_copy16(Bg + (size_t)64 * HIDS + k0, B0 + 4096);
    async_copy16(Bg + k0 + 32, B1);
    async_copy16(Bg + (size_t)64 * HIDS + k0 + 32, B1 + 4096);
    __syncthreads();

#pragma unroll
    for (int ks = 0; ks < 2; ++ks) {
      short8 af[4], bfr[4];
#pragma unroll
      for (int i = 0; i < 4; ++i)
        af[i] = *(const short8*)&As[ks][(wm + i * 16 + fm) * 32 + sq8];
#pragma unroll
      for (int j = 0; j < 4; ++j)
        bfr[j] = *(const short8*)&Bs[ks][(wn + j * 16 + fm) * 32 + sq8];
#pragma unroll
      for (int i = 0; i < 4; ++i)
#pragma unroll
        for (int j = 0; j < 4; ++j)
          acc[i][j] = __builtin_amdgcn_mfma_f32_16x16x32_bf16(af[i], bfr[j],
                                                              acc[i][j], 0, 0, 0);
    }
  }

#pragma unroll
  for (int i = 0; i < 4; ++i) {
    const int row0 = bm + wm + i * 16 + quad * 4;
#pragma unroll
    for (int j = 0; j < 4; ++j) {
      const int col = bn + wn + j * 16 + fm;
#pragma unroll
      for (int r = 0; r < 4; ++r)
        C[(size_t)(row0 + r) * HIDS + col] = f2bf(acc[i][j][r]);
    }
  }
}

// ---------------------------------------------------------------------------
// Output GEMM: 128x128 tile (same structure as proj4), fp32 out.
// ---------------------------------------------------------------------------
__global__ __launch_bounds__(256) void gemm_out_kernel(
    const ushort* __restrict__ A, const ushort* __restrict__ Bt,
    float* __restrict__ C) {
  __shared__ ushort As[2][128 * 32];
  __shared__ ushort Bs[2][128 * 32];
  const int tid = threadIdx.x;
  const int wave = tid >> 6, lane = tid & 63;
  const int wm = (wave >> 1) * 64, wn = (wave & 1) * 64;
  const int fm = lane & 15, quad = lane >> 4;
  const int sq8 = ((quad + (fm >> 1)) & 3) * 8;
  const int bm = blockIdx.y * 128, bn = blockIdx.x * 128;
  const int lrow = tid >> 2;
  const int lk8 = ((((tid & 3) - ((tid >> 3) & 3)) & 3)) * 8;
  const ushort* Ag = A + (size_t)(bm + lrow) * HIDS + lk8;
  const ushort* Bg = Bt + (size_t)(bn + lrow) * HIDS + lk8;
  char* A0 = (char*)&As[0][0] + tid * 16;
  char* A1 = (char*)&As[1][0] + tid * 16;
  char* B0 = (char*)&Bs[0][0] + tid * 16;
  char* B1 = (char*)&Bs[1][0] + tid * 16;

  floatx4 acc[4][4];
#pragma unroll
  for (int i = 0; i < 4; ++i)
#pragma unroll
    for (int j = 0; j < 4; ++j) acc[i][j] = (floatx4){0.f, 0.f, 0.f, 0.f};

  for (int k0 = 0; k0 < HIDS; k0 += 64) {
    __syncthreads();
    async_copy16(Ag + k0, A0);
    async_copy16(Ag + (size_t)64 * HIDS + k0, A0 + 4096);
    async_copy16(Ag + k0 + 32, A1);
    async_copy16(Ag + (size_t)64 * HIDS + k0 + 32, A1 + 4096);
    async_copy16(Bg + k0, B0);
    async_copy16(Bg + (size_t)64 * HIDS + k0, B0 + 4096);
    async_copy16(Bg + k0 + 32, B1);
    async_copy16(Bg + (size_t)64 * HIDS + k0 + 32, B1 + 4096);
    __syncthreads();

#pragma unroll
    for (int ks = 0; ks < 2; ++ks) {
      short8 af[4], bfr[4];
#pragma unroll
      for (int i = 0; i < 4; ++i)
        af[i] = *(const short8*)&As[ks][(wm + i * 16 + fm) * 32 + sq8];
#pragma unroll
      for (int j = 0; j < 4; ++j)
        bfr[j] = *(const short8*)&Bs[ks][(wn + j * 16 + fm) * 32 + sq8];
#pragma unroll
      for (int i = 0; i < 4; ++i)
#pragma unroll
        for (int j = 0; j < 4; ++j)
          acc[i][j] = __builtin_amdgcn_mfma_f32_16x16x32_bf16(af[i], bfr[j],
                                                              acc[i][j], 0, 0, 0);
    }
  }

#pragma unroll
  for (int i = 0; i < 4; ++i) {
    const int row0 = bm + wm + i * 16 + quad * 4;
#pragma unroll
    for (int j = 0; j < 4; ++j) {
      const int col = bn + wn + j * 16 + fm;
#pragma unroll
      for (int r = 0; r < 4; ++r)
        C[(size_t)(row0 + r) * HIDS + col] = acc[i][j][r];
    }
  }
}

#define SP 72   // ushort stride for bf16 LDS tiles (16B-aligned rows)
#define SGS 68  // float stride for Gamma tile

// ---------------------------------------------------------------------------
// sdelta: z = xr @ Wgk2 + b computed inline (rank-16); Gamma=cumsum(logsig16);
// Vt~=(e^-G V)^T; Sdelta = Lam.(V~^T K); exports Vtg (V~^T) and Eb = e^Gamma.
// ---------------------------------------------------------------------------
__global__ __launch_bounds__(256) void sdelta_kernel(
    const ushort* __restrict__ k, const ushort* __restrict__ v,
    const float* __restrict__ xr, const float* __restrict__ Wgk2,
    const float* __restrict__ bgk2, ushort* __restrict__ Sdelta,
    float* __restrict__ Lam, ushort* __restrict__ Vtg,
    ushort* __restrict__ Eb) {
  const int bid = blockIdx.x;
  const int c = bid & 31, bh = bid >> 5;
  const int b = bh >> 4, h = bh & 15;
  const int tid = threadIdx.x;
  const int lane = tid & 63, wave = tid >> 6;
  const int fm = lane & 15, quad = lane >> 4;
  const int wm2 = (wave >> 1) * 32, wn2 = (wave & 1) * 32;

  __shared__ ushort sKt[64 * SP];
  __shared__ ushort sVt[64 * SP];
  __shared__ float sG[64 * SGS];
  __shared__ float sW2[RANK * 64];

  const size_t base = ((size_t)b * LSEQ + (size_t)c * CHUNK) * HIDS + (size_t)h * HDIM;
  const int r = tid >> 2, c0 = (tid & 3) * 16;
  const size_t gb = base + (size_t)r * HIDS + c0;

  // stage Wgk2 head-slice [16][64] f32
  {
    const int wr = tid >> 4, wc = (tid & 15) * 4;
    *(float4*)&sW2[wr * 64 + wc] =
        *(const float4*)(Wgk2 + (size_t)wr * HIDS + h * HDIM + wc);
  }
  // xr row for this thread's time-step (4 lanes per row share; L2-hot)
  float xrr[16];
  {
    const size_t xrow = ((size_t)b * LSEQ + (size_t)c * CHUNK + r) * RANK;
#pragma unroll
    for (int m = 0; m < 4; ++m)
      *(float4*)&xrr[m * 4] = *(const float4*)(xr + xrow + m * 4);
  }
  float bias[16];
#pragma unroll
  for (int m = 0; m < 4; ++m)
    *(float4*)&bias[m * 4] = *(const float4*)(bgk2 + h * HDIM + c0 + m * 4);
  __syncthreads();

  // z = xr . W2slice + bias -> gk = logsig16(z)
#pragma unroll
  for (int i = 0; i < 16; ++i) {
    float z = bias[i];
#pragma unroll
    for (int t2 = 0; t2 < 16; ++t2)
      z = fmaf(xrr[t2], sW2[t2 * 64 + c0 + i], z);
    sG[r * SGS + c0 + i] = logsig16(z);
  }
  // pair partition (K, V) — issue loads to overlap with cumsum
  const int pr = (tid >> 3) * 2, pc = (tid & 7) * 8;
  const size_t pb = base + (size_t)pr * HIDS + pc;
  short8 ka = *(const short8*)(k + pb);
  short8 kb2 = *(const short8*)(k + pb + HIDS);
  short8 va = *(const short8*)(v + pb);
  short8 vb2 = *(const short8*)(v + pb + HIDS);
  __syncthreads();

  // inclusive cumsum along t per v column
  const int vcol = tid & 63, qtr = tid >> 6;
  {
    float run = 0.f;
#pragma unroll
    for (int i = 0; i < 16; ++i) {
      int idx = (qtr * 16 + i) * SGS + vcol;
      run += sG[idx];
      sG[idx] = run;
    }
  }
  __syncthreads();
  float pre = 0.f;
  for (int j = 0; j < qtr; ++j) pre += sG[(j * 16 + 15) * SGS + vcol];
  __syncthreads();
#pragma unroll
  for (int i = 0; i < 16; ++i) sG[(qtr * 16 + i) * SGS + vcol] += pre;
  __syncthreads();

  // E = e^Gamma -> global (coalesced 32B/thread)
  {
    ushort eb[16];
#pragma unroll
    for (int i = 0; i < 16; ++i) eb[i] = f2bf(__expf(sG[r * SGS + c0 + i]));
    *(short8*)(Eb + gb) = *(short8*)&eb[0];
    *(short8*)(Eb + gb + 8) = *(short8*)&eb[8];
  }

  // transposed tiles (ushort2 writes)
#pragma unroll
  for (int i = 0; i < 8; ++i) {
    ushort2 kk;
    kk.x = (ushort)ka[i];
    kk.y = (ushort)kb2[i];
    *(ushort2*)&sKt[(pc + i) * SP + pr] = kk;
    float Ga = sG[pr * SGS + pc + i];
    float Gb2 = sG[(pr + 1) * SGS + pc + i];
    ushort2 vv;
    vv.x = f2bf(bf2f((ushort)va[i]) * __expf(-Ga));
    vv.y = f2bf(bf2f((ushort)vb2[i]) * __expf(-Gb2));
    *(ushort2*)&sVt[(pc + i) * SP + pr] = vv;
  }
  __syncthreads();

  // export V~^T tile (coalesced 32B/thread)
  {
    const size_t vb3 = (size_t)(bh * NCHUNK + c) * (HDIM * HDIM);
    *(short8*)(Vtg + vb3 + (size_t)r * HDIM + c0) = *(const short8*)&sVt[r * SP + c0];
    *(short8*)(Vtg + vb3 + (size_t)r * HDIM + c0 + 8) =
        *(const short8*)&sVt[r * SP + c0 + 8];
  }

  if (tid < 64)
    Lam[(size_t)(bh * NCHUNK + c) * HDIM + tid] = __expf(sG[63 * SGS + tid]);

  floatx4 accD[2][2];
#pragma unroll
  for (int i = 0; i < 2; ++i)
#pragma unroll
    for (int j = 0; j < 2; ++j) accD[i][j] = (floatx4){0.f, 0.f, 0.f, 0.f};
#pragma unroll
  for (int ks = 0; ks < 2; ++ks) {
    short8 av[2], bk[2];
#pragma unroll
    for (int i = 0; i < 2; ++i)
      av[i] = *(const short8*)&sVt[(wm2 + i * 16 + fm) * SP + ks * 32 + quad * 8];
#pragma unroll
    for (int j = 0; j < 2; ++j)
      bk[j] = *(const short8*)&sKt[(wn2 + j * 16 + fm) * SP + ks * 32 + quad * 8];
#pragma unroll
    for (int i = 0; i < 2; ++i)
#pragma unroll
      for (int j = 0; j < 2; ++j)
        accD[i][j] = __builtin_amdgcn_mfma_f32_16x16x32_bf16(av[i], bk[j],
                                                             accD[i][j], 0, 0, 0);
  }
  const size_t sbase = (size_t)(bh * NCHUNK + c) * (HDIM * HDIM);
#pragma unroll
  for (int i = 0; i < 2; ++i) {
    const int m0 = wm2 + i * 16 + quad * 4;
    float lam[4];
#pragma unroll
    for (int rr = 0; rr < 4; ++rr) lam[rr] = __expf(sG[63 * SGS + m0 + rr]);
#pragma unroll
    for (int j = 0; j < 2; ++j) {
      const int n = wn2 + j * 16 + fm;
#pragma unroll
      for (int rr = 0; rr < 4; ++rr)
        Sdelta[sbase + (size_t)(m0 + rr) * HDIM + n] = f2bf(accD[i][j][rr] * lam[rr]);
    }
  }
}

// ---------------------------------------------------------------------------
// state_scan: elementwise-parallel over 4096 state slots; 256 blocks.
// ---------------------------------------------------------------------------
__global__ __launch_bounds__(256) void state_scan_kernel(
    const ushort* __restrict__ Sdelta, const float* __restrict__ Lam,
    ushort* __restrict__ Sprev) {
  const int bh = blockIdx.x >> 3;
  const int sl = blockIdx.x & 7;
  const int tid = threadIdx.x;
  const int e0 = sl * 512 + tid;
  float S0 = 0.f, S1 = 0.f;

  float pd0[2], pd1[2], pl0[2], pl1[2];
#pragma unroll
  for (int s = 0; s < 2; ++s) {
    size_t nb = (size_t)(bh * NCHUNK + s) * (HDIM * HDIM);
    size_t nl = (size_t)(bh * NCHUNK + s) * HDIM;
    pd0[s] = bf2f(Sdelta[nb + e0]);
    pd1[s] = bf2f(Sdelta[nb + e0 + 256]);
    pl0[s] = Lam[nl + (e0 >> 6)];
    pl1[s] = Lam[nl + ((e0 + 256) >> 6)];
  }

  for (int c = 0; c < NCHUNK; ++c) {
    const int s = c & 1;
    float cd0 = pd0[s], cd1 = pd1[s], cl0 = pl0[s], cl1 = pl1[s];
    if (c + 2 < NCHUNK) {
      size_t nb = (size_t)(bh * NCHUNK + c + 2) * (HDIM * HDIM);
      size_t nl = (size_t)(bh * NCHUNK + c + 2) * HDIM;
      pd0[s] = bf2f(Sdelta[nb + e0]);
      pd1[s] = bf2f(Sdelta[nb + e0 + 256]);
      pl0[s] = Lam[nl + (e0 >> 6)];
      pl1[s] = Lam[nl + ((e0 + 256) >> 6)];
    }
    size_t ob = (size_t)(bh * NCHUNK + c) * (HDIM * HDIM);
    Sprev[ob + e0] = f2bf(S0);
    Sprev[ob + e0 + 256] = f2bf(S1);
    S0 = fmaf(S0, cl0, cd0);
    S1 = fmaf(S1, cl1, cd1);
  }
}

// ---------------------------------------------------------------------------
// chunk_fused: att(bf16) = E . ( tril(QK^T) @ V~ + Q @ Sprev^T )
// ---------------------------------------------------------------------------
__global__ __launch_bounds__(256) void chunk_fused_kernel(
    const ushort* __restrict__ q, const ushort* __restrict__ k,
    const ushort* __restrict__ Vtg, const ushort* __restrict__ Eb,
    const ushort* __restrict__ Sprev, ushort* __restrict__ att) {
  const int bid = blockIdx.x;
  const int c = bid & 31, bh = bid >> 5;
  const int b = bh >> 4, h = bh & 15;
  const int tid = threadIdx.x;
  const int lane = tid & 63, wave = tid >> 6;
  const int fm = lane & 15, quad = lane >> 4;
  const int wm2 = (wave >> 1) * 32, wn2 = (wave & 1) * 32;

  __shared__ ushort sQ[64 * SP];
  __shared__ ushort sK[64 * SP];   // reused as sSp after scores
  __shared__ ushort sVt[64 * SP];
  __shared__ ushort sA[64 * SP];
  ushort* sSp = sK;

  const size_t base = ((size_t)b * LSEQ + (size_t)c * CHUNK) * HIDS + (size_t)h * HDIM;
  const size_t sbase = (size_t)(bh * NCHUNK + c) * (HDIM * HDIM);
  const int r = tid >> 2, c0 = (tid & 3) * 16;
  const size_t gb = base + (size_t)r * HIDS + c0;
  short8 sp0 = *(const short8*)(Sprev + sbase + (size_t)r * HDIM + c0);
  short8 sp1 = *(const short8*)(Sprev + sbase + (size_t)r * HDIM + c0 + 8);
  *(short8*)&sQ[r * SP + c0] = *(const short8*)(q + gb);
  *(short8*)&sQ[r * SP + c0 + 8] = *(const short8*)(q + gb + 8);
  *(short8*)&sK[r * SP + c0] = *(const short8*)(k + gb);
  *(short8*)&sK[r * SP + c0 + 8] = *(const short8*)(k + gb + 8);
  *(short8*)&sVt[r * SP + c0] = *(const short8*)(Vtg + sbase + (size_t)r * HDIM + c0);
  *(short8*)&sVt[r * SP + c0 + 8] =
      *(const short8*)(Vtg + sbase + (size_t)r * HDIM + c0 + 8);
  __syncthreads();

  // scores = tril(Q K^T)
  floatx4 accS[2][2];
#pragma unroll
  for (int i = 0; i < 2; ++i)
#pragma unroll
    for (int j = 0; j < 2; ++j) accS[i][j] = (floatx4){0.f, 0.f, 0.f, 0.f};
#pragma unroll
  for (int ks = 0; ks < 2; ++ks) {
    short8 a[2], bb[2];
#pragma unroll
    for (int i = 0; i < 2; ++i)
      a[i] = *(const short8*)&sQ[(wm2 + i * 16 + fm) * SP + ks * 32 + quad * 8];
#pragma unroll
    for (int j = 0; j < 2; ++j)
      bb[j] = *(const short8*)&sK[(wn2 + j * 16 + fm) * SP + ks * 32 + quad * 8];
#pragma unroll
    for (int i = 0; i < 2; ++i)
#pragma unroll
      for (int j = 0; j < 2; ++j)
        accS[i][j] = __builtin_amdgcn_mfma_f32_16x16x32_bf16(a[i], bb[j],
                                                             accS[i][j], 0, 0, 0);
  }
  __syncthreads();  // all waves done reading sK

  // write sA (tril) and sSp (into sK space)
#pragma unroll
  for (int i = 0; i < 2; ++i)
#pragma unroll
    for (int j = 0; j < 2; ++j) {
      const int t0 = wm2 + i * 16 + quad * 4;
      const int s = wn2 + j * 16 + fm;
#pragma unroll
      for (int rr = 0; rr < 4; ++rr) {
        float val = (s <= t0 + rr) ? accS[i][j][rr] : 0.f;
        sA[(t0 + rr) * SP + s] = f2bf(val);
      }
    }
  *(short8*)&sSp[r * SP + c0] = sp0;
  *(short8*)&sSp[r * SP + c0 + 8] = sp1;
  __syncthreads();

  // att = E . (sA @ V~  +  Q @ Sprev^T)
  floatx4 acc[2][2];
#pragma unroll
  for (int i = 0; i < 2; ++i)
#pragma unroll
    for (int j = 0; j < 2; ++j) acc[i][j] = (floatx4){0.f, 0.f, 0.f, 0.f};
#pragma unroll
  for (int ks = 0; ks < 2; ++ks) {
    short8 aa[2], aq[2], bv[2], bs[2];
#pragma unroll
    for (int i = 0; i < 2; ++i) {
      aa[i] = *(const short8*)&sA[(wm2 + i * 16 + fm) * SP + ks * 32 + quad * 8];
      aq[i] = *(const short8*)&sQ[(wm2 + i * 16 + fm) * SP + ks * 32 + quad * 8];
    }
#pragma unroll
    for (int j = 0; j < 2; ++j) {
      bv[j] = *(const short8*)&sVt[(wn2 + j * 16 + fm) * SP + ks * 32 + quad * 8];
      bs[j] = *(const short8*)&sSp[(wn2 + j * 16 + fm) * SP + ks * 32 + quad * 8];
    }
#pragma unroll
    for (int i = 0; i < 2; ++i)
#pragma unroll
      for (int j = 0; j < 2; ++j) {
        acc[i][j] = __builtin_amdgcn_mfma_f32_16x16x32_bf16(aa[i], bv[j],
                                                            acc[i][j], 0, 0, 0);
        acc[i][j] = __builtin_amdgcn_mfma_f32_16x16x32_bf16(aq[i], bs[j],
                                                            acc[i][j], 0, 0, 0);
      }
  }
#pragma unroll
  for (int i = 0; i < 2; ++i)
#pragma unroll
    for (int j = 0; j < 2; ++j) {
      const int m0 = wm2 + i * 16 + quad * 4;
      const int n = wn2 + j * 16 + fm;
#pragma unroll
      for (int rr = 0; rr < 4; ++rr) {
        const size_t idx = base + (size_t)(m0 + rr) * HIDS + n;
        att[idx] = f2bf(acc[i][j][rr] * bf2f(Eb[idx]));
      }
    }
}

// ---------------------------------------------------------------------------
// y = (LayerNorm(att) * gamma + beta) * silu(g), bf16 in/out.
// ---------------------------------------------------------------------------
__global__ __launch_bounds__(256) void ln_gate_kernel(const ushort* __restrict__ att,
                                                      const ushort* __restrict__ g,
                                                      const float* __restrict__ gamma,
                                                      const float* __restrict__ beta,
                                                      ushort* __restrict__ ybf) {
  const int row = blockIdx.x;
  const int tid = threadIdx.x;
  ushort4 au = *(const ushort4*)(att + (size_t)row * HIDS + tid * 4);
  float ax = bf2f(au.x), ay = bf2f(au.y), az = bf2f(au.z), aw = bf2f(au.w);
  float s = ax + ay + az + aw;
  float ss = ax * ax + ay * ay + az * az + aw * aw;
#pragma unroll
  for (int off = 32; off; off >>= 1) {
    s += __shfl_down(s, off);
    ss += __shfl_down(ss, off);
  }
  __shared__ float rs[4], rss[4];
  const int wid = tid >> 6;
  if ((tid & 63) == 0) { rs[wid] = s; rss[wid] = ss; }
  __syncthreads();
  const float mean = (rs[0] + rs[1] + rs[2] + rs[3]) * (1.f / HIDS);
  const float ex2 = (rss[0] + rss[1] + rss[2] + rss[3]) * (1.f / HIDS);
  const float rstd = rsqrtf(ex2 - mean * mean + 1e-5f);

  float4 ga = *(const float4*)(gamma + tid * 4);
  float4 be = *(const float4*)(beta + tid * 4);
  ushort4 gu = *(const ushort4*)(g + (size_t)row * HIDS + tid * 4);
  float gx = bf2f(gu.x), gy = bf2f(gu.y), gz = bf2f(gu.z), gw = bf2f(gu.w);
  float4 o;
  o.x = ((ax - mean) * rstd * ga.x + be.x) * (gx / (1.f + __expf(-gx)));
  o.y = ((ay - mean) * rstd * ga.y + be.y) * (gy / (1.f + __expf(-gy)));
  o.z = ((az - mean) * rstd * ga.z + be.z) * (gz / (1.f + __expf(-gz)));
  o.w = ((aw - mean) * rstd * ga.w + be.w) * (gw / (1.f + __expf(-gw)));
  ushort4 ob;
  ob.x = f2bf(o.x); ob.y = f2bf(o.y); ob.z = f2bf(o.z); ob.w = f2bf(o.w);
  *(ushort4*)(ybf + (size_t)row * HIDS + tid * 4) = ob;
}

// ---------------------------------------------------------------------------
extern "C" void kernel_launch(void* const* d_in, const int* in_sizes, int n_in,
                              void* d_out, int out_size, void* d_ws, size_t ws_size,
                              hipStream_t stream) {
  const float* x     = (const float*)d_in[0];
  const float* Wq    = (const float*)d_in[1];
  const float* Wk    = (const float*)d_in[2];
  const float* Wv    = (const float*)d_in[3];
  const float* Wg    = (const float*)d_in[4];
  const float* Wgk1  = (const float*)d_in[5];
  const float* Wgk2  = (const float*)d_in[6];
  const float* bgk2  = (const float*)d_in[7];
  const float* gamma = (const float*)d_in[8];
  const float* beta  = (const float*)d_in[9];
  const float* Wout  = (const float*)d_in[10];
  float* out = (float*)d_out;

  const size_t SZ = (size_t)NROW * HIDS;  // 4M elements
  float* ws = (float*)d_ws;
  float* Lamb = ws;                         // 64K floats
  ushort* attb   = (ushort*)(ws + 65536);   // bf16 4M
  ushort* Sdelta = attb + SZ;
  ushort* Sprevb = Sdelta + SZ;
  ushort* Vtgb   = Sprevb + SZ;             // V~^T tiles (bf16)
  ushort* Ebb    = Vtgb + SZ;               // e^Gamma (bf16)
  ushort* qbf = Ebb + SZ;
  ushort* kbf = qbf + SZ;
  ushort* vbf = kbf + SZ;
  ushort* gbf = vbf + SZ;
  ushort* xbf = gbf + SZ;
  ushort* Wtq = xbf + SZ;
  ushort* Wtk = Wtq + HIDS * HIDS;
  ushort* Wtv = Wtk + HIDS * HIDS;
  ushort* Wtg = Wtv + HIDS * HIDS;
  ushort* Wto = Wtg + HIDS * HIDS;
  float* xrb = (float*)(Wto + HIDS * HIDS);  // [4096][16] f32
  ushort* ybf = vbf;  // vbf dead after sdelta

  prep_kernel<<<4096 + 1280, 256, 0, stream>>>(
      x, xbf, Wq, Wk, Wv, Wg, Wout, Wtq, Wtk, Wtv, Wtg, Wto);

  xr_kernel<<<NROW / 16, 256, 0, stream>>>(xbf, Wgk1, xrb);

  proj4_kernel<<<dim3(4 * (HIDS / 128), NROW / 128), 256, 0, stream>>>(
      xbf, Wtq, Wtk, Wtv, Wtg, qbf, kbf, vbf, gbf);

  sdelta_kernel<<<BBATCH * NHEAD * NCHUNK, 256, 0, stream>>>(
      kbf, vbf, xrb, Wgk2, bgk2, Sdelta, Lamb, Vtgb, Ebb);
  state_scan_kernel<<<256, 256, 0, stream>>>(Sdelta, Lamb, Sprevb);
  chunk_fused_kernel<<<BBATCH * NHEAD * NCHUNK, 256, 0, stream>>>(
      qbf, kbf, Vtgb, Ebb, Sprevb, attb);

  ln_gate_kernel<<<NROW, 256, 0, stream>>>(attb, gbf, gamma, beta, ybf);
  gemm_out_kernel<<<dim3(HIDS / 128, NROW / 128), 256, 0, stream>>>(ybf, Wto, out);
}

// Round 3
// 219.243 us; speedup vs baseline: 1.0163x; 1.0163x over previous
//
#include <hip/hip_runtime.h>
#include <cstdint>
#include <cstddef>

#define HIDS 1024
#define NHEAD 16
#define HDIM 64
#define LSEQ 2048
#define BBATCH 2
#define NROW (BBATCH * LSEQ)  // 4096
#define CHUNK 64
#define NCHUNK (LSEQ / CHUNK)  // 32
#define RANK 16

typedef short short8 __attribute__((ext_vector_type(8)));
typedef float floatx4 __attribute__((ext_vector_type(4)));

__device__ __forceinline__ ushort f2bf(float f) {
  uint32_t u = __float_as_uint(f);
  uint32_t r = (u + 0x7fffu + ((u >> 16) & 1u)) >> 16;  // RNE
  return (ushort)r;
}
__device__ __forceinline__ float bf2f(ushort u) {
  return __uint_as_float(((uint32_t)u) << 16);
}
// log_sigmoid(z)/16 via native exp/log (arg of log in (1,2] -> accurate)
__device__ __forceinline__ float logsig16(float z) {
  return (fminf(z, 0.f) - __logf(1.f + __expf(-fabsf(z)))) * (1.f / 16.f);
}

__device__ __forceinline__ void async_copy16(const void* g, void* l) {
  __builtin_amdgcn_global_load_lds(
      (const __attribute__((address_space(1))) void*)g,
      (__attribute__((address_space(3))) void*)l, 16, 0, 0);
}

// ---------------------------------------------------------------------------
// prep: fused cvt_x (blocks 0..4095) + transpose_w (4096..5375).
// ---------------------------------------------------------------------------
__global__ __launch_bounds__(256) void prep_kernel(
    const float* __restrict__ x, ushort* __restrict__ xbf,
    const float* __restrict__ W0, const float* __restrict__ W1,
    const float* __restrict__ W2, const float* __restrict__ W3,
    const float* __restrict__ W4, ushort* __restrict__ T0,
    ushort* __restrict__ T1, ushort* __restrict__ T2, ushort* __restrict__ T3,
    ushort* __restrict__ T4) {
  __shared__ float sbuf[64 * 65];
  const int bid = blockIdx.x;
  const int tid = threadIdx.x;

  if (bid < 4096) {  // ---- cvt_x
    const int i = bid * 256 + tid;
    float4 f = *(const float4*)(x + (size_t)i * 4);
    ushort4 o;
    o.x = f2bf(f.x); o.y = f2bf(f.y); o.z = f2bf(f.z); o.w = f2bf(f.w);
    *(ushort4*)(xbf + (size_t)i * 4) = o;
  } else {  // ---- transpose_w
    const int w = bid - 4096;
    const int z = w >> 8, rem = w & 255;
    const float* W = (z == 0) ? W0 : (z == 1) ? W1 : (z == 2) ? W2
                     : (z == 3) ? W3 : W4;
    ushort* T = (z == 0) ? T0 : (z == 1) ? T1 : (z == 2) ? T2
                : (z == 3) ? T3 : T4;
    const int k0 = (rem >> 4) * 64, n0 = (rem & 15) * 64;
    const int r = tid >> 2, c4 = (tid & 3) * 16;
#pragma unroll
    for (int i = 0; i < 4; ++i) {
      float4 f = *(const float4*)(W + (size_t)(k0 + r) * HIDS + n0 + c4 + i * 4);
      sbuf[r * 65 + c4 + i * 4 + 0] = f.x;
      sbuf[r * 65 + c4 + i * 4 + 1] = f.y;
      sbuf[r * 65 + c4 + i * 4 + 2] = f.z;
      sbuf[r * 65 + c4 + i * 4 + 3] = f.w;
    }
    __syncthreads();
    const int n = tid >> 2, kc = (tid & 3) * 16;
#pragma unroll
    for (int i = 0; i < 4; ++i) {
      int kk = kc + i * 4;
      ushort4 o;
      o.x = f2bf(sbuf[(kk + 0) * 65 + n]);
      o.y = f2bf(sbuf[(kk + 1) * 65 + n]);
      o.z = f2bf(sbuf[(kk + 2) * 65 + n]);
      o.w = f2bf(sbuf[(kk + 3) * 65 + n]);
      *(ushort4*)(T + (size_t)(n0 + n) * HIDS + k0 + kk) = o;
    }
  }
}

// ---------------------------------------------------------------------------
// xr = xbf @ Wgk1 : [4096,1024] x [1024,16] -> f32 [4096,16]. 16 rows/block.
// ---------------------------------------------------------------------------
#define XSTR 1040
__global__ __launch_bounds__(256) void xr_kernel(
    const ushort* __restrict__ xbf, const float* __restrict__ Wgk1,
    float* __restrict__ xr) {
  __shared__ float sW1[HIDS * RANK];       // 64 KB, layout [k][16]
  __shared__ ushort sX[16 * XSTR];         // 16 rows, padded
  const int tid = threadIdx.x;
  const int r0 = blockIdx.x * 16;
#pragma unroll
  for (int j = 0; j < 16; ++j) {
    const int idx = j * 1024 + tid * 4;
    *(float4*)&sW1[idx] = *(const float4*)(Wgk1 + idx);
  }
#pragma unroll
  for (int j = 0; j < 8; ++j) {
    const int e = j * 2048 + tid * 8;
    const int rr = e >> 10, kk = e & 1023;
    *(short8*)&sX[rr * XSTR + kk] =
        *(const short8*)(xbf + (size_t)(r0 + rr) * HIDS + kk);
  }
  __syncthreads();
  const int r = tid >> 4, n = tid & 15;
  float acc = 0.f;
  for (int k8 = 0; k8 < HIDS; k8 += 8) {
    short8 xv = *(const short8*)&sX[r * XSTR + k8];
#pragma unroll
    for (int i = 0; i < 8; ++i)
      acc = fmaf(bf2f((ushort)xv[i]), sW1[(k8 + i) * RANK + n], acc);
  }
  xr[(size_t)(r0 + r) * RANK + n] = acc;
}

// ---------------------------------------------------------------------------
// proj8: ONE 4096(M) x 4096(N) x 1024(K) bf16 GEMM over the concatenated
// weights [Wtq|Wtk|Wtv|Wtg] (contiguous, n-major), 256x256 tile, BK=64,
// 8 waves (2Mx4N), 128KB LDS double-buffer, 4-phase K-step with counted
// vmcnt (T3+T4) + setprio around MFMA clusters (T5). Chunk-XOR LDS layout
// (same as proven proj4 scheme, 0 bank conflicts).
// Output scatters to the 4 contiguous buffers qb|kb|vb|gb.
// ---------------------------------------------------------------------------
#define POFF(buf, mat, half) ((((buf)*2 + (mat)) * 2 + (half)) * 8192)

__global__ __launch_bounds__(512, 2) void proj8_kernel(
    const ushort* __restrict__ xbf, const ushort* __restrict__ Wcat,
    ushort* __restrict__ Cq) {
  __shared__ ushort sT[2 * 2 * 2 * 8192];  // [buf][mat][half][256*32] = 128 KB
  const int tid = threadIdx.x;
  const int lane = tid & 63, wid = tid >> 6;
  const int fm = lane & 15, quad = lane >> 4;
  const int sq8 = ((quad + (fm >> 1)) & 3) * 8;  // read slot (XOR chunk swz)
  const int wr = wid >> 2, wc = wid & 3;         // 2Mx4N wave grid
  const int bm = blockIdx.y * 256, bn = blockIdx.x * 256;

  // staging: thread t covers slots t and t+512 of each 256x32 half-buffer
  const int srow = tid >> 2;
  const int qch = ((((tid & 3) - ((tid >> 3) & 3)) & 3)) * 8;  // src k-chunk
  const ushort* Ab = xbf + (size_t)(bm + srow) * HIDS + qch;
  const ushort* Bb = Wcat + (size_t)(bn + srow) * HIDS + qch;

#define STAGE_A(ktn, nb)                                                      \
  do {                                                                        \
    const int kc_ = (ktn) * 64;                                               \
    async_copy16(Ab + kc_, (char*)&sT[POFF(nb, 0, 0)] + tid * 16);            \
    async_copy16(Ab + (size_t)128 * HIDS + kc_,                               \
                 (char*)&sT[POFF(nb, 0, 0)] + tid * 16 + 8192);               \
    async_copy16(Ab + kc_ + 32, (char*)&sT[POFF(nb, 0, 1)] + tid * 16);       \
    async_copy16(Ab + (size_t)128 * HIDS + kc_ + 32,                          \
                 (char*)&sT[POFF(nb, 0, 1)] + tid * 16 + 8192);               \
  } while (0)
#define STAGE_B0(ktn, nb)                                                     \
  do {                                                                        \
    const int kc_ = (ktn) * 64;                                               \
    async_copy16(Bb + kc_, (char*)&sT[POFF(nb, 1, 0)] + tid * 16);            \
    async_copy16(Bb + (size_t)128 * HIDS + kc_,                               \
                 (char*)&sT[POFF(nb, 1, 0)] + tid * 16 + 8192);               \
  } while (0)
#define STAGE_B1(ktn, nb)                                                     \
  do {                                                                        \
    const int kc_ = (ktn) * 64;                                               \
    async_copy16(Bb + kc_ + 32, (char*)&sT[POFF(nb, 1, 1)] + tid * 16);       \
    async_copy16(Bb + (size_t)128 * HIDS + kc_ + 32,                          \
                 (char*)&sT[POFF(nb, 1, 1)] + tid * 16 + 8192);               \
  } while (0)
#define BARRIER()                        \
  do {                                   \
    asm volatile("" ::: "memory");       \
    __builtin_amdgcn_s_barrier();        \
    asm volatile("" ::: "memory");       \
  } while (0)

  const int aoff = (wr * 128 + fm) * 32 + sq8;  // + m*512, half selects buffer
  const int boff = (wc * 64 + fm) * 32 + sq8;   // + n*512

  floatx4 acc[8][4];
#pragma unroll
  for (int i = 0; i < 8; ++i)
#pragma unroll
    for (int j = 0; j < 4; ++j) acc[i][j] = (floatx4){0.f, 0.f, 0.f, 0.f};

  // prologue: stage K-tile 0 into buf 0 (8 loads)
  STAGE_A(0, 0);
  STAGE_B0(0, 0);
  STAGE_B1(0, 0);

  for (int kt = 0; kt < 16; ++kt) {
    const int cur = kt & 1, nxt = cur ^ 1;
    // top: issue next A-stage, counted wait for THIS tile's 8 loads
    if (kt < 15) {
      STAGE_A(kt + 1, nxt);
      asm volatile("s_waitcnt vmcnt(4)" ::: "memory");
    } else {
      asm volatile("s_waitcnt vmcnt(0)" ::: "memory");
    }
    BARRIER();

    short8 af[4][2], bfr[4][2];
    // ---- ph0: read A m=0..3 + B n=0..1, issue B-h0 stage, MFMA Q(0,0)
#pragma unroll
    for (int m = 0; m < 4; ++m) {
      af[m][0] = *(const short8*)&sT[POFF(cur, 0, 0) + aoff + m * 512];
      af[m][1] = *(const short8*)&sT[POFF(cur, 0, 1) + aoff + m * 512];
    }
#pragma unroll
    for (int n = 0; n < 2; ++n) {
      bfr[n][0] = *(const short8*)&sT[POFF(cur, 1, 0) + boff + n * 512];
      bfr[n][1] = *(const short8*)&sT[POFF(cur, 1, 1) + boff + n * 512];
    }
    if (kt < 15) STAGE_B0(kt + 1, nxt);
    BARRIER();
    __builtin_amdgcn_s_setprio(1);
#pragma unroll
    for (int m = 0; m < 4; ++m)
#pragma unroll
      for (int n = 0; n < 2; ++n) {
        acc[m][n] = __builtin_amdgcn_mfma_f32_16x16x32_bf16(af[m][0], bfr[n][0],
                                                            acc[m][n], 0, 0, 0);
        acc[m][n] = __builtin_amdgcn_mfma_f32_16x16x32_bf16(af[m][1], bfr[n][1],
                                                            acc[m][n], 0, 0, 0);
      }
    __builtin_amdgcn_s_setprio(0);
    BARRIER();

    // ---- ph1: read B n=2..3, issue B-h1 stage, MFMA Q(0,1)
#pragma unroll
    for (int n = 2; n < 4; ++n) {
      bfr[n][0] = *(const short8*)&sT[POFF(cur, 1, 0) + boff + n * 512];
      bfr[n][1] = *(const short8*)&sT[POFF(cur, 1, 1) + boff + n * 512];
    }
    if (kt < 15) STAGE_B1(kt + 1, nxt);
    BARRIER();
    __builtin_amdgcn_s_setprio(1);
#pragma unroll
    for (int m = 0; m < 4; ++m)
#pragma unroll
      for (int n = 2; n < 4; ++n) {
        acc[m][n] = __builtin_amdgcn_mfma_f32_16x16x32_bf16(af[m][0], bfr[n][0],
                                                            acc[m][n], 0, 0, 0);
        acc[m][n] = __builtin_amdgcn_mfma_f32_16x16x32_bf16(af[m][1], bfr[n][1],
                                                            acc[m][n], 0, 0, 0);
      }
    __builtin_amdgcn_s_setprio(0);
    BARRIER();

    // ---- ph2: read A m=4..7, MFMA Q(1,0)
#pragma unroll
    for (int m = 0; m < 4; ++m) {
      af[m][0] = *(const short8*)&sT[POFF(cur, 0, 0) + aoff + (m + 4) * 512];
      af[m][1] = *(const short8*)&sT[POFF(cur, 0, 1) + aoff + (m + 4) * 512];
    }
    BARRIER();
    __builtin_amdgcn_s_setprio(1);
#pragma unroll
    for (int m = 0; m < 4; ++m)
#pragma unroll
      for (int n = 0; n < 2; ++n) {
        acc[m + 4][n] = __builtin_amdgcn_mfma_f32_16x16x32_bf16(
            af[m][0], bfr[n][0], acc[m + 4][n], 0, 0, 0);
        acc[m + 4][n] = __builtin_amdgcn_mfma_f32_16x16x32_bf16(
            af[m][1], bfr[n][1], acc[m + 4][n], 0, 0, 0);
      }
    __builtin_amdgcn_s_setprio(0);
    BARRIER();

    // ---- ph3: MFMA Q(1,1) (all frags in regs)
    __builtin_amdgcn_s_setprio(1);
#pragma unroll
    for (int m = 0; m < 4; ++m)
#pragma unroll
      for (int n = 2; n < 4; ++n) {
        acc[m + 4][n] = __builtin_amdgcn_mfma_f32_16x16x32_bf16(
            af[m][0], bfr[n][0], acc[m + 4][n], 0, 0, 0);
        acc[m + 4][n] = __builtin_amdgcn_mfma_f32_16x16x32_bf16(
            af[m][1], bfr[n][1], acc[m + 4][n], 0, 0, 0);
      }
    __builtin_amdgcn_s_setprio(0);
    // end-of-iteration barrier: all waves done reading buf[cur] before anyone
    // issues the next iteration's stage into it
    BARRIER();
  }

  // epilogue: scatter to the z = col>>10 projection buffer (contiguous)
  const int cb = bn + wc * 64;
  const int z = cb >> 10;
  const int ccol = cb & 1023;
  ushort* C = Cq + (size_t)z * ((size_t)NROW * HIDS);
#pragma unroll
  for (int m = 0; m < 8; ++m) {
    const int row0 = bm + wr * 128 + m * 16 + quad * 4;
#pragma unroll
    for (int n = 0; n < 4; ++n) {
      const int col = ccol + n * 16 + fm;
#pragma unroll
      for (int rr = 0; rr < 4; ++rr)
        C[(size_t)(row0 + rr) * HIDS + col] = f2bf(acc[m][n][rr]);
    }
  }
#undef STAGE_A
#undef STAGE_B0
#undef STAGE_B1
#undef BARRIER
}

// ---------------------------------------------------------------------------
// Output GEMM: 128x128 tile, BK=64, swizzled staging, fp32 out.
// ---------------------------------------------------------------------------
__global__ __launch_bounds__(256) void gemm_out_kernel(
    const ushort* __restrict__ A, const ushort* __restrict__ Bt,
    float* __restrict__ C) {
  __shared__ ushort As[2][128 * 32];
  __shared__ ushort Bs[2][128 * 32];
  const int tid = threadIdx.x;
  const int wave = tid >> 6, lane = tid & 63;
  const int wm = (wave >> 1) * 64, wn = (wave & 1) * 64;
  const int fm = lane & 15, quad = lane >> 4;
  const int sq8 = ((quad + (fm >> 1)) & 3) * 8;
  const int bm = blockIdx.y * 128, bn = blockIdx.x * 128;
  const int lrow = tid >> 2;
  const int lk8 = ((((tid & 3) - ((tid >> 3) & 3)) & 3)) * 8;
  const ushort* Ag = A + (size_t)(bm + lrow) * HIDS + lk8;
  const ushort* Bg = Bt + (size_t)(bn + lrow) * HIDS + lk8;
  char* A0 = (char*)&As[0][0] + tid * 16;
  char* A1 = (char*)&As[1][0] + tid * 16;
  char* B0 = (char*)&Bs[0][0] + tid * 16;
  char* B1 = (char*)&Bs[1][0] + tid * 16;

  floatx4 acc[4][4];
#pragma unroll
  for (int i = 0; i < 4; ++i)
#pragma unroll
    for (int j = 0; j < 4; ++j) acc[i][j] = (floatx4){0.f, 0.f, 0.f, 0.f};

  for (int k0 = 0; k0 < HIDS; k0 += 64) {
    __syncthreads();
    async_copy16(Ag + k0, A0);
    async_copy16(Ag + (size_t)64 * HIDS + k0, A0 + 4096);
    async_copy16(Ag + k0 + 32, A1);
    async_copy16(Ag + (size_t)64 * HIDS + k0 + 32, A1 + 4096);
    async_copy16(Bg + k0, B0);
    async_copy16(Bg + (size_t)64 * HIDS + k0, B0 + 4096);
    async_copy16(Bg + k0 + 32, B1);
    async_copy16(Bg + (size_t)64 * HIDS + k0 + 32, B1 + 4096);
    __syncthreads();

#pragma unroll
    for (int ks = 0; ks < 2; ++ks) {
      short8 af[4], bfr[4];
#pragma unroll
      for (int i = 0; i < 4; ++i)
        af[i] = *(const short8*)&As[ks][(wm + i * 16 + fm) * 32 + sq8];
#pragma unroll
      for (int j = 0; j < 4; ++j)
        bfr[j] = *(const short8*)&Bs[ks][(wn + j * 16 + fm) * 32 + sq8];
#pragma unroll
      for (int i = 0; i < 4; ++i)
#pragma unroll
        for (int j = 0; j < 4; ++j)
          acc[i][j] = __builtin_amdgcn_mfma_f32_16x16x32_bf16(af[i], bfr[j],
                                                              acc[i][j], 0, 0, 0);
    }
  }

#pragma unroll
  for (int i = 0; i < 4; ++i) {
    const int row0 = bm + wm + i * 16 + quad * 4;
#pragma unroll
    for (int j = 0; j < 4; ++j) {
      const int col = bn + wn + j * 16 + fm;
#pragma unroll
      for (int r = 0; r < 4; ++r)
        C[(size_t)(row0 + r) * HIDS + col] = acc[i][j][r];
    }
  }
}

#define SP 72   // ushort stride for bf16 LDS tiles (16B-aligned rows)
#define SGS 68  // float stride for Gamma tile

// ---------------------------------------------------------------------------
// sdelta: z = xr @ Wgk2 + b computed inline (rank-16); Gamma=cumsum(logsig16);
// Vt~=(e^-G V)^T; Sdelta = Lam.(V~^T K); exports Vtg (V~^T) and Eb = e^Gamma.
// ---------------------------------------------------------------------------
__global__ __launch_bounds__(256) void sdelta_kernel(
    const ushort* __restrict__ k, const ushort* __restrict__ v,
    const float* __restrict__ xr, const float* __restrict__ Wgk2,
    const float* __restrict__ bgk2, ushort* __restrict__ Sdelta,
    float* __restrict__ Lam, ushort* __restrict__ Vtg,
    ushort* __restrict__ Eb) {
  const int bid = blockIdx.x;
  const int c = bid & 31, bh = bid >> 5;
  const int b = bh >> 4, h = bh & 15;
  const int tid = threadIdx.x;
  const int lane = tid & 63, wave = tid >> 6;
  const int fm = lane & 15, quad = lane >> 4;
  const int wm2 = (wave >> 1) * 32, wn2 = (wave & 1) * 32;

  __shared__ ushort sKt[64 * SP];
  __shared__ ushort sVt[64 * SP];
  __shared__ float sG[64 * SGS];
  __shared__ float sW2[RANK * 64];

  const size_t base = ((size_t)b * LSEQ + (size_t)c * CHUNK) * HIDS + (size_t)h * HDIM;
  const int r = tid >> 2, c0 = (tid & 3) * 16;
  const size_t gb = base + (size_t)r * HIDS + c0;

  // stage Wgk2 head-slice [16][64] f32
  {
    const int wr = tid >> 4, wc = (tid & 15) * 4;
    *(float4*)&sW2[wr * 64 + wc] =
        *(const float4*)(Wgk2 + (size_t)wr * HIDS + h * HDIM + wc);
  }
  // xr row for this thread's time-step (4 lanes per row share; L2-hot)
  float xrr[16];
  {
    const size_t xrow = ((size_t)b * LSEQ + (size_t)c * CHUNK + r) * RANK;
#pragma unroll
    for (int m = 0; m < 4; ++m)
      *(float4*)&xrr[m * 4] = *(const float4*)(xr + xrow + m * 4);
  }
  float bias[16];
#pragma unroll
  for (int m = 0; m < 4; ++m)
    *(float4*)&bias[m * 4] = *(const float4*)(bgk2 + h * HDIM + c0 + m * 4);
  __syncthreads();

  // z = xr . W2slice + bias -> gk = logsig16(z)
#pragma unroll
  for (int i = 0; i < 16; ++i) {
    float z = bias[i];
#pragma unroll
    for (int t2 = 0; t2 < 16; ++t2)
      z = fmaf(xrr[t2], sW2[t2 * 64 + c0 + i], z);
    sG[r * SGS + c0 + i] = logsig16(z);
  }
  // pair partition (K, V) — issue loads to overlap with cumsum
  const int pr = (tid >> 3) * 2, pc = (tid & 7) * 8;
  const size_t pb = base + (size_t)pr * HIDS + pc;
  short8 ka = *(const short8*)(k + pb);
  short8 kb2 = *(const short8*)(k + pb + HIDS);
  short8 va = *(const short8*)(v + pb);
  short8 vb2 = *(const short8*)(v + pb + HIDS);
  __syncthreads();

  // inclusive cumsum along t per v column
  const int vcol = tid & 63, qtr = tid >> 6;
  {
    float run = 0.f;
#pragma unroll
    for (int i = 0; i < 16; ++i) {
      int idx = (qtr * 16 + i) * SGS + vcol;
      run += sG[idx];
      sG[idx] = run;
    }
  }
  __syncthreads();
  float pre = 0.f;
  for (int j = 0; j < qtr; ++j) pre += sG[(j * 16 + 15) * SGS + vcol];
  __syncthreads();
#pragma unroll
  for (int i = 0; i < 16; ++i) sG[(qtr * 16 + i) * SGS + vcol] += pre;
  __syncthreads();

  // E = e^Gamma -> global (coalesced 32B/thread)
  {
    ushort eb[16];
#pragma unroll
    for (int i = 0; i < 16; ++i) eb[i] = f2bf(__expf(sG[r * SGS + c0 + i]));
    *(short8*)(Eb + gb) = *(short8*)&eb[0];
    *(short8*)(Eb + gb + 8) = *(short8*)&eb[8];
  }

  // transposed tiles (ushort2 writes)
#pragma unroll
  for (int i = 0; i < 8; ++i) {
    ushort2 kk;
    kk.x = (ushort)ka[i];
    kk.y = (ushort)kb2[i];
    *(ushort2*)&sKt[(pc + i) * SP + pr] = kk;
    float Ga = sG[pr * SGS + pc + i];
    float Gb2 = sG[(pr + 1) * SGS + pc + i];
    ushort2 vv;
    vv.x = f2bf(bf2f((ushort)va[i]) * __expf(-Ga));
    vv.y = f2bf(bf2f((ushort)vb2[i]) * __expf(-Gb2));
    *(ushort2*)&sVt[(pc + i) * SP + pr] = vv;
  }
  __syncthreads();

  // export V~^T tile (coalesced 32B/thread)
  {
    const size_t vb3 = (size_t)(bh * NCHUNK + c) * (HDIM * HDIM);
    *(short8*)(Vtg + vb3 + (size_t)r * HDIM + c0) = *(const short8*)&sVt[r * SP + c0];
    *(short8*)(Vtg + vb3 + (size_t)r * HDIM + c0 + 8) =
        *(const short8*)&sVt[r * SP + c0 + 8];
  }

  if (tid < 64)
    Lam[(size_t)(bh * NCHUNK + c) * HDIM + tid] = __expf(sG[63 * SGS + tid]);

  floatx4 accD[2][2];
#pragma unroll
  for (int i = 0; i < 2; ++i)
#pragma unroll
    for (int j = 0; j < 2; ++j) accD[i][j] = (floatx4){0.f, 0.f, 0.f, 0.f};
#pragma unroll
  for (int ks = 0; ks < 2; ++ks) {
    short8 av[2], bk[2];
#pragma unroll
    for (int i = 0; i < 2; ++i)
      av[i] = *(const short8*)&sVt[(wm2 + i * 16 + fm) * SP + ks * 32 + quad * 8];
#pragma unroll
    for (int j = 0; j < 2; ++j)
      bk[j] = *(const short8*)&sKt[(wn2 + j * 16 + fm) * SP + ks * 32 + quad * 8];
#pragma unroll
    for (int i = 0; i < 2; ++i)
#pragma unroll
      for (int j = 0; j < 2; ++j)
        accD[i][j] = __builtin_amdgcn_mfma_f32_16x16x32_bf16(av[i], bk[j],
                                                             accD[i][j], 0, 0, 0);
  }
  const size_t sbase = (size_t)(bh * NCHUNK + c) * (HDIM * HDIM);
#pragma unroll
  for (int i = 0; i < 2; ++i) {
    const int m0 = wm2 + i * 16 + quad * 4;
    float lam[4];
#pragma unroll
    for (int rr = 0; rr < 4; ++rr) lam[rr] = __expf(sG[63 * SGS + m0 + rr]);
#pragma unroll
    for (int j = 0; j < 2; ++j) {
      const int n = wn2 + j * 16 + fm;
#pragma unroll
      for (int rr = 0; rr < 4; ++rr)
        Sdelta[sbase + (size_t)(m0 + rr) * HDIM + n] = f2bf(accD[i][j][rr] * lam[rr]);
    }
  }
}

// ---------------------------------------------------------------------------
// state_scan: elementwise-parallel over 4096 state slots; 256 blocks.
// ---------------------------------------------------------------------------
__global__ __launch_bounds__(256) void state_scan_kernel(
    const ushort* __restrict__ Sdelta, const float* __restrict__ Lam,
    ushort* __restrict__ Sprev) {
  const int bh = blockIdx.x >> 3;
  const int sl = blockIdx.x & 7;
  const int tid = threadIdx.x;
  const int e0 = sl * 512 + tid;
  float S0 = 0.f, S1 = 0.f;

  float pd0[2], pd1[2], pl0[2], pl1[2];
#pragma unroll
  for (int s = 0; s < 2; ++s) {
    size_t nb = (size_t)(bh * NCHUNK + s) * (HDIM * HDIM);
    size_t nl = (size_t)(bh * NCHUNK + s) * HDIM;
    pd0[s] = bf2f(Sdelta[nb + e0]);
    pd1[s] = bf2f(Sdelta[nb + e0 + 256]);
    pl0[s] = Lam[nl + (e0 >> 6)];
    pl1[s] = Lam[nl + ((e0 + 256) >> 6)];
  }

  for (int c = 0; c < NCHUNK; ++c) {
    const int s = c & 1;
    float cd0 = pd0[s], cd1 = pd1[s], cl0 = pl0[s], cl1 = pl1[s];
    if (c + 2 < NCHUNK) {
      size_t nb = (size_t)(bh * NCHUNK + c + 2) * (HDIM * HDIM);
      size_t nl = (size_t)(bh * NCHUNK + c + 2) * HDIM;
      pd0[s] = bf2f(Sdelta[nb + e0]);
      pd1[s] = bf2f(Sdelta[nb + e0 + 256]);
      pl0[s] = Lam[nl + (e0 >> 6)];
      pl1[s] = Lam[nl + ((e0 + 256) >> 6)];
    }
    size_t ob = (size_t)(bh * NCHUNK + c) * (HDIM * HDIM);
    Sprev[ob + e0] = f2bf(S0);
    Sprev[ob + e0 + 256] = f2bf(S1);
    S0 = fmaf(S0, cl0, cd0);
    S1 = fmaf(S1, cl1, cd1);
  }
}

// ---------------------------------------------------------------------------
// chunk_fused: att(bf16) = E . ( tril(QK^T) @ V~ + Q @ Sprev^T )
// ---------------------------------------------------------------------------
__global__ __launch_bounds__(256) void chunk_fused_kernel(
    const ushort* __restrict__ q, const ushort* __restrict__ k,
    const ushort* __restrict__ Vtg, const ushort* __restrict__ Eb,
    const ushort* __restrict__ Sprev, ushort* __restrict__ att) {
  const int bid = blockIdx.x;
  const int c = bid & 31, bh = bid >> 5;
  const int b = bh >> 4, h = bh & 15;
  const int tid = threadIdx.x;
  const int lane = tid & 63, wave = tid >> 6;
  const int fm = lane & 15, quad = lane >> 4;
  const int wm2 = (wave >> 1) * 32, wn2 = (wave & 1) * 32;

  __shared__ ushort sQ[64 * SP];
  __shared__ ushort sK[64 * SP];   // reused as sSp after scores
  __shared__ ushort sVt[64 * SP];
  __shared__ ushort sA[64 * SP];
  ushort* sSp = sK;

  const size_t base = ((size_t)b * LSEQ + (size_t)c * CHUNK) * HIDS + (size_t)h * HDIM;
  const size_t sbase = (size_t)(bh * NCHUNK + c) * (HDIM * HDIM);
  const int r = tid >> 2, c0 = (tid & 3) * 16;
  const size_t gb = base + (size_t)r * HIDS + c0;
  short8 sp0 = *(const short8*)(Sprev + sbase + (size_t)r * HDIM + c0);
  short8 sp1 = *(const short8*)(Sprev + sbase + (size_t)r * HDIM + c0 + 8);
  *(short8*)&sQ[r * SP + c0] = *(const short8*)(q + gb);
  *(short8*)&sQ[r * SP + c0 + 8] = *(const short8*)(q + gb + 8);
  *(short8*)&sK[r * SP + c0] = *(const short8*)(k + gb);
  *(short8*)&sK[r * SP + c0 + 8] = *(const short8*)(k + gb + 8);
  *(short8*)&sVt[r * SP + c0] = *(const short8*)(Vtg + sbase + (size_t)r * HDIM + c0);
  *(short8*)&sVt[r * SP + c0 + 8] =
      *(const short8*)(Vtg + sbase + (size_t)r * HDIM + c0 + 8);
  __syncthreads();

  // scores = tril(Q K^T)
  floatx4 accS[2][2];
#pragma unroll
  for (int i = 0; i < 2; ++i)
#pragma unroll
    for (int j = 0; j < 2; ++j) accS[i][j] = (floatx4){0.f, 0.f, 0.f, 0.f};
#pragma unroll
  for (int ks = 0; ks < 2; ++ks) {
    short8 a[2], bb[2];
#pragma unroll
    for (int i = 0; i < 2; ++i)
      a[i] = *(const short8*)&sQ[(wm2 + i * 16 + fm) * SP + ks * 32 + quad * 8];
#pragma unroll
    for (int j = 0; j < 2; ++j)
      bb[j] = *(const short8*)&sK[(wn2 + j * 16 + fm) * SP + ks * 32 + quad * 8];
#pragma unroll
    for (int i = 0; i < 2; ++i)
#pragma unroll
      for (int j = 0; j < 2; ++j)
        accS[i][j] = __builtin_amdgcn_mfma_f32_16x16x32_bf16(a[i], bb[j],
                                                             accS[i][j], 0, 0, 0);
  }
  __syncthreads();  // all waves done reading sK

  // write sA (tril) and sSp (into sK space)
#pragma unroll
  for (int i = 0; i < 2; ++i)
#pragma unroll
    for (int j = 0; j < 2; ++j) {
      const int t0 = wm2 + i * 16 + quad * 4;
      const int s = wn2 + j * 16 + fm;
#pragma unroll
      for (int rr = 0; rr < 4; ++rr) {
        float val = (s <= t0 + rr) ? accS[i][j][rr] : 0.f;
        sA[(t0 + rr) * SP + s] = f2bf(val);
      }
    }
  *(short8*)&sSp[r * SP + c0] = sp0;
  *(short8*)&sSp[r * SP + c0 + 8] = sp1;
  __syncthreads();

  // att = E . (sA @ V~  +  Q @ Sprev^T)
  floatx4 acc[2][2];
#pragma unroll
  for (int i = 0; i < 2; ++i)
#pragma unroll
    for (int j = 0; j < 2; ++j) acc[i][j] = (floatx4){0.f, 0.f, 0.f, 0.f};
#pragma unroll
  for (int ks = 0; ks < 2; ++ks) {
    short8 aa[2], aq[2], bv[2], bs[2];
#pragma unroll
    for (int i = 0; i < 2; ++i) {
      aa[i] = *(const short8*)&sA[(wm2 + i * 16 + fm) * SP + ks * 32 + quad * 8];
      aq[i] = *(const short8*)&sQ[(wm2 + i * 16 + fm) * SP + ks * 32 + quad * 8];
    }
#pragma unroll
    for (int j = 0; j < 2; ++j) {
      bv[j] = *(const short8*)&sVt[(wn2 + j * 16 + fm) * SP + ks * 32 + quad * 8];
      bs[j] = *(const short8*)&sSp[(wn2 + j * 16 + fm) * SP + ks * 32 + quad * 8];
    }
#pragma unroll
    for (int i = 0; i < 2; ++i)
#pragma unroll
      for (int j = 0; j < 2; ++j) {
        acc[i][j] = __builtin_amdgcn_mfma_f32_16x16x32_bf16(aa[i], bv[j],
                                                            acc[i][j], 0, 0, 0);
        acc[i][j] = __builtin_amdgcn_mfma_f32_16x16x32_bf16(aq[i], bs[j],
                                                            acc[i][j], 0, 0, 0);
      }
  }
#pragma unroll
  for (int i = 0; i < 2; ++i)
#pragma unroll
    for (int j = 0; j < 2; ++j) {
      const int m0 = wm2 + i * 16 + quad * 4;
      const int n = wn2 + j * 16 + fm;
#pragma unroll
      for (int rr = 0; rr < 4; ++rr) {
        const size_t idx = base + (size_t)(m0 + rr) * HIDS + n;
        att[idx] = f2bf(acc[i][j][rr] * bf2f(Eb[idx]));
      }
    }
}

// ---------------------------------------------------------------------------
// y = (LayerNorm(att) * gamma + beta) * silu(g), bf16 in/out.
// ---------------------------------------------------------------------------
__global__ __launch_bounds__(256) void ln_gate_kernel(const ushort* __restrict__ att,
                                                      const ushort* __restrict__ g,
                                                      const float* __restrict__ gamma,
                                                      const float* __restrict__ beta,
                                                      ushort* __restrict__ ybf) {
  const int row = blockIdx.x;
  const int tid = threadIdx.x;
  ushort4 au = *(const ushort4*)(att + (size_t)row * HIDS + tid * 4);
  float ax = bf2f(au.x), ay = bf2f(au.y), az = bf2f(au.z), aw = bf2f(au.w);
  float s = ax + ay + az + aw;
  float ss = ax * ax + ay * ay + az * az + aw * aw;
#pragma unroll
  for (int off = 32; off; off >>= 1) {
    s += __shfl_down(s, off);
    ss += __shfl_down(ss, off);
  }
  __shared__ float rs[4], rss[4];
  const int wid = tid >> 6;
  if ((tid & 63) == 0) { rs[wid] = s; rss[wid] = ss; }
  __syncthreads();
  const float mean = (rs[0] + rs[1] + rs[2] + rs[3]) * (1.f / HIDS);
  const float ex2 = (rss[0] + rss[1] + rss[2] + rss[3]) * (1.f / HIDS);
  const float rstd = rsqrtf(ex2 - mean * mean + 1e-5f);

  float4 ga = *(const float4*)(gamma + tid * 4);
  float4 be = *(const float4*)(beta + tid * 4);
  ushort4 gu = *(const ushort4*)(g + (size_t)row * HIDS + tid * 4);
  float gx = bf2f(gu.x), gy = bf2f(gu.y), gz = bf2f(gu.z), gw = bf2f(gu.w);
  float4 o;
  o.x = ((ax - mean) * rstd * ga.x + be.x) * (gx / (1.f + __expf(-gx)));
  o.y = ((ay - mean) * rstd * ga.y + be.y) * (gy / (1.f + __expf(-gy)));
  o.z = ((az - mean) * rstd * ga.z + be.z) * (gz / (1.f + __expf(-gz)));
  o.w = ((aw - mean) * rstd * ga.w + be.w) * (gw / (1.f + __expf(-gw)));
  ushort4 ob;
  ob.x = f2bf(o.x); ob.y = f2bf(o.y); ob.z = f2bf(o.z); ob.w = f2bf(o.w);
  *(ushort4*)(ybf + (size_t)row * HIDS + tid * 4) = ob;
}

// ---------------------------------------------------------------------------
extern "C" void kernel_launch(void* const* d_in, const int* in_sizes, int n_in,
                              void* d_out, int out_size, void* d_ws, size_t ws_size,
                              hipStream_t stream) {
  const float* x     = (const float*)d_in[0];
  const float* Wq    = (const float*)d_in[1];
  const float* Wk    = (const float*)d_in[2];
  const float* Wv    = (const float*)d_in[3];
  const float* Wg    = (const float*)d_in[4];
  const float* Wgk1  = (const float*)d_in[5];
  const float* Wgk2  = (const float*)d_in[6];
  const float* bgk2  = (const float*)d_in[7];
  const float* gamma = (const float*)d_in[8];
  const float* beta  = (const float*)d_in[9];
  const float* Wout  = (const float*)d_in[10];
  float* out = (float*)d_out;

  const size_t SZ = (size_t)NROW * HIDS;  // 4M elements
  float* ws = (float*)d_ws;
  float* Lamb = ws;                         // 64K floats
  ushort* attb   = (ushort*)(ws + 65536);   // bf16 4M
  ushort* Sdelta = attb + SZ;
  ushort* Sprevb = Sdelta + SZ;
  ushort* Vtgb   = Sprevb + SZ;             // V~^T tiles (bf16)
  ushort* Ebb    = Vtgb + SZ;               // e^Gamma (bf16)
  ushort* qbf = Ebb + SZ;                   // qb|kb|vb|gb contiguous
  ushort* kbf = qbf + SZ;
  ushort* vbf = kbf + SZ;
  ushort* gbf = vbf + SZ;
  ushort* xbf = gbf + SZ;
  ushort* Wtq = xbf + SZ;                   // Wtq|Wtk|Wtv|Wtg contiguous
  ushort* Wtk = Wtq + HIDS * HIDS;
  ushort* Wtv = Wtk + HIDS * HIDS;
  ushort* Wtg = Wtv + HIDS * HIDS;
  ushort* Wto = Wtg + HIDS * HIDS;
  float* xrb = (float*)(Wto + HIDS * HIDS);  // [4096][16] f32
  ushort* ybf = vbf;  // vbf dead after sdelta

  prep_kernel<<<4096 + 1280, 256, 0, stream>>>(
      x, xbf, Wq, Wk, Wv, Wg, Wout, Wtq, Wtk, Wtv, Wtg, Wto);

  xr_kernel<<<NROW / 16, 256, 0, stream>>>(xbf, Wgk1, xrb);

  // single 4096x4096x1024 GEMM over concatenated weights / outputs
  proj8_kernel<<<dim3(NROW / 256, NROW / 256), 512, 0, stream>>>(xbf, Wtq, qbf);

  sdelta_kernel<<<BBATCH * NHEAD * NCHUNK, 256, 0, stream>>>(
      kbf, vbf, xrb, Wgk2, bgk2, Sdelta, Lamb, Vtgb, Ebb);
  state_scan_kernel<<<256, 256, 0, stream>>>(Sdelta, Lamb, Sprevb);
  chunk_fused_kernel<<<BBATCH * NHEAD * NCHUNK, 256, 0, stream>>>(
      qbf, kbf, Vtgb, Ebb, Sprevb, attb);

  ln_gate_kernel<<<NROW, 256, 0, stream>>>(attb, gbf, gamma, beta, ybf);
  gemm_out_kernel<<<dim3(HIDS / 128, NROW / 128), 256, 0, stream>>>(ybf, Wto, out);
}

// Round 4
// 218.258 us; speedup vs baseline: 1.0209x; 1.0045x over previous
//
#include <hip/hip_runtime.h>
#include <cstdint>
#include <cstddef>

#define HIDS 1024
#define NHEAD 16
#define HDIM 64
#define LSEQ 2048
#define BBATCH 2
#define NROW (BBATCH * LSEQ)  // 4096
#define CHUNK 64
#define NCHUNK (LSEQ / CHUNK)  // 32
#define RANK 16

typedef short short8 __attribute__((ext_vector_type(8)));
typedef float floatx4 __attribute__((ext_vector_type(4)));

__device__ __forceinline__ ushort f2bf(float f) {
  uint32_t u = __float_as_uint(f);
  uint32_t r = (u + 0x7fffu + ((u >> 16) & 1u)) >> 16;  // RNE
  return (ushort)r;
}
__device__ __forceinline__ float bf2f(ushort u) {
  return __uint_as_float(((uint32_t)u) << 16);
}
// log_sigmoid(z)/16 via native exp/log (arg of log in (1,2] -> accurate)
__device__ __forceinline__ float logsig16(float z) {
  return (fminf(z, 0.f) - __logf(1.f + __expf(-fabsf(z)))) * (1.f / 16.f);
}

__device__ __forceinline__ void async_copy16(const void* g, void* l) {
  __builtin_amdgcn_global_load_lds(
      (const __attribute__((address_space(1))) void*)g,
      (__attribute__((address_space(3))) void*)l, 16, 0, 0);
}

// ---------------------------------------------------------------------------
// prep: fused cvt_x (blocks 0..4095) + transpose_w (4096..5375).
// ---------------------------------------------------------------------------
__global__ __launch_bounds__(256) void prep_kernel(
    const float* __restrict__ x, ushort* __restrict__ xbf,
    const float* __restrict__ W0, const float* __restrict__ W1,
    const float* __restrict__ W2, const float* __restrict__ W3,
    const float* __restrict__ W4, ushort* __restrict__ T0,
    ushort* __restrict__ T1, ushort* __restrict__ T2, ushort* __restrict__ T3,
    ushort* __restrict__ T4) {
  __shared__ float sbuf[64 * 65];
  const int bid = blockIdx.x;
  const int tid = threadIdx.x;

  if (bid < 4096) {  // ---- cvt_x
    const int i = bid * 256 + tid;
    float4 f = *(const float4*)(x + (size_t)i * 4);
    ushort4 o;
    o.x = f2bf(f.x); o.y = f2bf(f.y); o.z = f2bf(f.z); o.w = f2bf(f.w);
    *(ushort4*)(xbf + (size_t)i * 4) = o;
  } else {  // ---- transpose_w
    const int w = bid - 4096;
    const int z = w >> 8, rem = w & 255;
    const float* W = (z == 0) ? W0 : (z == 1) ? W1 : (z == 2) ? W2
                     : (z == 3) ? W3 : W4;
    ushort* T = (z == 0) ? T0 : (z == 1) ? T1 : (z == 2) ? T2
                : (z == 3) ? T3 : T4;
    const int k0 = (rem >> 4) * 64, n0 = (rem & 15) * 64;
    const int r = tid >> 2, c4 = (tid & 3) * 16;
#pragma unroll
    for (int i = 0; i < 4; ++i) {
      float4 f = *(const float4*)(W + (size_t)(k0 + r) * HIDS + n0 + c4 + i * 4);
      sbuf[r * 65 + c4 + i * 4 + 0] = f.x;
      sbuf[r * 65 + c4 + i * 4 + 1] = f.y;
      sbuf[r * 65 + c4 + i * 4 + 2] = f.z;
      sbuf[r * 65 + c4 + i * 4 + 3] = f.w;
    }
    __syncthreads();
    const int n = tid >> 2, kc = (tid & 3) * 16;
#pragma unroll
    for (int i = 0; i < 4; ++i) {
      int kk = kc + i * 4;
      ushort4 o;
      o.x = f2bf(sbuf[(kk + 0) * 65 + n]);
      o.y = f2bf(sbuf[(kk + 1) * 65 + n]);
      o.z = f2bf(sbuf[(kk + 2) * 65 + n]);
      o.w = f2bf(sbuf[(kk + 3) * 65 + n]);
      *(ushort4*)(T + (size_t)(n0 + n) * HIDS + k0 + kk) = o;
    }
  }
}

// ---------------------------------------------------------------------------
// xr = xbf @ Wgk1 : [4096,1024] x [1024,16] -> f32 [4096,16]. 16 rows/block.
// ---------------------------------------------------------------------------
#define XSTR 1040
__global__ __launch_bounds__(256) void xr_kernel(
    const ushort* __restrict__ xbf, const float* __restrict__ Wgk1,
    float* __restrict__ xr) {
  __shared__ float sW1[HIDS * RANK];       // 64 KB, layout [k][16]
  __shared__ ushort sX[16 * XSTR];         // 16 rows, padded
  const int tid = threadIdx.x;
  const int r0 = blockIdx.x * 16;
#pragma unroll
  for (int j = 0; j < 16; ++j) {
    const int idx = j * 1024 + tid * 4;
    *(float4*)&sW1[idx] = *(const float4*)(Wgk1 + idx);
  }
#pragma unroll
  for (int j = 0; j < 8; ++j) {
    const int e = j * 2048 + tid * 8;
    const int rr = e >> 10, kk = e & 1023;
    *(short8*)&sX[rr * XSTR + kk] =
        *(const short8*)(xbf + (size_t)(r0 + rr) * HIDS + kk);
  }
  __syncthreads();
  const int r = tid >> 4, n = tid & 15;
  float acc = 0.f;
  for (int k8 = 0; k8 < HIDS; k8 += 8) {
    short8 xv = *(const short8*)&sX[r * XSTR + k8];
#pragma unroll
    for (int i = 0; i < 8; ++i)
      acc = fmaf(bf2f((ushort)xv[i]), sW1[(k8 + i) * RANK + n], acc);
  }
  xr[(size_t)(r0 + r) * RANK + n] = acc;
}

// ---------------------------------------------------------------------------
// proj8: ONE 4096(M) x 4096(N) x 1024(K) bf16 GEMM over the concatenated
// weights [Wtq|Wtk|Wtv|Wtg], 256x256 tile, BK=64, 8 waves (2Mx4N), 128KB LDS
// double-buffer, 4-phase K-step, counted vmcnt (T4), setprio (T5), and the
// template's explicit { barrier; lgkmcnt(0); sched_barrier(0) } fence before
// each MFMA cluster (prevents per-MFMA serialized lgkm waits).
// ---------------------------------------------------------------------------
#define POFF(buf, mat, half) ((((buf)*2 + (mat)) * 2 + (half)) * 8192)

__global__ __launch_bounds__(512, 2) void proj8_kernel(
    const ushort* __restrict__ xbf, const ushort* __restrict__ Wcat,
    ushort* __restrict__ Cq) {
  __shared__ ushort sT[2 * 2 * 2 * 8192];  // [buf][mat][half][256*32] = 128 KB
  const int tid = threadIdx.x;
  const int lane = tid & 63, wid = tid >> 6;
  const int fm = lane & 15, quad = lane >> 4;
  const int sq8 = ((quad + (fm >> 1)) & 3) * 8;  // read slot (XOR chunk swz)
  const int wr = wid >> 2, wc = wid & 3;         // 2Mx4N wave grid
  const int bm = blockIdx.y * 256, bn = blockIdx.x * 256;

  // staging: thread t covers slots t and t+512 of each 256x32 half-buffer
  const int srow = tid >> 2;
  const int qch = ((((tid & 3) - ((tid >> 3) & 3)) & 3)) * 8;  // src k-chunk
  const ushort* Ab = xbf + (size_t)(bm + srow) * HIDS + qch;
  const ushort* Bb = Wcat + (size_t)(bn + srow) * HIDS + qch;

#define STAGE_A(ktn, nb)                                                      \
  do {                                                                        \
    const int kc_ = (ktn) * 64;                                               \
    async_copy16(Ab + kc_, (char*)&sT[POFF(nb, 0, 0)] + tid * 16);            \
    async_copy16(Ab + (size_t)128 * HIDS + kc_,                               \
                 (char*)&sT[POFF(nb, 0, 0)] + tid * 16 + 8192);               \
    async_copy16(Ab + kc_ + 32, (char*)&sT[POFF(nb, 0, 1)] + tid * 16);       \
    async_copy16(Ab + (size_t)128 * HIDS + kc_ + 32,                          \
                 (char*)&sT[POFF(nb, 0, 1)] + tid * 16 + 8192);               \
  } while (0)
#define STAGE_B0(ktn, nb)                                                     \
  do {                                                                        \
    const int kc_ = (ktn) * 64;                                               \
    async_copy16(Bb + kc_, (char*)&sT[POFF(nb, 1, 0)] + tid * 16);            \
    async_copy16(Bb + (size_t)128 * HIDS + kc_,                               \
                 (char*)&sT[POFF(nb, 1, 0)] + tid * 16 + 8192);               \
  } while (0)
#define STAGE_B1(ktn, nb)                                                     \
  do {                                                                        \
    const int kc_ = (ktn) * 64;                                               \
    async_copy16(Bb + kc_ + 32, (char*)&sT[POFF(nb, 1, 1)] + tid * 16);       \
    async_copy16(Bb + (size_t)128 * HIDS + kc_ + 32,                          \
                 (char*)&sT[POFF(nb, 1, 1)] + tid * 16 + 8192);               \
  } while (0)
#define BARRIER()                        \
  do {                                   \
    asm volatile("" ::: "memory");       \
    __builtin_amdgcn_s_barrier();        \
    asm volatile("" ::: "memory");       \
  } while (0)
// pre-MFMA fence: barrier, then drain LDS reads, then pin scheduling so the
// MFMA cluster issues with zero interior lgkm waits (rule #18 / m201).
#define PHASE_WAIT()                                     \
  do {                                                   \
    asm volatile("" ::: "memory");                       \
    __builtin_amdgcn_s_barrier();                        \
    asm volatile("s_waitcnt lgkmcnt(0)" ::: "memory");   \
    __builtin_amdgcn_sched_barrier(0);                   \
  } while (0)

  const int aoff = (wr * 128 + fm) * 32 + sq8;  // + m*512, half selects buffer
  const int boff = (wc * 64 + fm) * 32 + sq8;   // + n*512

  floatx4 acc[8][4];
#pragma unroll
  for (int i = 0; i < 8; ++i)
#pragma unroll
    for (int j = 0; j < 4; ++j) acc[i][j] = (floatx4){0.f, 0.f, 0.f, 0.f};

  // prologue: stage K-tile 0 into buf 0 (8 loads)
  STAGE_A(0, 0);
  STAGE_B0(0, 0);
  STAGE_B1(0, 0);

  for (int kt = 0; kt < 16; ++kt) {
    const int cur = kt & 1, nxt = cur ^ 1;
    // top: issue next A-stage, counted wait for THIS tile's 8 loads
    if (kt < 15) {
      STAGE_A(kt + 1, nxt);
      asm volatile("s_waitcnt vmcnt(4)" ::: "memory");
    } else {
      asm volatile("s_waitcnt vmcnt(0)" ::: "memory");
    }
    BARRIER();

    short8 af[4][2], bfr[4][2];
    // ---- ph0: read A m=0..3 + B n=0..1, issue B-h0 stage, MFMA Q(0,0)
#pragma unroll
    for (int m = 0; m < 4; ++m) {
      af[m][0] = *(const short8*)&sT[POFF(cur, 0, 0) + aoff + m * 512];
      af[m][1] = *(const short8*)&sT[POFF(cur, 0, 1) + aoff + m * 512];
    }
#pragma unroll
    for (int n = 0; n < 2; ++n) {
      bfr[n][0] = *(const short8*)&sT[POFF(cur, 1, 0) + boff + n * 512];
      bfr[n][1] = *(const short8*)&sT[POFF(cur, 1, 1) + boff + n * 512];
    }
    if (kt < 15) STAGE_B0(kt + 1, nxt);
    PHASE_WAIT();
    __builtin_amdgcn_s_setprio(1);
#pragma unroll
    for (int m = 0; m < 4; ++m)
#pragma unroll
      for (int n = 0; n < 2; ++n) {
        acc[m][n] = __builtin_amdgcn_mfma_f32_16x16x32_bf16(af[m][0], bfr[n][0],
                                                            acc[m][n], 0, 0, 0);
        acc[m][n] = __builtin_amdgcn_mfma_f32_16x16x32_bf16(af[m][1], bfr[n][1],
                                                            acc[m][n], 0, 0, 0);
      }
    __builtin_amdgcn_s_setprio(0);
    BARRIER();

    // ---- ph1: read B n=2..3, issue B-h1 stage, MFMA Q(0,1)
#pragma unroll
    for (int n = 2; n < 4; ++n) {
      bfr[n][0] = *(const short8*)&sT[POFF(cur, 1, 0) + boff + n * 512];
      bfr[n][1] = *(const short8*)&sT[POFF(cur, 1, 1) + boff + n * 512];
    }
    if (kt < 15) STAGE_B1(kt + 1, nxt);
    PHASE_WAIT();
    __builtin_amdgcn_s_setprio(1);
#pragma unroll
    for (int m = 0; m < 4; ++m)
#pragma unroll
      for (int n = 2; n < 4; ++n) {
        acc[m][n] = __builtin_amdgcn_mfma_f32_16x16x32_bf16(af[m][0], bfr[n][0],
                                                            acc[m][n], 0, 0, 0);
        acc[m][n] = __builtin_amdgcn_mfma_f32_16x16x32_bf16(af[m][1], bfr[n][1],
                                                            acc[m][n], 0, 0, 0);
      }
    __builtin_amdgcn_s_setprio(0);
    BARRIER();

    // ---- ph2: read A m=4..7, MFMA Q(1,0)
#pragma unroll
    for (int m = 0; m < 4; ++m) {
      af[m][0] = *(const short8*)&sT[POFF(cur, 0, 0) + aoff + (m + 4) * 512];
      af[m][1] = *(const short8*)&sT[POFF(cur, 0, 1) + aoff + (m + 4) * 512];
    }
    PHASE_WAIT();
    __builtin_amdgcn_s_setprio(1);
#pragma unroll
    for (int m = 0; m < 4; ++m)
#pragma unroll
      for (int n = 0; n < 2; ++n) {
        acc[m + 4][n] = __builtin_amdgcn_mfma_f32_16x16x32_bf16(
            af[m][0], bfr[n][0], acc[m + 4][n], 0, 0, 0);
        acc[m + 4][n] = __builtin_amdgcn_mfma_f32_16x16x32_bf16(
            af[m][1], bfr[n][1], acc[m + 4][n], 0, 0, 0);
      }
    __builtin_amdgcn_s_setprio(0);
    BARRIER();

    // ---- ph3: MFMA Q(1,1) (all frags in regs)
    __builtin_amdgcn_s_setprio(1);
#pragma unroll
    for (int m = 0; m < 4; ++m)
#pragma unroll
      for (int n = 2; n < 4; ++n) {
        acc[m + 4][n] = __builtin_amdgcn_mfma_f32_16x16x32_bf16(
            af[m][0], bfr[n][0], acc[m + 4][n], 0, 0, 0);
        acc[m + 4][n] = __builtin_amdgcn_mfma_f32_16x16x32_bf16(
            af[m][1], bfr[n][1], acc[m + 4][n], 0, 0, 0);
      }
    __builtin_amdgcn_s_setprio(0);
    // end-of-iteration barrier: all waves done reading buf[cur] before anyone
    // issues the next iteration's stage into it
    BARRIER();
  }

  // epilogue: scatter to the z = col>>10 projection buffer (contiguous)
  const int cb = bn + wc * 64;
  const int z = cb >> 10;
  const int ccol = cb & 1023;
  ushort* C = Cq + (size_t)z * ((size_t)NROW * HIDS);
#pragma unroll
  for (int m = 0; m < 8; ++m) {
    const int row0 = bm + wr * 128 + m * 16 + quad * 4;
#pragma unroll
    for (int n = 0; n < 4; ++n) {
      const int col = ccol + n * 16 + fm;
#pragma unroll
      for (int rr = 0; rr < 4; ++rr)
        C[(size_t)(row0 + rr) * HIDS + col] = f2bf(acc[m][n][rr]);
    }
  }
#undef STAGE_A
#undef STAGE_B0
#undef STAGE_B1
#undef BARRIER
#undef PHASE_WAIT
}

// ---------------------------------------------------------------------------
// Output GEMM: 128x128 tile, BK=64, swizzled staging, fp32 out.
// ---------------------------------------------------------------------------
__global__ __launch_bounds__(256) void gemm_out_kernel(
    const ushort* __restrict__ A, const ushort* __restrict__ Bt,
    float* __restrict__ C) {
  __shared__ ushort As[2][128 * 32];
  __shared__ ushort Bs[2][128 * 32];
  const int tid = threadIdx.x;
  const int wave = tid >> 6, lane = tid & 63;
  const int wm = (wave >> 1) * 64, wn = (wave & 1) * 64;
  const int fm = lane & 15, quad = lane >> 4;
  const int sq8 = ((quad + (fm >> 1)) & 3) * 8;
  const int bm = blockIdx.y * 128, bn = blockIdx.x * 128;
  const int lrow = tid >> 2;
  const int lk8 = ((((tid & 3) - ((tid >> 3) & 3)) & 3)) * 8;
  const ushort* Ag = A + (size_t)(bm + lrow) * HIDS + lk8;
  const ushort* Bg = Bt + (size_t)(bn + lrow) * HIDS + lk8;
  char* A0 = (char*)&As[0][0] + tid * 16;
  char* A1 = (char*)&As[1][0] + tid * 16;
  char* B0 = (char*)&Bs[0][0] + tid * 16;
  char* B1 = (char*)&Bs[1][0] + tid * 16;

  floatx4 acc[4][4];
#pragma unroll
  for (int i = 0; i < 4; ++i)
#pragma unroll
    for (int j = 0; j < 4; ++j) acc[i][j] = (floatx4){0.f, 0.f, 0.f, 0.f};

  for (int k0 = 0; k0 < HIDS; k0 += 64) {
    __syncthreads();
    async_copy16(Ag + k0, A0);
    async_copy16(Ag + (size_t)64 * HIDS + k0, A0 + 4096);
    async_copy16(Ag + k0 + 32, A1);
    async_copy16(Ag + (size_t)64 * HIDS + k0 + 32, A1 + 4096);
    async_copy16(Bg + k0, B0);
    async_copy16(Bg + (size_t)64 * HIDS + k0, B0 + 4096);
    async_copy16(Bg + k0 + 32, B1);
    async_copy16(Bg + (size_t)64 * HIDS + k0 + 32, B1 + 4096);
    __syncthreads();

#pragma unroll
    for (int ks = 0; ks < 2; ++ks) {
      short8 af[4], bfr[4];
#pragma unroll
      for (int i = 0; i < 4; ++i)
        af[i] = *(const short8*)&As[ks][(wm + i * 16 + fm) * 32 + sq8];
#pragma unroll
      for (int j = 0; j < 4; ++j)
        bfr[j] = *(const short8*)&Bs[ks][(wn + j * 16 + fm) * 32 + sq8];
#pragma unroll
      for (int i = 0; i < 4; ++i)
#pragma unroll
        for (int j = 0; j < 4; ++j)
          acc[i][j] = __builtin_amdgcn_mfma_f32_16x16x32_bf16(af[i], bfr[j],
                                                              acc[i][j], 0, 0, 0);
    }
  }

#pragma unroll
  for (int i = 0; i < 4; ++i) {
    const int row0 = bm + wm + i * 16 + quad * 4;
#pragma unroll
    for (int j = 0; j < 4; ++j) {
      const int col = bn + wn + j * 16 + fm;
#pragma unroll
      for (int r = 0; r < 4; ++r)
        C[(size_t)(row0 + r) * HIDS + col] = acc[i][j][r];
    }
  }
}

#define SP 72   // ushort stride for bf16 LDS tiles (16B-aligned rows)
#define SGS 68  // float stride for Gamma tile

// ---------------------------------------------------------------------------
// sdelta: z = xr @ Wgk2 + b computed inline (rank-16); Gamma=cumsum(logsig16);
// Vt~=(e^-G V)^T; Sdelta = Lam.(V~^T K); exports Vtg (V~^T) and Eb = e^Gamma.
// ---------------------------------------------------------------------------
__global__ __launch_bounds__(256) void sdelta_kernel(
    const ushort* __restrict__ k, const ushort* __restrict__ v,
    const float* __restrict__ xr, const float* __restrict__ Wgk2,
    const float* __restrict__ bgk2, ushort* __restrict__ Sdelta,
    float* __restrict__ Lam, ushort* __restrict__ Vtg,
    ushort* __restrict__ Eb) {
  const int bid = blockIdx.x;
  const int c = bid & 31, bh = bid >> 5;
  const int b = bh >> 4, h = bh & 15;
  const int tid = threadIdx.x;
  const int lane = tid & 63, wave = tid >> 6;
  const int fm = lane & 15, quad = lane >> 4;
  const int wm2 = (wave >> 1) * 32, wn2 = (wave & 1) * 32;

  __shared__ ushort sKt[64 * SP];
  __shared__ ushort sVt[64 * SP];
  __shared__ float sG[64 * SGS];
  __shared__ float sW2[RANK * 64];

  const size_t base = ((size_t)b * LSEQ + (size_t)c * CHUNK) * HIDS + (size_t)h * HDIM;
  const int r = tid >> 2, c0 = (tid & 3) * 16;
  const size_t gb = base + (size_t)r * HIDS + c0;

  // stage Wgk2 head-slice [16][64] f32
  {
    const int wr = tid >> 4, wc = (tid & 15) * 4;
    *(float4*)&sW2[wr * 64 + wc] =
        *(const float4*)(Wgk2 + (size_t)wr * HIDS + h * HDIM + wc);
  }
  // xr row for this thread's time-step (4 lanes per row share; L2-hot)
  float xrr[16];
  {
    const size_t xrow = ((size_t)b * LSEQ + (size_t)c * CHUNK + r) * RANK;
#pragma unroll
    for (int m = 0; m < 4; ++m)
      *(float4*)&xrr[m * 4] = *(const float4*)(xr + xrow + m * 4);
  }
  float bias[16];
#pragma unroll
  for (int m = 0; m < 4; ++m)
    *(float4*)&bias[m * 4] = *(const float4*)(bgk2 + h * HDIM + c0 + m * 4);
  __syncthreads();

  // z = xr . W2slice + bias -> gk = logsig16(z)
#pragma unroll
  for (int i = 0; i < 16; ++i) {
    float z = bias[i];
#pragma unroll
    for (int t2 = 0; t2 < 16; ++t2)
      z = fmaf(xrr[t2], sW2[t2 * 64 + c0 + i], z);
    sG[r * SGS + c0 + i] = logsig16(z);
  }
  // pair partition (K, V) — issue loads to overlap with cumsum
  const int pr = (tid >> 3) * 2, pc = (tid & 7) * 8;
  const size_t pb = base + (size_t)pr * HIDS + pc;
  short8 ka = *(const short8*)(k + pb);
  short8 kb2 = *(const short8*)(k + pb + HIDS);
  short8 va = *(const short8*)(v + pb);
  short8 vb2 = *(const short8*)(v + pb + HIDS);
  __syncthreads();

  // inclusive cumsum along t per v column
  const int vcol = tid & 63, qtr = tid >> 6;
  {
    float run = 0.f;
#pragma unroll
    for (int i = 0; i < 16; ++i) {
      int idx = (qtr * 16 + i) * SGS + vcol;
      run += sG[idx];
      sG[idx] = run;
    }
  }
  __syncthreads();
  float pre = 0.f;
  for (int j = 0; j < qtr; ++j) pre += sG[(j * 16 + 15) * SGS + vcol];
  __syncthreads();
#pragma unroll
  for (int i = 0; i < 16; ++i) sG[(qtr * 16 + i) * SGS + vcol] += pre;
  __syncthreads();

  // E = e^Gamma -> global (coalesced 32B/thread)
  {
    ushort eb[16];
#pragma unroll
    for (int i = 0; i < 16; ++i) eb[i] = f2bf(__expf(sG[r * SGS + c0 + i]));
    *(short8*)(Eb + gb) = *(short8*)&eb[0];
    *(short8*)(Eb + gb + 8) = *(short8*)&eb[8];
  }

  // transposed tiles (ushort2 writes)
#pragma unroll
  for (int i = 0; i < 8; ++i) {
    ushort2 kk;
    kk.x = (ushort)ka[i];
    kk.y = (ushort)kb2[i];
    *(ushort2*)&sKt[(pc + i) * SP + pr] = kk;
    float Ga = sG[pr * SGS + pc + i];
    float Gb2 = sG[(pr + 1) * SGS + pc + i];
    ushort2 vv;
    vv.x = f2bf(bf2f((ushort)va[i]) * __expf(-Ga));
    vv.y = f2bf(bf2f((ushort)vb2[i]) * __expf(-Gb2));
    *(ushort2*)&sVt[(pc + i) * SP + pr] = vv;
  }
  __syncthreads();

  // export V~^T tile (coalesced 32B/thread)
  {
    const size_t vb3 = (size_t)(bh * NCHUNK + c) * (HDIM * HDIM);
    *(short8*)(Vtg + vb3 + (size_t)r * HDIM + c0) = *(const short8*)&sVt[r * SP + c0];
    *(short8*)(Vtg + vb3 + (size_t)r * HDIM + c0 + 8) =
        *(const short8*)&sVt[r * SP + c0 + 8];
  }

  if (tid < 64)
    Lam[(size_t)(bh * NCHUNK + c) * HDIM + tid] = __expf(sG[63 * SGS + tid]);

  floatx4 accD[2][2];
#pragma unroll
  for (int i = 0; i < 2; ++i)
#pragma unroll
    for (int j = 0; j < 2; ++j) accD[i][j] = (floatx4){0.f, 0.f, 0.f, 0.f};
#pragma unroll
  for (int ks = 0; ks < 2; ++ks) {
    short8 av[2], bk[2];
#pragma unroll
    for (int i = 0; i < 2; ++i)
      av[i] = *(const short8*)&sVt[(wm2 + i * 16 + fm) * SP + ks * 32 + quad * 8];
#pragma unroll
    for (int j = 0; j < 2; ++j)
      bk[j] = *(const short8*)&sKt[(wn2 + j * 16 + fm) * SP + ks * 32 + quad * 8];
#pragma unroll
    for (int i = 0; i < 2; ++i)
#pragma unroll
      for (int j = 0; j < 2; ++j)
        accD[i][j] = __builtin_amdgcn_mfma_f32_16x16x32_bf16(av[i], bk[j],
                                                             accD[i][j], 0, 0, 0);
  }
  const size_t sbase = (size_t)(bh * NCHUNK + c) * (HDIM * HDIM);
#pragma unroll
  for (int i = 0; i < 2; ++i) {
    const int m0 = wm2 + i * 16 + quad * 4;
    float lam[4];
#pragma unroll
    for (int rr = 0; rr < 4; ++rr) lam[rr] = __expf(sG[63 * SGS + m0 + rr]);
#pragma unroll
    for (int j = 0; j < 2; ++j) {
      const int n = wn2 + j * 16 + fm;
#pragma unroll
      for (int rr = 0; rr < 4; ++rr)
        Sdelta[sbase + (size_t)(m0 + rr) * HDIM + n] = f2bf(accD[i][j][rr] * lam[rr]);
    }
  }
}

// ---------------------------------------------------------------------------
// state_scan: elementwise-parallel over 4096 state slots; 256 blocks.
// ---------------------------------------------------------------------------
__global__ __launch_bounds__(256) void state_scan_kernel(
    const ushort* __restrict__ Sdelta, const float* __restrict__ Lam,
    ushort* __restrict__ Sprev) {
  const int bh = blockIdx.x >> 3;
  const int sl = blockIdx.x & 7;
  const int tid = threadIdx.x;
  const int e0 = sl * 512 + tid;
  float S0 = 0.f, S1 = 0.f;

  float pd0[2], pd1[2], pl0[2], pl1[2];
#pragma unroll
  for (int s = 0; s < 2; ++s) {
    size_t nb = (size_t)(bh * NCHUNK + s) * (HDIM * HDIM);
    size_t nl = (size_t)(bh * NCHUNK + s) * HDIM;
    pd0[s] = bf2f(Sdelta[nb + e0]);
    pd1[s] = bf2f(Sdelta[nb + e0 + 256]);
    pl0[s] = Lam[nl + (e0 >> 6)];
    pl1[s] = Lam[nl + ((e0 + 256) >> 6)];
  }

  for (int c = 0; c < NCHUNK; ++c) {
    const int s = c & 1;
    float cd0 = pd0[s], cd1 = pd1[s], cl0 = pl0[s], cl1 = pl1[s];
    if (c + 2 < NCHUNK) {
      size_t nb = (size_t)(bh * NCHUNK + c + 2) * (HDIM * HDIM);
      size_t nl = (size_t)(bh * NCHUNK + c + 2) * HDIM;
      pd0[s] = bf2f(Sdelta[nb + e0]);
      pd1[s] = bf2f(Sdelta[nb + e0 + 256]);
      pl0[s] = Lam[nl + (e0 >> 6)];
      pl1[s] = Lam[nl + ((e0 + 256) >> 6)];
    }
    size_t ob = (size_t)(bh * NCHUNK + c) * (HDIM * HDIM);
    Sprev[ob + e0] = f2bf(S0);
    Sprev[ob + e0 + 256] = f2bf(S1);
    S0 = fmaf(S0, cl0, cd0);
    S1 = fmaf(S1, cl1, cd1);
  }
}

// ---------------------------------------------------------------------------
// chunk_fused: att(bf16) = E . ( tril(QK^T) @ V~ + Q @ Sprev^T )
// ---------------------------------------------------------------------------
__global__ __launch_bounds__(256) void chunk_fused_kernel(
    const ushort* __restrict__ q, const ushort* __restrict__ k,
    const ushort* __restrict__ Vtg, const ushort* __restrict__ Eb,
    const ushort* __restrict__ Sprev, ushort* __restrict__ att) {
  const int bid = blockIdx.x;
  const int c = bid & 31, bh = bid >> 5;
  const int b = bh >> 4, h = bh & 15;
  const int tid = threadIdx.x;
  const int lane = tid & 63, wave = tid >> 6;
  const int fm = lane & 15, quad = lane >> 4;
  const int wm2 = (wave >> 1) * 32, wn2 = (wave & 1) * 32;

  __shared__ ushort sQ[64 * SP];
  __shared__ ushort sK[64 * SP];   // reused as sSp after scores
  __shared__ ushort sVt[64 * SP];
  __shared__ ushort sA[64 * SP];
  ushort* sSp = sK;

  const size_t base = ((size_t)b * LSEQ + (size_t)c * CHUNK) * HIDS + (size_t)h * HDIM;
  const size_t sbase = (size_t)(bh * NCHUNK + c) * (HDIM * HDIM);
  const int r = tid >> 2, c0 = (tid & 3) * 16;
  const size_t gb = base + (size_t)r * HIDS + c0;
  short8 sp0 = *(const short8*)(Sprev + sbase + (size_t)r * HDIM + c0);
  short8 sp1 = *(const short8*)(Sprev + sbase + (size_t)r * HDIM + c0 + 8);
  *(short8*)&sQ[r * SP + c0] = *(const short8*)(q + gb);
  *(short8*)&sQ[r * SP + c0 + 8] = *(const short8*)(q + gb + 8);
  *(short8*)&sK[r * SP + c0] = *(const short8*)(k + gb);
  *(short8*)&sK[r * SP + c0 + 8] = *(const short8*)(k + gb + 8);
  *(short8*)&sVt[r * SP + c0] = *(const short8*)(Vtg + sbase + (size_t)r * HDIM + c0);
  *(short8*)&sVt[r * SP + c0 + 8] =
      *(const short8*)(Vtg + sbase + (size_t)r * HDIM + c0 + 8);
  __syncthreads();

  // scores = tril(Q K^T)
  floatx4 accS[2][2];
#pragma unroll
  for (int i = 0; i < 2; ++i)
#pragma unroll
    for (int j = 0; j < 2; ++j) accS[i][j] = (floatx4){0.f, 0.f, 0.f, 0.f};
#pragma unroll
  for (int ks = 0; ks < 2; ++ks) {
    short8 a[2], bb[2];
#pragma unroll
    for (int i = 0; i < 2; ++i)
      a[i] = *(const short8*)&sQ[(wm2 + i * 16 + fm) * SP + ks * 32 + quad * 8];
#pragma unroll
    for (int j = 0; j < 2; ++j)
      bb[j] = *(const short8*)&sK[(wn2 + j * 16 + fm) * SP + ks * 32 + quad * 8];
#pragma unroll
    for (int i = 0; i < 2; ++i)
#pragma unroll
      for (int j = 0; j < 2; ++j)
        accS[i][j] = __builtin_amdgcn_mfma_f32_16x16x32_bf16(a[i], bb[j],
                                                             accS[i][j], 0, 0, 0);
  }
  __syncthreads();  // all waves done reading sK

  // write sA (tril) and sSp (into sK space)
#pragma unroll
  for (int i = 0; i < 2; ++i)
#pragma unroll
    for (int j = 0; j < 2; ++j) {
      const int t0 = wm2 + i * 16 + quad * 4;
      const int s = wn2 + j * 16 + fm;
#pragma unroll
      for (int rr = 0; rr < 4; ++rr) {
        float val = (s <= t0 + rr) ? accS[i][j][rr] : 0.f;
        sA[(t0 + rr) * SP + s] = f2bf(val);
      }
    }
  *(short8*)&sSp[r * SP + c0] = sp0;
  *(short8*)&sSp[r * SP + c0 + 8] = sp1;
  __syncthreads();

  // att = E . (sA @ V~  +  Q @ Sprev^T)
  floatx4 acc[2][2];
#pragma unroll
  for (int i = 0; i < 2; ++i)
#pragma unroll
    for (int j = 0; j < 2; ++j) acc[i][j] = (floatx4){0.f, 0.f, 0.f, 0.f};
#pragma unroll
  for (int ks = 0; ks < 2; ++ks) {
    short8 aa[2], aq[2], bv[2], bs[2];
#pragma unroll
    for (int i = 0; i < 2; ++i) {
      aa[i] = *(const short8*)&sA[(wm2 + i * 16 + fm) * SP + ks * 32 + quad * 8];
      aq[i] = *(const short8*)&sQ[(wm2 + i * 16 + fm) * SP + ks * 32 + quad * 8];
    }
#pragma unroll
    for (int j = 0; j < 2; ++j) {
      bv[j] = *(const short8*)&sVt[(wn2 + j * 16 + fm) * SP + ks * 32 + quad * 8];
      bs[j] = *(const short8*)&sSp[(wn2 + j * 16 + fm) * SP + ks * 32 + quad * 8];
    }
#pragma unroll
    for (int i = 0; i < 2; ++i)
#pragma unroll
      for (int j = 0; j < 2; ++j) {
        acc[i][j] = __builtin_amdgcn_mfma_f32_16x16x32_bf16(aa[i], bv[j],
                                                            acc[i][j], 0, 0, 0);
        acc[i][j] = __builtin_amdgcn_mfma_f32_16x16x32_bf16(aq[i], bs[j],
                                                            acc[i][j], 0, 0, 0);
      }
  }
#pragma unroll
  for (int i = 0; i < 2; ++i)
#pragma unroll
    for (int j = 0; j < 2; ++j) {
      const int m0 = wm2 + i * 16 + quad * 4;
      const int n = wn2 + j * 16 + fm;
#pragma unroll
      for (int rr = 0; rr < 4; ++rr) {
        const size_t idx = base + (size_t)(m0 + rr) * HIDS + n;
        att[idx] = f2bf(acc[i][j][rr] * bf2f(Eb[idx]));
      }
    }
}

// ---------------------------------------------------------------------------
// y = (LayerNorm(att) * gamma + beta) * silu(g), bf16 in/out.
// ---------------------------------------------------------------------------
__global__ __launch_bounds__(256) void ln_gate_kernel(const ushort* __restrict__ att,
                                                      const ushort* __restrict__ g,
                                                      const float* __restrict__ gamma,
                                                      const float* __restrict__ beta,
                                                      ushort* __restrict__ ybf) {
  const int row = blockIdx.x;
  const int tid = threadIdx.x;
  ushort4 au = *(const ushort4*)(att + (size_t)row * HIDS + tid * 4);
  float ax = bf2f(au.x), ay = bf2f(au.y), az = bf2f(au.z), aw = bf2f(au.w);
  float s = ax + ay + az + aw;
  float ss = ax * ax + ay * ay + az * az + aw * aw;
#pragma unroll
  for (int off = 32; off; off >>= 1) {
    s += __shfl_down(s, off);
    ss += __shfl_down(ss, off);
  }
  __shared__ float rs[4], rss[4];
  const int wid = tid >> 6;
  if ((tid & 63) == 0) { rs[wid] = s; rss[wid] = ss; }
  __syncthreads();
  const float mean = (rs[0] + rs[1] + rs[2] + rs[3]) * (1.f / HIDS);
  const float ex2 = (rss[0] + rss[1] + rss[2] + rss[3]) * (1.f / HIDS);
  const float rstd = rsqrtf(ex2 - mean * mean + 1e-5f);

  float4 ga = *(const float4*)(gamma + tid * 4);
  float4 be = *(const float4*)(beta + tid * 4);
  ushort4 gu = *(const ushort4*)(g + (size_t)row * HIDS + tid * 4);
  float gx = bf2f(gu.x), gy = bf2f(gu.y), gz = bf2f(gu.z), gw = bf2f(gu.w);
  float4 o;
  o.x = ((ax - mean) * rstd * ga.x + be.x) * (gx / (1.f + __expf(-gx)));
  o.y = ((ay - mean) * rstd * ga.y + be.y) * (gy / (1.f + __expf(-gy)));
  o.z = ((az - mean) * rstd * ga.z + be.z) * (gz / (1.f + __expf(-gz)));
  o.w = ((aw - mean) * rstd * ga.w + be.w) * (gw / (1.f + __expf(-gw)));
  ushort4 ob;
  ob.x = f2bf(o.x); ob.y = f2bf(o.y); ob.z = f2bf(o.z); ob.w = f2bf(o.w);
  *(ushort4*)(ybf + (size_t)row * HIDS + tid * 4) = ob;
}

// ---------------------------------------------------------------------------
extern "C" void kernel_launch(void* const* d_in, const int* in_sizes, int n_in,
                              void* d_out, int out_size, void* d_ws, size_t ws_size,
                              hipStream_t stream) {
  const float* x     = (const float*)d_in[0];
  const float* Wq    = (const float*)d_in[1];
  const float* Wk    = (const float*)d_in[2];
  const float* Wv    = (const float*)d_in[3];
  const float* Wg    = (const float*)d_in[4];
  const float* Wgk1  = (const float*)d_in[5];
  const float* Wgk2  = (const float*)d_in[6];
  const float* bgk2  = (const float*)d_in[7];
  const float* gamma = (const float*)d_in[8];
  const float* beta  = (const float*)d_in[9];
  const float* Wout  = (const float*)d_in[10];
  float* out = (float*)d_out;

  const size_t SZ = (size_t)NROW * HIDS;  // 4M elements
  float* ws = (float*)d_ws;
  float* Lamb = ws;                         // 64K floats
  ushort* attb   = (ushort*)(ws + 65536);   // bf16 4M
  ushort* Sdelta = attb + SZ;
  ushort* Sprevb = Sdelta + SZ;
  ushort* Vtgb   = Sprevb + SZ;             // V~^T tiles (bf16)
  ushort* Ebb    = Vtgb + SZ;               // e^Gamma (bf16)
  ushort* qbf = Ebb + SZ;                   // qb|kb|vb|gb contiguous
  ushort* kbf = qbf + SZ;
  ushort* vbf = kbf + SZ;
  ushort* gbf = vbf + SZ;
  ushort* xbf = gbf + SZ;
  ushort* Wtq = xbf + SZ;                   // Wtq|Wtk|Wtv|Wtg contiguous
  ushort* Wtk = Wtq + HIDS * HIDS;
  ushort* Wtv = Wtk + HIDS * HIDS;
  ushort* Wtg = Wtv + HIDS * HIDS;
  ushort* Wto = Wtg + HIDS * HIDS;
  float* xrb = (float*)(Wto + HIDS * HIDS);  // [4096][16] f32
  ushort* ybf = vbf;  // vbf dead after sdelta

  prep_kernel<<<4096 + 1280, 256, 0, stream>>>(
      x, xbf, Wq, Wk, Wv, Wg, Wout, Wtq, Wtk, Wtv, Wtg, Wto);

  xr_kernel<<<NROW / 16, 256, 0, stream>>>(xbf, Wgk1, xrb);

  // single 4096x4096x1024 GEMM over concatenated weights / outputs
  proj8_kernel<<<dim3(NROW / 256, NROW / 256), 512, 0, stream>>>(xbf, Wtq, qbf);

  sdelta_kernel<<<BBATCH * NHEAD * NCHUNK, 256, 0, stream>>>(
      kbf, vbf, xrb, Wgk2, bgk2, Sdelta, Lamb, Vtgb, Ebb);
  state_scan_kernel<<<256, 256, 0, stream>>>(Sdelta, Lamb, Sprevb);
  chunk_fused_kernel<<<BBATCH * NHEAD * NCHUNK, 256, 0, stream>>>(
      qbf, kbf, Vtgb, Ebb, Sprevb, attb);

  ln_gate_kernel<<<NROW, 256, 0, stream>>>(attb, gbf, gamma, beta, ybf);
  gemm_out_kernel<<<dim3(HIDS / 128, NROW / 128), 256, 0, stream>>>(ybf, Wto, out);
}

// Round 5
// 216.200 us; speedup vs baseline: 1.0307x; 1.0095x over previous
//
#include <hip/hip_runtime.h>
#include <cstdint>
#include <cstddef>

#define HIDS 1024
#define NHEAD 16
#define HDIM 64
#define LSEQ 2048
#define BBATCH 2
#define NROW (BBATCH * LSEQ)  // 4096
#define CHUNK 64
#define NCHUNK (LSEQ / CHUNK)  // 32
#define RANK 16

typedef short short8 __attribute__((ext_vector_type(8)));
typedef float floatx4 __attribute__((ext_vector_type(4)));

__device__ __forceinline__ ushort f2bf(float f) {
  uint32_t u = __float_as_uint(f);
  uint32_t r = (u + 0x7fffu + ((u >> 16) & 1u)) >> 16;  // RNE
  return (ushort)r;
}
__device__ __forceinline__ float bf2f(ushort u) {
  return __uint_as_float(((uint32_t)u) << 16);
}
// log_sigmoid(z)/16 via native exp/log (arg of log in (1,2] -> accurate)
__device__ __forceinline__ float logsig16(float z) {
  return (fminf(z, 0.f) - __logf(1.f + __expf(-fabsf(z)))) * (1.f / 16.f);
}

__device__ __forceinline__ void async_copy16(const void* g, void* l) {
  __builtin_amdgcn_global_load_lds(
      (const __attribute__((address_space(1))) void*)g,
      (__attribute__((address_space(3))) void*)l, 16, 0, 0);
}

// ---------------------------------------------------------------------------
// prep: fused cvt_x (blocks 0..4095) + transpose_w (4096..5375).
// ---------------------------------------------------------------------------
__global__ __launch_bounds__(256) void prep_kernel(
    const float* __restrict__ x, ushort* __restrict__ xbf,
    const float* __restrict__ W0, const float* __restrict__ W1,
    const float* __restrict__ W2, const float* __restrict__ W3,
    const float* __restrict__ W4, ushort* __restrict__ T0,
    ushort* __restrict__ T1, ushort* __restrict__ T2, ushort* __restrict__ T3,
    ushort* __restrict__ T4) {
  __shared__ float sbuf[64 * 65];
  const int bid = blockIdx.x;
  const int tid = threadIdx.x;

  if (bid < 4096) {  // ---- cvt_x
    const int i = bid * 256 + tid;
    float4 f = *(const float4*)(x + (size_t)i * 4);
    ushort4 o;
    o.x = f2bf(f.x); o.y = f2bf(f.y); o.z = f2bf(f.z); o.w = f2bf(f.w);
    *(ushort4*)(xbf + (size_t)i * 4) = o;
  } else {  // ---- transpose_w
    const int w = bid - 4096;
    const int z = w >> 8, rem = w & 255;
    const float* W = (z == 0) ? W0 : (z == 1) ? W1 : (z == 2) ? W2
                     : (z == 3) ? W3 : W4;
    ushort* T = (z == 0) ? T0 : (z == 1) ? T1 : (z == 2) ? T2
                : (z == 3) ? T3 : T4;
    const int k0 = (rem >> 4) * 64, n0 = (rem & 15) * 64;
    const int r = tid >> 2, c4 = (tid & 3) * 16;
#pragma unroll
    for (int i = 0; i < 4; ++i) {
      float4 f = *(const float4*)(W + (size_t)(k0 + r) * HIDS + n0 + c4 + i * 4);
      sbuf[r * 65 + c4 + i * 4 + 0] = f.x;
      sbuf[r * 65 + c4 + i * 4 + 1] = f.y;
      sbuf[r * 65 + c4 + i * 4 + 2] = f.z;
      sbuf[r * 65 + c4 + i * 4 + 3] = f.w;
    }
    __syncthreads();
    const int n = tid >> 2, kc = (tid & 3) * 16;
#pragma unroll
    for (int i = 0; i < 4; ++i) {
      int kk = kc + i * 4;
      ushort4 o;
      o.x = f2bf(sbuf[(kk + 0) * 65 + n]);
      o.y = f2bf(sbuf[(kk + 1) * 65 + n]);
      o.z = f2bf(sbuf[(kk + 2) * 65 + n]);
      o.w = f2bf(sbuf[(kk + 3) * 65 + n]);
      *(ushort4*)(T + (size_t)(n0 + n) * HIDS + k0 + kk) = o;
    }
  }
}

// ---------------------------------------------------------------------------
// xr = xbf @ Wgk1 : [4096,1024] x [1024,16] -> f32 [4096,16]. 16 rows/block.
// ---------------------------------------------------------------------------
#define XSTR 1040
__global__ __launch_bounds__(256) void xr_kernel(
    const ushort* __restrict__ xbf, const float* __restrict__ Wgk1,
    float* __restrict__ xr) {
  __shared__ float sW1[HIDS * RANK];       // 64 KB, layout [k][16]
  __shared__ ushort sX[16 * XSTR];         // 16 rows, padded
  const int tid = threadIdx.x;
  const int r0 = blockIdx.x * 16;
#pragma unroll
  for (int j = 0; j < 16; ++j) {
    const int idx = j * 1024 + tid * 4;
    *(float4*)&sW1[idx] = *(const float4*)(Wgk1 + idx);
  }
#pragma unroll
  for (int j = 0; j < 8; ++j) {
    const int e = j * 2048 + tid * 8;
    const int rr = e >> 10, kk = e & 1023;
    *(short8*)&sX[rr * XSTR + kk] =
        *(const short8*)(xbf + (size_t)(r0 + rr) * HIDS + kk);
  }
  __syncthreads();
  const int r = tid >> 4, n = tid & 15;
  float acc = 0.f;
  for (int k8 = 0; k8 < HIDS; k8 += 8) {
    short8 xv = *(const short8*)&sX[r * XSTR + k8];
#pragma unroll
    for (int i = 0; i < 8; ++i)
      acc = fmaf(bf2f((ushort)xv[i]), sW1[(k8 + i) * RANK + n], acc);
  }
  xr[(size_t)(r0 + r) * RANK + n] = acc;
}

// ---------------------------------------------------------------------------
// proj8: ONE 4096(M) x 4096(N) x 1024(K) bf16 GEMM over the concatenated
// weights [Wtq|Wtk|Wtv|Wtg], 256x256 tile, BK=64, 8 waves (2Mx4N), 128KB LDS
// double-buffer. Flat per-kt pipeline: 1 barrier/kt, counted vmcnt, register
// subtile rotation (aA/bA -> Q00; bB -> Q01; aB -> Q10/Q11) so each read
// group issues under the previous quadrant's in-flight MFMAs and overwrites
// only registers whose consumers already drained (no WAR serialization).
// ---------------------------------------------------------------------------
#define POFF(buf, mat, half) ((((buf)*2 + (mat)) * 2 + (half)) * 8192)

__global__ __launch_bounds__(512, 2) void proj8_kernel(
    const ushort* __restrict__ xbf, const ushort* __restrict__ Wcat,
    ushort* __restrict__ Cq) {
  __shared__ ushort sT[2 * 2 * 2 * 8192];  // [buf][mat][half][256*32] = 128 KB
  const int tid = threadIdx.x;
  const int lane = tid & 63, wid = tid >> 6;
  const int fm = lane & 15, quad = lane >> 4;
  const int sq8 = ((quad + (fm >> 1)) & 3) * 8;  // read slot (XOR chunk swz)
  const int wr = wid >> 2, wc = wid & 3;         // 2Mx4N wave grid
  const int bm = blockIdx.y * 256, bn = blockIdx.x * 256;

  // staging: thread t covers slots t and t+512 of each 256x32 half-buffer
  const int srow = tid >> 2;
  const int qch = ((((tid & 3) - ((tid >> 3) & 3)) & 3)) * 8;  // src k-chunk
  const ushort* Ab = xbf + (size_t)(bm + srow) * HIDS + qch;
  const ushort* Bb = Wcat + (size_t)(bn + srow) * HIDS + qch;

#define STAGE_A(ktn, nb)                                                      \
  do {                                                                        \
    const int kc_ = (ktn) * 64;                                               \
    async_copy16(Ab + kc_, (char*)&sT[POFF(nb, 0, 0)] + tid * 16);            \
    async_copy16(Ab + (size_t)128 * HIDS + kc_,                               \
                 (char*)&sT[POFF(nb, 0, 0)] + tid * 16 + 8192);               \
    async_copy16(Ab + kc_ + 32, (char*)&sT[POFF(nb, 0, 1)] + tid * 16);       \
    async_copy16(Ab + (size_t)128 * HIDS + kc_ + 32,                          \
                 (char*)&sT[POFF(nb, 0, 1)] + tid * 16 + 8192);               \
  } while (0)
#define STAGE_B0(ktn, nb)                                                     \
  do {                                                                        \
    const int kc_ = (ktn) * 64;                                               \
    async_copy16(Bb + kc_, (char*)&sT[POFF(nb, 1, 0)] + tid * 16);            \
    async_copy16(Bb + (size_t)128 * HIDS + kc_,                               \
                 (char*)&sT[POFF(nb, 1, 0)] + tid * 16 + 8192);               \
  } while (0)
#define STAGE_B1(ktn, nb)                                                     \
  do {                                                                        \
    const int kc_ = (ktn) * 64;                                               \
    async_copy16(Bb + kc_ + 32, (char*)&sT[POFF(nb, 1, 1)] + tid * 16);       \
    async_copy16(Bb + (size_t)128 * HIDS + kc_ + 32,                          \
                 (char*)&sT[POFF(nb, 1, 1)] + tid * 16 + 8192);               \
  } while (0)
#define SB() __builtin_amdgcn_sched_barrier(0)
#define LGKM0()                                          \
  do {                                                   \
    SB();                                                \
    asm volatile("s_waitcnt lgkmcnt(0)" ::: "memory");   \
    SB();                                                \
  } while (0)

  const int aoff = (wr * 128 + fm) * 32 + sq8;  // + m*512, half selects buffer
  const int boff = (wc * 64 + fm) * 32 + sq8;   // + n*512

  floatx4 acc[8][4];
#pragma unroll
  for (int i = 0; i < 8; ++i)
#pragma unroll
    for (int j = 0; j < 4; ++j) acc[i][j] = (floatx4){0.f, 0.f, 0.f, 0.f};

  // prologue: stage K-tile 0 into buf 0 (8 loads)
  STAGE_A(0, 0);
  STAGE_B0(0, 0);
  STAGE_B1(0, 0);

  short8 aA[4][2], aB[4][2], bA[2][2], bB[2][2];

  for (int kt = 0; kt < 16; ++kt) {
    const int cur = kt & 1, nxt = cur ^ 1;
    // top: issue next A-stage; counted wait: all of tile kt landed,
    // A(kt+1) still in flight.
    if (kt < 15) {
      STAGE_A(kt + 1, nxt);
      asm volatile("s_waitcnt vmcnt(4)" ::: "memory");
    } else {
      asm volatile("s_waitcnt vmcnt(0)" ::: "memory");
    }
    SB();
    __builtin_amdgcn_s_barrier();
    SB();

    // R0: frags for Q00 (aA m=0..3, bA n=0..1). Issues under the in-pipe
    // Q10/Q11 MFMAs of the previous kt.
#pragma unroll
    for (int m = 0; m < 4; ++m) {
      aA[m][0] = *(const short8*)&sT[POFF(cur, 0, 0) + aoff + m * 512];
      aA[m][1] = *(const short8*)&sT[POFF(cur, 0, 1) + aoff + m * 512];
    }
#pragma unroll
    for (int n = 0; n < 2; ++n) {
      bA[n][0] = *(const short8*)&sT[POFF(cur, 1, 0) + boff + n * 512];
      bA[n][1] = *(const short8*)&sT[POFF(cur, 1, 1) + boff + n * 512];
    }
    LGKM0();
    __builtin_amdgcn_s_setprio(1);
#pragma unroll
    for (int m = 0; m < 4; ++m)
#pragma unroll
      for (int n = 0; n < 2; ++n) {
        acc[m][n] = __builtin_amdgcn_mfma_f32_16x16x32_bf16(aA[m][0], bA[n][0],
                                                            acc[m][n], 0, 0, 0);
        acc[m][n] = __builtin_amdgcn_mfma_f32_16x16x32_bf16(aA[m][1], bA[n][1],
                                                            acc[m][n], 0, 0, 0);
      }
    __builtin_amdgcn_s_setprio(0);

    // R1: bB (n=2..3) under Q00's in-pipe MFMAs; stage B-half0 of kt+1.
#pragma unroll
    for (int j = 0; j < 2; ++j) {
      bB[j][0] = *(const short8*)&sT[POFF(cur, 1, 0) + boff + (j + 2) * 512];
      bB[j][1] = *(const short8*)&sT[POFF(cur, 1, 1) + boff + (j + 2) * 512];
    }
    if (kt < 15) STAGE_B0(kt + 1, nxt);
    LGKM0();
    __builtin_amdgcn_s_setprio(1);
#pragma unroll
    for (int m = 0; m < 4; ++m)
#pragma unroll
      for (int n = 2; n < 4; ++n) {
        acc[m][n] = __builtin_amdgcn_mfma_f32_16x16x32_bf16(
            aA[m][0], bB[n - 2][0], acc[m][n], 0, 0, 0);
        acc[m][n] = __builtin_amdgcn_mfma_f32_16x16x32_bf16(
            aA[m][1], bB[n - 2][1], acc[m][n], 0, 0, 0);
      }
    __builtin_amdgcn_s_setprio(0);

    // R2: aB (m=4..7) under Q01's in-pipe MFMAs; stage B-half1 of kt+1.
#pragma unroll
    for (int m = 0; m < 4; ++m) {
      aB[m][0] = *(const short8*)&sT[POFF(cur, 0, 0) + aoff + (m + 4) * 512];
      aB[m][1] = *(const short8*)&sT[POFF(cur, 0, 1) + aoff + (m + 4) * 512];
    }
    if (kt < 15) STAGE_B1(kt + 1, nxt);
    LGKM0();
    __builtin_amdgcn_s_setprio(1);
#pragma unroll
    for (int m = 0; m < 4; ++m)
#pragma unroll
      for (int n = 0; n < 2; ++n) {
        acc[m + 4][n] = __builtin_amdgcn_mfma_f32_16x16x32_bf16(
            aB[m][0], bA[n][0], acc[m + 4][n], 0, 0, 0);
        acc[m + 4][n] = __builtin_amdgcn_mfma_f32_16x16x32_bf16(
            aB[m][1], bA[n][1], acc[m + 4][n], 0, 0, 0);
      }
#pragma unroll
    for (int m = 0; m < 4; ++m)
#pragma unroll
      for (int n = 2; n < 4; ++n) {
        acc[m + 4][n] = __builtin_amdgcn_mfma_f32_16x16x32_bf16(
            aB[m][0], bB[n - 2][0], acc[m + 4][n], 0, 0, 0);
        acc[m + 4][n] = __builtin_amdgcn_mfma_f32_16x16x32_bf16(
            aB[m][1], bB[n - 2][1], acc[m + 4][n], 0, 0, 0);
      }
    __builtin_amdgcn_s_setprio(0);
    // Q10/Q11's 32 in-pipe MFMAs cover the next kt's top (stage+vmcnt+
    // barrier+R0). The next top barrier is the only sync needed: every wave
    // drained its buf[cur] reads at its own LGKM0 before reaching it.
  }

  // epilogue: scatter to the z = col>>10 projection buffer (contiguous)
  const int cb = bn + wc * 64;
  const int z = cb >> 10;
  const int ccol = cb & 1023;
  ushort* C = Cq + (size_t)z * ((size_t)NROW * HIDS);
#pragma unroll
  for (int m = 0; m < 8; ++m) {
    const int row0 = bm + wr * 128 + m * 16 + quad * 4;
#pragma unroll
    for (int n = 0; n < 4; ++n) {
      const int col = ccol + n * 16 + fm;
#pragma unroll
      for (int rr = 0; rr < 4; ++rr)
        C[(size_t)(row0 + rr) * HIDS + col] = f2bf(acc[m][n][rr]);
    }
  }
#undef STAGE_A
#undef STAGE_B0
#undef STAGE_B1
#undef SB
#undef LGKM0
}

// ---------------------------------------------------------------------------
// Output GEMM: 128x128 tile, BK=64, swizzled staging, fp32 out.
// ---------------------------------------------------------------------------
__global__ __launch_bounds__(256) void gemm_out_kernel(
    const ushort* __restrict__ A, const ushort* __restrict__ Bt,
    float* __restrict__ C) {
  __shared__ ushort As[2][128 * 32];
  __shared__ ushort Bs[2][128 * 32];
  const int tid = threadIdx.x;
  const int wave = tid >> 6, lane = tid & 63;
  const int wm = (wave >> 1) * 64, wn = (wave & 1) * 64;
  const int fm = lane & 15, quad = lane >> 4;
  const int sq8 = ((quad + (fm >> 1)) & 3) * 8;
  const int bm = blockIdx.y * 128, bn = blockIdx.x * 128;
  const int lrow = tid >> 2;
  const int lk8 = ((((tid & 3) - ((tid >> 3) & 3)) & 3)) * 8;
  const ushort* Ag = A + (size_t)(bm + lrow) * HIDS + lk8;
  const ushort* Bg = Bt + (size_t)(bn + lrow) * HIDS + lk8;
  char* A0 = (char*)&As[0][0] + tid * 16;
  char* A1 = (char*)&As[1][0] + tid * 16;
  char* B0 = (char*)&Bs[0][0] + tid * 16;
  char* B1 = (char*)&Bs[1][0] + tid * 16;

  floatx4 acc[4][4];
#pragma unroll
  for (int i = 0; i < 4; ++i)
#pragma unroll
    for (int j = 0; j < 4; ++j) acc[i][j] = (floatx4){0.f, 0.f, 0.f, 0.f};

  for (int k0 = 0; k0 < HIDS; k0 += 64) {
    __syncthreads();
    async_copy16(Ag + k0, A0);
    async_copy16(Ag + (size_t)64 * HIDS + k0, A0 + 4096);
    async_copy16(Ag + k0 + 32, A1);
    async_copy16(Ag + (size_t)64 * HIDS + k0 + 32, A1 + 4096);
    async_copy16(Bg + k0, B0);
    async_copy16(Bg + (size_t)64 * HIDS + k0, B0 + 4096);
    async_copy16(Bg + k0 + 32, B1);
    async_copy16(Bg + (size_t)64 * HIDS + k0 + 32, B1 + 4096);
    __syncthreads();

#pragma unroll
    for (int ks = 0; ks < 2; ++ks) {
      short8 af[4], bfr[4];
#pragma unroll
      for (int i = 0; i < 4; ++i)
        af[i] = *(const short8*)&As[ks][(wm + i * 16 + fm) * 32 + sq8];
#pragma unroll
      for (int j = 0; j < 4; ++j)
        bfr[j] = *(const short8*)&Bs[ks][(wn + j * 16 + fm) * 32 + sq8];
#pragma unroll
      for (int i = 0; i < 4; ++i)
#pragma unroll
        for (int j = 0; j < 4; ++j)
          acc[i][j] = __builtin_amdgcn_mfma_f32_16x16x32_bf16(af[i], bfr[j],
                                                              acc[i][j], 0, 0, 0);
    }
  }

#pragma unroll
  for (int i = 0; i < 4; ++i) {
    const int row0 = bm + wm + i * 16 + quad * 4;
#pragma unroll
    for (int j = 0; j < 4; ++j) {
      const int col = bn + wn + j * 16 + fm;
#pragma unroll
      for (int r = 0; r < 4; ++r)
        C[(size_t)(row0 + r) * HIDS + col] = acc[i][j][r];
    }
  }
}

#define SP 72   // ushort stride for bf16 LDS tiles (16B-aligned rows)
#define SGS 68  // float stride for Gamma tile

// ---------------------------------------------------------------------------
// sdelta: z = xr @ Wgk2 + b computed inline (rank-16); Gamma=cumsum(logsig16);
// Vt~=(e^-G V)^T; Sdelta = Lam.(V~^T K); exports Vtg (V~^T) and Eb = e^Gamma.
// ---------------------------------------------------------------------------
__global__ __launch_bounds__(256) void sdelta_kernel(
    const ushort* __restrict__ k, const ushort* __restrict__ v,
    const float* __restrict__ xr, const float* __restrict__ Wgk2,
    const float* __restrict__ bgk2, ushort* __restrict__ Sdelta,
    float* __restrict__ Lam, ushort* __restrict__ Vtg,
    ushort* __restrict__ Eb) {
  const int bid = blockIdx.x;
  const int c = bid & 31, bh = bid >> 5;
  const int b = bh >> 4, h = bh & 15;
  const int tid = threadIdx.x;
  const int lane = tid & 63, wave = tid >> 6;
  const int fm = lane & 15, quad = lane >> 4;
  const int wm2 = (wave >> 1) * 32, wn2 = (wave & 1) * 32;

  __shared__ ushort sKt[64 * SP];
  __shared__ ushort sVt[64 * SP];
  __shared__ float sG[64 * SGS];
  __shared__ float sW2[RANK * 64];

  const size_t base = ((size_t)b * LSEQ + (size_t)c * CHUNK) * HIDS + (size_t)h * HDIM;
  const int r = tid >> 2, c0 = (tid & 3) * 16;
  const size_t gb = base + (size_t)r * HIDS + c0;

  // stage Wgk2 head-slice [16][64] f32
  {
    const int wr = tid >> 4, wc = (tid & 15) * 4;
    *(float4*)&sW2[wr * 64 + wc] =
        *(const float4*)(Wgk2 + (size_t)wr * HIDS + h * HDIM + wc);
  }
  // xr row for this thread's time-step (4 lanes per row share; L2-hot)
  float xrr[16];
  {
    const size_t xrow = ((size_t)b * LSEQ + (size_t)c * CHUNK + r) * RANK;
#pragma unroll
    for (int m = 0; m < 4; ++m)
      *(float4*)&xrr[m * 4] = *(const float4*)(xr + xrow + m * 4);
  }
  float bias[16];
#pragma unroll
  for (int m = 0; m < 4; ++m)
    *(float4*)&bias[m * 4] = *(const float4*)(bgk2 + h * HDIM + c0 + m * 4);
  __syncthreads();

  // z = xr . W2slice + bias -> gk = logsig16(z)
#pragma unroll
  for (int i = 0; i < 16; ++i) {
    float z = bias[i];
#pragma unroll
    for (int t2 = 0; t2 < 16; ++t2)
      z = fmaf(xrr[t2], sW2[t2 * 64 + c0 + i], z);
    sG[r * SGS + c0 + i] = logsig16(z);
  }
  // pair partition (K, V) — issue loads to overlap with cumsum
  const int pr = (tid >> 3) * 2, pc = (tid & 7) * 8;
  const size_t pb = base + (size_t)pr * HIDS + pc;
  short8 ka = *(const short8*)(k + pb);
  short8 kb2 = *(const short8*)(k + pb + HIDS);
  short8 va = *(const short8*)(v + pb);
  short8 vb2 = *(const short8*)(v + pb + HIDS);
  __syncthreads();

  // inclusive cumsum along t per v column
  const int vcol = tid & 63, qtr = tid >> 6;
  {
    float run = 0.f;
#pragma unroll
    for (int i = 0; i < 16; ++i) {
      int idx = (qtr * 16 + i) * SGS + vcol;
      run += sG[idx];
      sG[idx] = run;
    }
  }
  __syncthreads();
  float pre = 0.f;
  for (int j = 0; j < qtr; ++j) pre += sG[(j * 16 + 15) * SGS + vcol];
  __syncthreads();
#pragma unroll
  for (int i = 0; i < 16; ++i) sG[(qtr * 16 + i) * SGS + vcol] += pre;
  __syncthreads();

  // E = e^Gamma -> global (coalesced 32B/thread)
  {
    ushort eb[16];
#pragma unroll
    for (int i = 0; i < 16; ++i) eb[i] = f2bf(__expf(sG[r * SGS + c0 + i]));
    *(short8*)(Eb + gb) = *(short8*)&eb[0];
    *(short8*)(Eb + gb + 8) = *(short8*)&eb[8];
  }

  // transposed tiles (ushort2 writes)
#pragma unroll
  for (int i = 0; i < 8; ++i) {
    ushort2 kk;
    kk.x = (ushort)ka[i];
    kk.y = (ushort)kb2[i];
    *(ushort2*)&sKt[(pc + i) * SP + pr] = kk;
    float Ga = sG[pr * SGS + pc + i];
    float Gb2 = sG[(pr + 1) * SGS + pc + i];
    ushort2 vv;
    vv.x = f2bf(bf2f((ushort)va[i]) * __expf(-Ga));
    vv.y = f2bf(bf2f((ushort)vb2[i]) * __expf(-Gb2));
    *(ushort2*)&sVt[(pc + i) * SP + pr] = vv;
  }
  __syncthreads();

  // export V~^T tile (coalesced 32B/thread)
  {
    const size_t vb3 = (size_t)(bh * NCHUNK + c) * (HDIM * HDIM);
    *(short8*)(Vtg + vb3 + (size_t)r * HDIM + c0) = *(const short8*)&sVt[r * SP + c0];
    *(short8*)(Vtg + vb3 + (size_t)r * HDIM + c0 + 8) =
        *(const short8*)&sVt[r * SP + c0 + 8];
  }

  if (tid < 64)
    Lam[(size_t)(bh * NCHUNK + c) * HDIM + tid] = __expf(sG[63 * SGS + tid]);

  floatx4 accD[2][2];
#pragma unroll
  for (int i = 0; i < 2; ++i)
#pragma unroll
    for (int j = 0; j < 2; ++j) accD[i][j] = (floatx4){0.f, 0.f, 0.f, 0.f};
#pragma unroll
  for (int ks = 0; ks < 2; ++ks) {
    short8 av[2], bk[2];
#pragma unroll
    for (int i = 0; i < 2; ++i)
      av[i] = *(const short8*)&sVt[(wm2 + i * 16 + fm) * SP + ks * 32 + quad * 8];
#pragma unroll
    for (int j = 0; j < 2; ++j)
      bk[j] = *(const short8*)&sKt[(wn2 + j * 16 + fm) * SP + ks * 32 + quad * 8];
#pragma unroll
    for (int i = 0; i < 2; ++i)
#pragma unroll
      for (int j = 0; j < 2; ++j)
        accD[i][j] = __builtin_amdgcn_mfma_f32_16x16x32_bf16(av[i], bk[j],
                                                             accD[i][j], 0, 0, 0);
  }
  const size_t sbase = (size_t)(bh * NCHUNK + c) * (HDIM * HDIM);
#pragma unroll
  for (int i = 0; i < 2; ++i) {
    const int m0 = wm2 + i * 16 + quad * 4;
    float lam[4];
#pragma unroll
    for (int rr = 0; rr < 4; ++rr) lam[rr] = __expf(sG[63 * SGS + m0 + rr]);
#pragma unroll
    for (int j = 0; j < 2; ++j) {
      const int n = wn2 + j * 16 + fm;
#pragma unroll
      for (int rr = 0; rr < 4; ++rr)
        Sdelta[sbase + (size_t)(m0 + rr) * HDIM + n] = f2bf(accD[i][j][rr] * lam[rr]);
    }
  }
}

// ---------------------------------------------------------------------------
// state_scan: elementwise-parallel over 4096 state slots; 256 blocks.
// ---------------------------------------------------------------------------
__global__ __launch_bounds__(256) void state_scan_kernel(
    const ushort* __restrict__ Sdelta, const float* __restrict__ Lam,
    ushort* __restrict__ Sprev) {
  const int bh = blockIdx.x >> 3;
  const int sl = blockIdx.x & 7;
  const int tid = threadIdx.x;
  const int e0 = sl * 512 + tid;
  float S0 = 0.f, S1 = 0.f;

  float pd0[2], pd1[2], pl0[2], pl1[2];
#pragma unroll
  for (int s = 0; s < 2; ++s) {
    size_t nb = (size_t)(bh * NCHUNK + s) * (HDIM * HDIM);
    size_t nl = (size_t)(bh * NCHUNK + s) * HDIM;
    pd0[s] = bf2f(Sdelta[nb + e0]);
    pd1[s] = bf2f(Sdelta[nb + e0 + 256]);
    pl0[s] = Lam[nl + (e0 >> 6)];
    pl1[s] = Lam[nl + ((e0 + 256) >> 6)];
  }

  for (int c = 0; c < NCHUNK; ++c) {
    const int s = c & 1;
    float cd0 = pd0[s], cd1 = pd1[s], cl0 = pl0[s], cl1 = pl1[s];
    if (c + 2 < NCHUNK) {
      size_t nb = (size_t)(bh * NCHUNK + c + 2) * (HDIM * HDIM);
      size_t nl = (size_t)(bh * NCHUNK + c + 2) * HDIM;
      pd0[s] = bf2f(Sdelta[nb + e0]);
      pd1[s] = bf2f(Sdelta[nb + e0 + 256]);
      pl0[s] = Lam[nl + (e0 >> 6)];
      pl1[s] = Lam[nl + ((e0 + 256) >> 6)];
    }
    size_t ob = (size_t)(bh * NCHUNK + c) * (HDIM * HDIM);
    Sprev[ob + e0] = f2bf(S0);
    Sprev[ob + e0 + 256] = f2bf(S1);
    S0 = fmaf(S0, cl0, cd0);
    S1 = fmaf(S1, cl1, cd1);
  }
}

// ---------------------------------------------------------------------------
// chunk_fused: att(bf16) = E . ( tril(QK^T) @ V~ + Q @ Sprev^T )
// ---------------------------------------------------------------------------
__global__ __launch_bounds__(256) void chunk_fused_kernel(
    const ushort* __restrict__ q, const ushort* __restrict__ k,
    const ushort* __restrict__ Vtg, const ushort* __restrict__ Eb,
    const ushort* __restrict__ Sprev, ushort* __restrict__ att) {
  const int bid = blockIdx.x;
  const int c = bid & 31, bh = bid >> 5;
  const int b = bh >> 4, h = bh & 15;
  const int tid = threadIdx.x;
  const int lane = tid & 63, wave = tid >> 6;
  const int fm = lane & 15, quad = lane >> 4;
  const int wm2 = (wave >> 1) * 32, wn2 = (wave & 1) * 32;

  __shared__ ushort sQ[64 * SP];
  __shared__ ushort sK[64 * SP];   // reused as sSp after scores
  __shared__ ushort sVt[64 * SP];
  __shared__ ushort sA[64 * SP];
  ushort* sSp = sK;

  const size_t base = ((size_t)b * LSEQ + (size_t)c * CHUNK) * HIDS + (size_t)h * HDIM;
  const size_t sbase = (size_t)(bh * NCHUNK + c) * (HDIM * HDIM);
  const int r = tid >> 2, c0 = (tid & 3) * 16;
  const size_t gb = base + (size_t)r * HIDS + c0;
  short8 sp0 = *(const short8*)(Sprev + sbase + (size_t)r * HDIM + c0);
  short8 sp1 = *(const short8*)(Sprev + sbase + (size_t)r * HDIM + c0 + 8);
  *(short8*)&sQ[r * SP + c0] = *(const short8*)(q + gb);
  *(short8*)&sQ[r * SP + c0 + 8] = *(const short8*)(q + gb + 8);
  *(short8*)&sK[r * SP + c0] = *(const short8*)(k + gb);
  *(short8*)&sK[r * SP + c0 + 8] = *(const short8*)(k + gb + 8);
  *(short8*)&sVt[r * SP + c0] = *(const short8*)(Vtg + sbase + (size_t)r * HDIM + c0);
  *(short8*)&sVt[r * SP + c0 + 8] =
      *(const short8*)(Vtg + sbase + (size_t)r * HDIM + c0 + 8);
  __syncthreads();

  // scores = tril(Q K^T)
  floatx4 accS[2][2];
#pragma unroll
  for (int i = 0; i < 2; ++i)
#pragma unroll
    for (int j = 0; j < 2; ++j) accS[i][j] = (floatx4){0.f, 0.f, 0.f, 0.f};
#pragma unroll
  for (int ks = 0; ks < 2; ++ks) {
    short8 a[2], bb[2];
#pragma unroll
    for (int i = 0; i < 2; ++i)
      a[i] = *(const short8*)&sQ[(wm2 + i * 16 + fm) * SP + ks * 32 + quad * 8];
#pragma unroll
    for (int j = 0; j < 2; ++j)
      bb[j] = *(const short8*)&sK[(wn2 + j * 16 + fm) * SP + ks * 32 + quad * 8];
#pragma unroll
    for (int i = 0; i < 2; ++i)
#pragma unroll
      for (int j = 0; j < 2; ++j)
        accS[i][j] = __builtin_amdgcn_mfma_f32_16x16x32_bf16(a[i], bb[j],
                                                             accS[i][j], 0, 0, 0);
  }
  __syncthreads();  // all waves done reading sK

  // write sA (tril) and sSp (into sK space)
#pragma unroll
  for (int i = 0; i < 2; ++i)
#pragma unroll
    for (int j = 0; j < 2; ++j) {
      const int t0 = wm2 + i * 16 + quad * 4;
      const int s = wn2 + j * 16 + fm;
#pragma unroll
      for (int rr = 0; rr < 4; ++rr) {
        float val = (s <= t0 + rr) ? accS[i][j][rr] : 0.f;
        sA[(t0 + rr) * SP + s] = f2bf(val);
      }
    }
  *(short8*)&sSp[r * SP + c0] = sp0;
  *(short8*)&sSp[r * SP + c0 + 8] = sp1;
  __syncthreads();

  // att = E . (sA @ V~  +  Q @ Sprev^T)
  floatx4 acc[2][2];
#pragma unroll
  for (int i = 0; i < 2; ++i)
#pragma unroll
    for (int j = 0; j < 2; ++j) acc[i][j] = (floatx4){0.f, 0.f, 0.f, 0.f};
#pragma unroll
  for (int ks = 0; ks < 2; ++ks) {
    short8 aa[2], aq[2], bv[2], bs[2];
#pragma unroll
    for (int i = 0; i < 2; ++i) {
      aa[i] = *(const short8*)&sA[(wm2 + i * 16 + fm) * SP + ks * 32 + quad * 8];
      aq[i] = *(const short8*)&sQ[(wm2 + i * 16 + fm) * SP + ks * 32 + quad * 8];
    }
#pragma unroll
    for (int j = 0; j < 2; ++j) {
      bv[j] = *(const short8*)&sVt[(wn2 + j * 16 + fm) * SP + ks * 32 + quad * 8];
      bs[j] = *(const short8*)&sSp[(wn2 + j * 16 + fm) * SP + ks * 32 + quad * 8];
    }
#pragma unroll
    for (int i = 0; i < 2; ++i)
#pragma unroll
      for (int j = 0; j < 2; ++j) {
        acc[i][j] = __builtin_amdgcn_mfma_f32_16x16x32_bf16(aa[i], bv[j],
                                                            acc[i][j], 0, 0, 0);
        acc[i][j] = __builtin_amdgcn_mfma_f32_16x16x32_bf16(aq[i], bs[j],
                                                            acc[i][j], 0, 0, 0);
      }
  }
#pragma unroll
  for (int i = 0; i < 2; ++i)
#pragma unroll
    for (int j = 0; j < 2; ++j) {
      const int m0 = wm2 + i * 16 + quad * 4;
      const int n = wn2 + j * 16 + fm;
#pragma unroll
      for (int rr = 0; rr < 4; ++rr) {
        const size_t idx = base + (size_t)(m0 + rr) * HIDS + n;
        att[idx] = f2bf(acc[i][j][rr] * bf2f(Eb[idx]));
      }
    }
}

// ---------------------------------------------------------------------------
// y = (LayerNorm(att) * gamma + beta) * silu(g), bf16 in/out.
// ---------------------------------------------------------------------------
__global__ __launch_bounds__(256) void ln_gate_kernel(const ushort* __restrict__ att,
                                                      const ushort* __restrict__ g,
                                                      const float* __restrict__ gamma,
                                                      const float* __restrict__ beta,
                                                      ushort* __restrict__ ybf) {
  const int row = blockIdx.x;
  const int tid = threadIdx.x;
  ushort4 au = *(const ushort4*)(att + (size_t)row * HIDS + tid * 4);
  float ax = bf2f(au.x), ay = bf2f(au.y), az = bf2f(au.z), aw = bf2f(au.w);
  float s = ax + ay + az + aw;
  float ss = ax * ax + ay * ay + az * az + aw * aw;
#pragma unroll
  for (int off = 32; off; off >>= 1) {
    s += __shfl_down(s, off);
    ss += __shfl_down(ss, off);
  }
  __shared__ float rs[4], rss[4];
  const int wid = tid >> 6;
  if ((tid & 63) == 0) { rs[wid] = s; rss[wid] = ss; }
  __syncthreads();
  const float mean = (rs[0] + rs[1] + rs[2] + rs[3]) * (1.f / HIDS);
  const float ex2 = (rss[0] + rss[1] + rss[2] + rss[3]) * (1.f / HIDS);
  const float rstd = rsqrtf(ex2 - mean * mean + 1e-5f);

  float4 ga = *(const float4*)(gamma + tid * 4);
  float4 be = *(const float4*)(beta + tid * 4);
  ushort4 gu = *(const ushort4*)(g + (size_t)row * HIDS + tid * 4);
  float gx = bf2f(gu.x), gy = bf2f(gu.y), gz = bf2f(gu.z), gw = bf2f(gu.w);
  float4 o;
  o.x = ((ax - mean) * rstd * ga.x + be.x) * (gx / (1.f + __expf(-gx)));
  o.y = ((ay - mean) * rstd * ga.y + be.y) * (gy / (1.f + __expf(-gy)));
  o.z = ((az - mean) * rstd * ga.z + be.z) * (gz / (1.f + __expf(-gz)));
  o.w = ((aw - mean) * rstd * ga.w + be.w) * (gw / (1.f + __expf(-gw)));
  ushort4 ob;
  ob.x = f2bf(o.x); ob.y = f2bf(o.y); ob.z = f2bf(o.z); ob.w = f2bf(o.w);
  *(ushort4*)(ybf + (size_t)row * HIDS + tid * 4) = ob;
}

// ---------------------------------------------------------------------------
extern "C" void kernel_launch(void* const* d_in, const int* in_sizes, int n_in,
                              void* d_out, int out_size, void* d_ws, size_t ws_size,
                              hipStream_t stream) {
  const float* x     = (const float*)d_in[0];
  const float* Wq    = (const float*)d_in[1];
  const float* Wk    = (const float*)d_in[2];
  const float* Wv    = (const float*)d_in[3];
  const float* Wg    = (const float*)d_in[4];
  const float* Wgk1  = (const float*)d_in[5];
  const float* Wgk2  = (const float*)d_in[6];
  const float* bgk2  = (const float*)d_in[7];
  const float* gamma = (const float*)d_in[8];
  const float* beta  = (const float*)d_in[9];
  const float* Wout  = (const float*)d_in[10];
  float* out = (float*)d_out;

  const size_t SZ = (size_t)NROW * HIDS;  // 4M elements
  float* ws = (float*)d_ws;
  float* Lamb = ws;                         // 64K floats
  ushort* attb   = (ushort*)(ws + 65536);   // bf16 4M
  ushort* Sdelta = attb + SZ;
  ushort* Sprevb = Sdelta + SZ;
  ushort* Vtgb   = Sprevb + SZ;             // V~^T tiles (bf16)
  ushort* Ebb    = Vtgb + SZ;               // e^Gamma (bf16)
  ushort* qbf = Ebb + SZ;                   // qb|kb|vb|gb contiguous
  ushort* kbf = qbf + SZ;
  ushort* vbf = kbf + SZ;
  ushort* gbf = vbf + SZ;
  ushort* xbf = gbf + SZ;
  ushort* Wtq = xbf + SZ;                   // Wtq|Wtk|Wtv|Wtg contiguous
  ushort* Wtk = Wtq + HIDS * HIDS;
  ushort* Wtv = Wtk + HIDS * HIDS;
  ushort* Wtg = Wtv + HIDS * HIDS;
  ushort* Wto = Wtg + HIDS * HIDS;
  float* xrb = (float*)(Wto + HIDS * HIDS);  // [4096][16] f32
  ushort* ybf = vbf;  // vbf dead after sdelta

  prep_kernel<<<4096 + 1280, 256, 0, stream>>>(
      x, xbf, Wq, Wk, Wv, Wg, Wout, Wtq, Wtk, Wtv, Wtg, Wto);

  xr_kernel<<<NROW / 16, 256, 0, stream>>>(xbf, Wgk1, xrb);

  // single 4096x4096x1024 GEMM over concatenated weights / outputs
  proj8_kernel<<<dim3(NROW / 256, NROW / 256), 512, 0, stream>>>(xbf, Wtq, qbf);

  sdelta_kernel<<<BBATCH * NHEAD * NCHUNK, 256, 0, stream>>>(
      kbf, vbf, xrb, Wgk2, bgk2, Sdelta, Lamb, Vtgb, Ebb);
  state_scan_kernel<<<256, 256, 0, stream>>>(Sdelta, Lamb, Sprevb);
  chunk_fused_kernel<<<BBATCH * NHEAD * NCHUNK, 256, 0, stream>>>(
      qbf, kbf, Vtgb, Ebb, Sprevb, attb);

  ln_gate_kernel<<<NROW, 256, 0, stream>>>(attb, gbf, gamma, beta, ybf);
  gemm_out_kernel<<<dim3(HIDS / 128, NROW / 128), 256, 0, stream>>>(ybf, Wto, out);
}

// Round 6
// 199.994 us; speedup vs baseline: 1.1142x; 1.0810x over previous
//
#include <hip/hip_runtime.h>
#include <cstdint>
#include <cstddef>

#define HIDS 1024
#define NHEAD 16
#define HDIM 64
#define LSEQ 2048
#define BBATCH 2
#define NROW (BBATCH * LSEQ)  // 4096
#define CHUNK 64
#define NCHUNK (LSEQ / CHUNK)  // 32
#define RANK 16

typedef short short8 __attribute__((ext_vector_type(8)));
typedef float floatx4 __attribute__((ext_vector_type(4)));

__device__ __forceinline__ ushort f2bf(float f) {
  uint32_t u = __float_as_uint(f);
  uint32_t r = (u + 0x7fffu + ((u >> 16) & 1u)) >> 16;  // RNE
  return (ushort)r;
}
__device__ __forceinline__ float bf2f(ushort u) {
  return __uint_as_float(((uint32_t)u) << 16);
}
// log_sigmoid(z)/16 via native exp/log (arg of log in (1,2] -> accurate)
__device__ __forceinline__ float logsig16(float z) {
  return (fminf(z, 0.f) - __logf(1.f + __expf(-fabsf(z)))) * (1.f / 16.f);
}

__device__ __forceinline__ void async_copy16(const void* g, void* l) {
  __builtin_amdgcn_global_load_lds(
      (const __attribute__((address_space(1))) void*)g,
      (__attribute__((address_space(3))) void*)l, 16, 0, 0);
}

// ---------------------------------------------------------------------------
// prep: fused cvt_x (blocks 0..4095) + transpose_w (4096..5375).
// ---------------------------------------------------------------------------
__global__ __launch_bounds__(256) void prep_kernel(
    const float* __restrict__ x, ushort* __restrict__ xbf,
    const float* __restrict__ W0, const float* __restrict__ W1,
    const float* __restrict__ W2, const float* __restrict__ W3,
    const float* __restrict__ W4, ushort* __restrict__ T0,
    ushort* __restrict__ T1, ushort* __restrict__ T2, ushort* __restrict__ T3,
    ushort* __restrict__ T4) {
  __shared__ float sbuf[64 * 65];
  const int bid = blockIdx.x;
  const int tid = threadIdx.x;

  if (bid < 4096) {  // ---- cvt_x
    const int i = bid * 256 + tid;
    float4 f = *(const float4*)(x + (size_t)i * 4);
    ushort4 o;
    o.x = f2bf(f.x); o.y = f2bf(f.y); o.z = f2bf(f.z); o.w = f2bf(f.w);
    *(ushort4*)(xbf + (size_t)i * 4) = o;
  } else {  // ---- transpose_w
    const int w = bid - 4096;
    const int z = w >> 8, rem = w & 255;
    const float* W = (z == 0) ? W0 : (z == 1) ? W1 : (z == 2) ? W2
                     : (z == 3) ? W3 : W4;
    ushort* T = (z == 0) ? T0 : (z == 1) ? T1 : (z == 2) ? T2
                : (z == 3) ? T3 : T4;
    const int k0 = (rem >> 4) * 64, n0 = (rem & 15) * 64;
    const int r = tid >> 2, c4 = (tid & 3) * 16;
#pragma unroll
    for (int i = 0; i < 4; ++i) {
      float4 f = *(const float4*)(W + (size_t)(k0 + r) * HIDS + n0 + c4 + i * 4);
      sbuf[r * 65 + c4 + i * 4 + 0] = f.x;
      sbuf[r * 65 + c4 + i * 4 + 1] = f.y;
      sbuf[r * 65 + c4 + i * 4 + 2] = f.z;
      sbuf[r * 65 + c4 + i * 4 + 3] = f.w;
    }
    __syncthreads();
    const int n = tid >> 2, kc = (tid & 3) * 16;
#pragma unroll
    for (int i = 0; i < 4; ++i) {
      int kk = kc + i * 4;
      ushort4 o;
      o.x = f2bf(sbuf[(kk + 0) * 65 + n]);
      o.y = f2bf(sbuf[(kk + 1) * 65 + n]);
      o.z = f2bf(sbuf[(kk + 2) * 65 + n]);
      o.w = f2bf(sbuf[(kk + 3) * 65 + n]);
      *(ushort4*)(T + (size_t)(n0 + n) * HIDS + k0 + kk) = o;
    }
  }
}

// ---------------------------------------------------------------------------
// xr = xbf @ Wgk1 : [4096,1024] x [1024,16] -> f32 [4096,16]. 16 rows/block.
// ---------------------------------------------------------------------------
#define XSTR 1040
__global__ __launch_bounds__(256) void xr_kernel(
    const ushort* __restrict__ xbf, const float* __restrict__ Wgk1,
    float* __restrict__ xr) {
  __shared__ float sW1[HIDS * RANK];       // 64 KB, layout [k][16]
  __shared__ ushort sX[16 * XSTR];         // 16 rows, padded
  const int tid = threadIdx.x;
  const int r0 = blockIdx.x * 16;
#pragma unroll
  for (int j = 0; j < 16; ++j) {
    const int idx = j * 1024 + tid * 4;
    *(float4*)&sW1[idx] = *(const float4*)(Wgk1 + idx);
  }
#pragma unroll
  for (int j = 0; j < 8; ++j) {
    const int e = j * 2048 + tid * 8;
    const int rr = e >> 10, kk = e & 1023;
    *(short8*)&sX[rr * XSTR + kk] =
        *(const short8*)(xbf + (size_t)(r0 + rr) * HIDS + kk);
  }
  __syncthreads();
  const int r = tid >> 4, n = tid & 15;
  float acc = 0.f;
  for (int k8 = 0; k8 < HIDS; k8 += 8) {
    short8 xv = *(const short8*)&sX[r * XSTR + k8];
#pragma unroll
    for (int i = 0; i < 8; ++i)
      acc = fmaf(bf2f((ushort)xv[i]), sW1[(k8 + i) * RANK + n], acc);
  }
  xr[(size_t)(r0 + r) * RANK + n] = acc;
}

// ---------------------------------------------------------------------------
// proj8: ONE 4096(M) x 4096(N) x 1024(K) bf16 GEMM over the concatenated
// weights [Wtq|Wtk|Wtv|Wtg], 256x256 tile, BK=64, 8 waves (2Mx4N), 128KB LDS
// double-buffer. Flat per-kt pipeline: 1 barrier/kt, counted vmcnt, register
// subtile rotation.
// ---------------------------------------------------------------------------
#define POFF(buf, mat, half) ((((buf)*2 + (mat)) * 2 + (half)) * 8192)

__global__ __launch_bounds__(512, 2) void proj8_kernel(
    const ushort* __restrict__ xbf, const ushort* __restrict__ Wcat,
    ushort* __restrict__ Cq) {
  __shared__ ushort sT[2 * 2 * 2 * 8192];  // [buf][mat][half][256*32] = 128 KB
  const int tid = threadIdx.x;
  const int lane = tid & 63, wid = tid >> 6;
  const int fm = lane & 15, quad = lane >> 4;
  const int sq8 = ((quad + (fm >> 1)) & 3) * 8;  // read slot (XOR chunk swz)
  const int wr = wid >> 2, wc = wid & 3;         // 2Mx4N wave grid
  const int bm = blockIdx.y * 256, bn = blockIdx.x * 256;

  // staging: thread t covers slots t and t+512 of each 256x32 half-buffer
  const int srow = tid >> 2;
  const int qch = ((((tid & 3) - ((tid >> 3) & 3)) & 3)) * 8;  // src k-chunk
  const ushort* Ab = xbf + (size_t)(bm + srow) * HIDS + qch;
  const ushort* Bb = Wcat + (size_t)(bn + srow) * HIDS + qch;

#define STAGE_A(ktn, nb)                                                      \
  do {                                                                        \
    const int kc_ = (ktn) * 64;                                               \
    async_copy16(Ab + kc_, (char*)&sT[POFF(nb, 0, 0)] + tid * 16);            \
    async_copy16(Ab + (size_t)128 * HIDS + kc_,                               \
                 (char*)&sT[POFF(nb, 0, 0)] + tid * 16 + 8192);               \
    async_copy16(Ab + kc_ + 32, (char*)&sT[POFF(nb, 0, 1)] + tid * 16);       \
    async_copy16(Ab + (size_t)128 * HIDS + kc_ + 32,                          \
                 (char*)&sT[POFF(nb, 0, 1)] + tid * 16 + 8192);               \
  } while (0)
#define STAGE_B0(ktn, nb)                                                     \
  do {                                                                        \
    const int kc_ = (ktn) * 64;                                               \
    async_copy16(Bb + kc_, (char*)&sT[POFF(nb, 1, 0)] + tid * 16);            \
    async_copy16(Bb + (size_t)128 * HIDS + kc_,                               \
                 (char*)&sT[POFF(nb, 1, 0)] + tid * 16 + 8192);               \
  } while (0)
#define STAGE_B1(ktn, nb)                                                     \
  do {                                                                        \
    const int kc_ = (ktn) * 64;                                               \
    async_copy16(Bb + kc_ + 32, (char*)&sT[POFF(nb, 1, 1)] + tid * 16);       \
    async_copy16(Bb + (size_t)128 * HIDS + kc_ + 32,                          \
                 (char*)&sT[POFF(nb, 1, 1)] + tid * 16 + 8192);               \
  } while (0)
#define SB() __builtin_amdgcn_sched_barrier(0)
#define LGKM0()                                          \
  do {                                                   \
    SB();                                                \
    asm volatile("s_waitcnt lgkmcnt(0)" ::: "memory");   \
    SB();                                                \
  } while (0)

  const int aoff = (wr * 128 + fm) * 32 + sq8;  // + m*512, half selects buffer
  const int boff = (wc * 64 + fm) * 32 + sq8;   // + n*512

  floatx4 acc[8][4];
#pragma unroll
  for (int i = 0; i < 8; ++i)
#pragma unroll
    for (int j = 0; j < 4; ++j) acc[i][j] = (floatx4){0.f, 0.f, 0.f, 0.f};

  // prologue: stage K-tile 0 into buf 0 (8 loads)
  STAGE_A(0, 0);
  STAGE_B0(0, 0);
  STAGE_B1(0, 0);

  short8 aA[4][2], aB[4][2], bA[2][2], bB[2][2];

  for (int kt = 0; kt < 16; ++kt) {
    const int cur = kt & 1, nxt = cur ^ 1;
    // top: issue next A-stage; counted wait: all of tile kt landed,
    // A(kt+1) still in flight.
    if (kt < 15) {
      STAGE_A(kt + 1, nxt);
      asm volatile("s_waitcnt vmcnt(4)" ::: "memory");
    } else {
      asm volatile("s_waitcnt vmcnt(0)" ::: "memory");
    }
    SB();
    __builtin_amdgcn_s_barrier();
    SB();

    // R0: frags for Q00 (aA m=0..3, bA n=0..1).
#pragma unroll
    for (int m = 0; m < 4; ++m) {
      aA[m][0] = *(const short8*)&sT[POFF(cur, 0, 0) + aoff + m * 512];
      aA[m][1] = *(const short8*)&sT[POFF(cur, 0, 1) + aoff + m * 512];
    }
#pragma unroll
    for (int n = 0; n < 2; ++n) {
      bA[n][0] = *(const short8*)&sT[POFF(cur, 1, 0) + boff + n * 512];
      bA[n][1] = *(const short8*)&sT[POFF(cur, 1, 1) + boff + n * 512];
    }
    LGKM0();
    __builtin_amdgcn_s_setprio(1);
#pragma unroll
    for (int m = 0; m < 4; ++m)
#pragma unroll
      for (int n = 0; n < 2; ++n) {
        acc[m][n] = __builtin_amdgcn_mfma_f32_16x16x32_bf16(aA[m][0], bA[n][0],
                                                            acc[m][n], 0, 0, 0);
        acc[m][n] = __builtin_amdgcn_mfma_f32_16x16x32_bf16(aA[m][1], bA[n][1],
                                                            acc[m][n], 0, 0, 0);
      }
    __builtin_amdgcn_s_setprio(0);

    // R1: bB (n=2..3) under Q00's in-pipe MFMAs; stage B-half0 of kt+1.
#pragma unroll
    for (int j = 0; j < 2; ++j) {
      bB[j][0] = *(const short8*)&sT[POFF(cur, 1, 0) + boff + (j + 2) * 512];
      bB[j][1] = *(const short8*)&sT[POFF(cur, 1, 1) + boff + (j + 2) * 512];
    }
    if (kt < 15) STAGE_B0(kt + 1, nxt);
    LGKM0();
    __builtin_amdgcn_s_setprio(1);
#pragma unroll
    for (int m = 0; m < 4; ++m)
#pragma unroll
      for (int n = 2; n < 4; ++n) {
        acc[m][n] = __builtin_amdgcn_mfma_f32_16x16x32_bf16(
            aA[m][0], bB[n - 2][0], acc[m][n], 0, 0, 0);
        acc[m][n] = __builtin_amdgcn_mfma_f32_16x16x32_bf16(
            aA[m][1], bB[n - 2][1], acc[m][n], 0, 0, 0);
      }
    __builtin_amdgcn_s_setprio(0);

    // R2: aB (m=4..7) under Q01's in-pipe MFMAs; stage B-half1 of kt+1.
#pragma unroll
    for (int m = 0; m < 4; ++m) {
      aB[m][0] = *(const short8*)&sT[POFF(cur, 0, 0) + aoff + (m + 4) * 512];
      aB[m][1] = *(const short8*)&sT[POFF(cur, 0, 1) + aoff + (m + 4) * 512];
    }
    if (kt < 15) STAGE_B1(kt + 1, nxt);
    LGKM0();
    __builtin_amdgcn_s_setprio(1);
#pragma unroll
    for (int m = 0; m < 4; ++m)
#pragma unroll
      for (int n = 0; n < 2; ++n) {
        acc[m + 4][n] = __builtin_amdgcn_mfma_f32_16x16x32_bf16(
            aB[m][0], bA[n][0], acc[m + 4][n], 0, 0, 0);
        acc[m + 4][n] = __builtin_amdgcn_mfma_f32_16x16x32_bf16(
            aB[m][1], bA[n][1], acc[m + 4][n], 0, 0, 0);
      }
#pragma unroll
    for (int m = 0; m < 4; ++m)
#pragma unroll
      for (int n = 2; n < 4; ++n) {
        acc[m + 4][n] = __builtin_amdgcn_mfma_f32_16x16x32_bf16(
            aB[m][0], bB[n - 2][0], acc[m + 4][n], 0, 0, 0);
        acc[m + 4][n] = __builtin_amdgcn_mfma_f32_16x16x32_bf16(
            aB[m][1], bB[n - 2][1], acc[m + 4][n], 0, 0, 0);
      }
    __builtin_amdgcn_s_setprio(0);
  }

  // epilogue: scatter to the z = col>>10 projection buffer (contiguous)
  const int cb = bn + wc * 64;
  const int z = cb >> 10;
  const int ccol = cb & 1023;
  ushort* C = Cq + (size_t)z * ((size_t)NROW * HIDS);
#pragma unroll
  for (int m = 0; m < 8; ++m) {
    const int row0 = bm + wr * 128 + m * 16 + quad * 4;
#pragma unroll
    for (int n = 0; n < 4; ++n) {
      const int col = ccol + n * 16 + fm;
#pragma unroll
      for (int rr = 0; rr < 4; ++rr)
        C[(size_t)(row0 + rr) * HIDS + col] = f2bf(acc[m][n][rr]);
    }
  }
#undef STAGE_A
#undef STAGE_B0
#undef STAGE_B1
#undef SB
#undef LGKM0
}

// ---------------------------------------------------------------------------
// Output GEMM: 128(M) x 64(N) tile, BK=64, swizzled staging, fp32 out.
// 512 blocks = 2 blocks/CU so barrier drains overlap across blocks
// (the 128x128 / 1-block-per-CU variant starves the CU at every drain).
// ---------------------------------------------------------------------------
__global__ __launch_bounds__(256) void gemm_out_kernel(
    const ushort* __restrict__ A, const ushort* __restrict__ Bt,
    float* __restrict__ C) {
  __shared__ ushort As[2][128 * 32];
  __shared__ ushort Bs[2][64 * 32];
  const int tid = threadIdx.x;
  const int wave = tid >> 6, lane = tid & 63;
  const int fm = lane & 15, quad = lane >> 4;
  const int sq8 = ((quad + (fm >> 1)) & 3) * 8;
  const int bm = blockIdx.y * 128, bn = blockIdx.x * 64;
  const int lrow = tid >> 2;
  const int lk8 = ((((tid & 3) - ((tid >> 3) & 3)) & 3)) * 8;
  const ushort* Ag = A + (size_t)(bm + lrow) * HIDS + lk8;
  const ushort* Bg = Bt + (size_t)(bn + lrow) * HIDS + lk8;
  char* A0 = (char*)&As[0][0] + tid * 16;
  char* A1 = (char*)&As[1][0] + tid * 16;
  char* B0 = (char*)&Bs[0][0] + tid * 16;
  char* B1 = (char*)&Bs[1][0] + tid * 16;

  floatx4 acc[2][4];
#pragma unroll
  for (int i = 0; i < 2; ++i)
#pragma unroll
    for (int j = 0; j < 4; ++j) acc[i][j] = (floatx4){0.f, 0.f, 0.f, 0.f};

  for (int k0 = 0; k0 < HIDS; k0 += 64) {
    __syncthreads();
    async_copy16(Ag + k0, A0);
    async_copy16(Ag + (size_t)64 * HIDS + k0, A0 + 4096);
    async_copy16(Ag + k0 + 32, A1);
    async_copy16(Ag + (size_t)64 * HIDS + k0 + 32, A1 + 4096);
    async_copy16(Bg + k0, B0);
    async_copy16(Bg + k0 + 32, B1);
    __syncthreads();

#pragma unroll
    for (int ks = 0; ks < 2; ++ks) {
      short8 af[2], bfr[4];
#pragma unroll
      for (int i = 0; i < 2; ++i)
        af[i] = *(const short8*)&As[ks][(wave * 32 + i * 16 + fm) * 32 + sq8];
#pragma unroll
      for (int j = 0; j < 4; ++j)
        bfr[j] = *(const short8*)&Bs[ks][(j * 16 + fm) * 32 + sq8];
#pragma unroll
      for (int i = 0; i < 2; ++i)
#pragma unroll
        for (int j = 0; j < 4; ++j)
          acc[i][j] = __builtin_amdgcn_mfma_f32_16x16x32_bf16(af[i], bfr[j],
                                                              acc[i][j], 0, 0, 0);
    }
  }

#pragma unroll
  for (int i = 0; i < 2; ++i) {
    const int row0 = bm + wave * 32 + i * 16 + quad * 4;
#pragma unroll
    for (int j = 0; j < 4; ++j) {
      const int col = bn + j * 16 + fm;
#pragma unroll
      for (int r = 0; r < 4; ++r)
        C[(size_t)(row0 + r) * HIDS + col] = acc[i][j][r];
    }
  }
}

#define SP 72   // ushort stride for bf16 LDS tiles (16B-aligned rows)
#define SGS 68  // float stride for Gamma tile

// ---------------------------------------------------------------------------
// sdelta: z = xr @ Wgk2 + b computed inline (rank-16); Gamma=cumsum(logsig16);
// Vt~=(e^-G V)^T; Sdelta = Lam.(V~^T K); exports Vtg (V~^T) and Eb = e^Gamma.
// ---------------------------------------------------------------------------
__global__ __launch_bounds__(256) void sdelta_kernel(
    const ushort* __restrict__ k, const ushort* __restrict__ v,
    const float* __restrict__ xr, const float* __restrict__ Wgk2,
    const float* __restrict__ bgk2, ushort* __restrict__ Sdelta,
    float* __restrict__ Lam, ushort* __restrict__ Vtg,
    ushort* __restrict__ Eb) {
  const int bid = blockIdx.x;
  const int c = bid & 31, bh = bid >> 5;
  const int b = bh >> 4, h = bh & 15;
  const int tid = threadIdx.x;
  const int lane = tid & 63, wave = tid >> 6;
  const int fm = lane & 15, quad = lane >> 4;
  const int wm2 = (wave >> 1) * 32, wn2 = (wave & 1) * 32;

  __shared__ ushort sKt[64 * SP];
  __shared__ ushort sVt[64 * SP];
  __shared__ float sG[64 * SGS];
  __shared__ float sW2[RANK * 64];

  const size_t base = ((size_t)b * LSEQ + (size_t)c * CHUNK) * HIDS + (size_t)h * HDIM;
  const int r = tid >> 2, c0 = (tid & 3) * 16;
  const size_t gb = base + (size_t)r * HIDS + c0;

  // stage Wgk2 head-slice [16][64] f32
  {
    const int wr = tid >> 4, wc = (tid & 15) * 4;
    *(float4*)&sW2[wr * 64 + wc] =
        *(const float4*)(Wgk2 + (size_t)wr * HIDS + h * HDIM + wc);
  }
  // xr row for this thread's time-step (4 lanes per row share; L2-hot)
  float xrr[16];
  {
    const size_t xrow = ((size_t)b * LSEQ + (size_t)c * CHUNK + r) * RANK;
#pragma unroll
    for (int m = 0; m < 4; ++m)
      *(float4*)&xrr[m * 4] = *(const float4*)(xr + xrow + m * 4);
  }
  float bias[16];
#pragma unroll
  for (int m = 0; m < 4; ++m)
    *(float4*)&bias[m * 4] = *(const float4*)(bgk2 + h * HDIM + c0 + m * 4);
  __syncthreads();

  // z = xr . W2slice + bias -> gk = logsig16(z)
#pragma unroll
  for (int i = 0; i < 16; ++i) {
    float z = bias[i];
#pragma unroll
    for (int t2 = 0; t2 < 16; ++t2)
      z = fmaf(xrr[t2], sW2[t2 * 64 + c0 + i], z);
    sG[r * SGS + c0 + i] = logsig16(z);
  }
  // pair partition (K, V) — issue loads to overlap with cumsum
  const int pr = (tid >> 3) * 2, pc = (tid & 7) * 8;
  const size_t pb = base + (size_t)pr * HIDS + pc;
  short8 ka = *(const short8*)(k + pb);
  short8 kb2 = *(const short8*)(k + pb + HIDS);
  short8 va = *(const short8*)(v + pb);
  short8 vb2 = *(const short8*)(v + pb + HIDS);
  __syncthreads();

  // inclusive cumsum along t per v column
  const int vcol = tid & 63, qtr = tid >> 6;
  {
    float run = 0.f;
#pragma unroll
    for (int i = 0; i < 16; ++i) {
      int idx = (qtr * 16 + i) * SGS + vcol;
      run += sG[idx];
      sG[idx] = run;
    }
  }
  __syncthreads();
  float pre = 0.f;
  for (int j = 0; j < qtr; ++j) pre += sG[(j * 16 + 15) * SGS + vcol];
  __syncthreads();
#pragma unroll
  for (int i = 0; i < 16; ++i) sG[(qtr * 16 + i) * SGS + vcol] += pre;
  __syncthreads();

  // E = e^Gamma -> global (coalesced 32B/thread)
  {
    ushort eb[16];
#pragma unroll
    for (int i = 0; i < 16; ++i) eb[i] = f2bf(__expf(sG[r * SGS + c0 + i]));
    *(short8*)(Eb + gb) = *(short8*)&eb[0];
    *(short8*)(Eb + gb + 8) = *(short8*)&eb[8];
  }

  // transposed tiles (ushort2 writes)
#pragma unroll
  for (int i = 0; i < 8; ++i) {
    ushort2 kk;
    kk.x = (ushort)ka[i];
    kk.y = (ushort)kb2[i];
    *(ushort2*)&sKt[(pc + i) * SP + pr] = kk;
    float Ga = sG[pr * SGS + pc + i];
    float Gb2 = sG[(pr + 1) * SGS + pc + i];
    ushort2 vv;
    vv.x = f2bf(bf2f((ushort)va[i]) * __expf(-Ga));
    vv.y = f2bf(bf2f((ushort)vb2[i]) * __expf(-Gb2));
    *(ushort2*)&sVt[(pc + i) * SP + pr] = vv;
  }
  __syncthreads();

  // export V~^T tile (coalesced 32B/thread)
  {
    const size_t vb3 = (size_t)(bh * NCHUNK + c) * (HDIM * HDIM);
    *(short8*)(Vtg + vb3 + (size_t)r * HDIM + c0) = *(const short8*)&sVt[r * SP + c0];
    *(short8*)(Vtg + vb3 + (size_t)r * HDIM + c0 + 8) =
        *(const short8*)&sVt[r * SP + c0 + 8];
  }

  if (tid < 64)
    Lam[(size_t)(bh * NCHUNK + c) * HDIM + tid] = __expf(sG[63 * SGS + tid]);

  floatx4 accD[2][2];
#pragma unroll
  for (int i = 0; i < 2; ++i)
#pragma unroll
    for (int j = 0; j < 2; ++j) accD[i][j] = (floatx4){0.f, 0.f, 0.f, 0.f};
#pragma unroll
  for (int ks = 0; ks < 2; ++ks) {
    short8 av[2], bk[2];
#pragma unroll
    for (int i = 0; i < 2; ++i)
      av[i] = *(const short8*)&sVt[(wm2 + i * 16 + fm) * SP + ks * 32 + quad * 8];
#pragma unroll
    for (int j = 0; j < 2; ++j)
      bk[j] = *(const short8*)&sKt[(wn2 + j * 16 + fm) * SP + ks * 32 + quad * 8];
#pragma unroll
    for (int i = 0; i < 2; ++i)
#pragma unroll
      for (int j = 0; j < 2; ++j)
        accD[i][j] = __builtin_amdgcn_mfma_f32_16x16x32_bf16(av[i], bk[j],
                                                             accD[i][j], 0, 0, 0);
  }
  const size_t sbase = (size_t)(bh * NCHUNK + c) * (HDIM * HDIM);
#pragma unroll
  for (int i = 0; i < 2; ++i) {
    const int m0 = wm2 + i * 16 + quad * 4;
    float lam[4];
#pragma unroll
    for (int rr = 0; rr < 4; ++rr) lam[rr] = __expf(sG[63 * SGS + m0 + rr]);
#pragma unroll
    for (int j = 0; j < 2; ++j) {
      const int n = wn2 + j * 16 + fm;
#pragma unroll
      for (int rr = 0; rr < 4; ++rr)
        Sdelta[sbase + (size_t)(m0 + rr) * HDIM + n] = f2bf(accD[i][j][rr] * lam[rr]);
    }
  }
}

// ---------------------------------------------------------------------------
// state_scan: 512 blocks (2/CU, 8 waves/CU), 1 state element per thread,
// prefetch 4 chunks ahead (2-deep was ~40 cyc of cover vs ~900 cyc HBM).
// ---------------------------------------------------------------------------
__global__ __launch_bounds__(256) void state_scan_kernel(
    const ushort* __restrict__ Sdelta, const float* __restrict__ Lam,
    ushort* __restrict__ Sprev) {
  const int bh = blockIdx.x >> 4;   // 32 (b,h) pairs
  const int sl = blockIdx.x & 15;   // 16 slices of 256 elements
  const int e0 = sl * 256 + threadIdx.x;
  float S = 0.f;

  float pd[4], pl[4];
#pragma unroll
  for (int s = 0; s < 4; ++s) {
    size_t nb = (size_t)(bh * NCHUNK + s) * (HDIM * HDIM);
    pd[s] = bf2f(Sdelta[nb + e0]);
    pl[s] = Lam[(size_t)(bh * NCHUNK + s) * HDIM + (e0 >> 6)];
  }

  for (int c = 0; c < NCHUNK; ++c) {
    const int s = c & 3;
    float cd = pd[s], cl = pl[s];
    if (c + 4 < NCHUNK) {
      size_t nb = (size_t)(bh * NCHUNK + c + 4) * (HDIM * HDIM);
      pd[s] = bf2f(Sdelta[nb + e0]);
      pl[s] = Lam[(size_t)(bh * NCHUNK + c + 4) * HDIM + (e0 >> 6)];
    }
    Sprev[(size_t)(bh * NCHUNK + c) * (HDIM * HDIM) + e0] = f2bf(S);
    S = fmaf(S, cl, cd);
  }
}

// ---------------------------------------------------------------------------
// chunk_fused: att(bf16) = E . ( tril(QK^T) @ V~ + Q @ Sprev^T )
// ---------------------------------------------------------------------------
__global__ __launch_bounds__(256) void chunk_fused_kernel(
    const ushort* __restrict__ q, const ushort* __restrict__ k,
    const ushort* __restrict__ Vtg, const ushort* __restrict__ Eb,
    const ushort* __restrict__ Sprev, ushort* __restrict__ att) {
  const int bid = blockIdx.x;
  const int c = bid & 31, bh = bid >> 5;
  const int b = bh >> 4, h = bh & 15;
  const int tid = threadIdx.x;
  const int lane = tid & 63, wave = tid >> 6;
  const int fm = lane & 15, quad = lane >> 4;
  const int wm2 = (wave >> 1) * 32, wn2 = (wave & 1) * 32;

  __shared__ ushort sQ[64 * SP];
  __shared__ ushort sK[64 * SP];   // reused as sSp after scores
  __shared__ ushort sVt[64 * SP];
  __shared__ ushort sA[64 * SP];
  ushort* sSp = sK;

  const size_t base = ((size_t)b * LSEQ + (size_t)c * CHUNK) * HIDS + (size_t)h * HDIM;
  const size_t sbase = (size_t)(bh * NCHUNK + c) * (HDIM * HDIM);
  const int r = tid >> 2, c0 = (tid & 3) * 16;
  const size_t gb = base + (size_t)r * HIDS + c0;
  short8 sp0 = *(const short8*)(Sprev + sbase + (size_t)r * HDIM + c0);
  short8 sp1 = *(const short8*)(Sprev + sbase + (size_t)r * HDIM + c0 + 8);
  *(short8*)&sQ[r * SP + c0] = *(const short8*)(q + gb);
  *(short8*)&sQ[r * SP + c0 + 8] = *(const short8*)(q + gb + 8);
  *(short8*)&sK[r * SP + c0] = *(const short8*)(k + gb);
  *(short8*)&sK[r * SP + c0 + 8] = *(const short8*)(k + gb + 8);
  *(short8*)&sVt[r * SP + c0] = *(const short8*)(Vtg + sbase + (size_t)r * HDIM + c0);
  *(short8*)&sVt[r * SP + c0 + 8] =
      *(const short8*)(Vtg + sbase + (size_t)r * HDIM + c0 + 8);
  __syncthreads();

  // scores = tril(Q K^T)
  floatx4 accS[2][2];
#pragma unroll
  for (int i = 0; i < 2; ++i)
#pragma unroll
    for (int j = 0; j < 2; ++j) accS[i][j] = (floatx4){0.f, 0.f, 0.f, 0.f};
#pragma unroll
  for (int ks = 0; ks < 2; ++ks) {
    short8 a[2], bb[2];
#pragma unroll
    for (int i = 0; i < 2; ++i)
      a[i] = *(const short8*)&sQ[(wm2 + i * 16 + fm) * SP + ks * 32 + quad * 8];
#pragma unroll
    for (int j = 0; j < 2; ++j)
      bb[j] = *(const short8*)&sK[(wn2 + j * 16 + fm) * SP + ks * 32 + quad * 8];
#pragma unroll
    for (int i = 0; i < 2; ++i)
#pragma unroll
      for (int j = 0; j < 2; ++j)
        accS[i][j] = __builtin_amdgcn_mfma_f32_16x16x32_bf16(a[i], bb[j],
                                                             accS[i][j], 0, 0, 0);
  }
  __syncthreads();  // all waves done reading sK

  // write sA (tril) and sSp (into sK space)
#pragma unroll
  for (int i = 0; i < 2; ++i)
#pragma unroll
    for (int j = 0; j < 2; ++j) {
      const int t0 = wm2 + i * 16 + quad * 4;
      const int s = wn2 + j * 16 + fm;
#pragma unroll
      for (int rr = 0; rr < 4; ++rr) {
        float val = (s <= t0 + rr) ? accS[i][j][rr] : 0.f;
        sA[(t0 + rr) * SP + s] = f2bf(val);
      }
    }
  *(short8*)&sSp[r * SP + c0] = sp0;
  *(short8*)&sSp[r * SP + c0 + 8] = sp1;
  __syncthreads();

  // att = E . (sA @ V~  +  Q @ Sprev^T)
  floatx4 acc[2][2];
#pragma unroll
  for (int i = 0; i < 2; ++i)
#pragma unroll
    for (int j = 0; j < 2; ++j) acc[i][j] = (floatx4){0.f, 0.f, 0.f, 0.f};
#pragma unroll
  for (int ks = 0; ks < 2; ++ks) {
    short8 aa[2], aq[2], bv[2], bs[2];
#pragma unroll
    for (int i = 0; i < 2; ++i) {
      aa[i] = *(const short8*)&sA[(wm2 + i * 16 + fm) * SP + ks * 32 + quad * 8];
      aq[i] = *(const short8*)&sQ[(wm2 + i * 16 + fm) * SP + ks * 32 + quad * 8];
    }
#pragma unroll
    for (int j = 0; j < 2; ++j) {
      bv[j] = *(const short8*)&sVt[(wn2 + j * 16 + fm) * SP + ks * 32 + quad * 8];
      bs[j] = *(const short8*)&sSp[(wn2 + j * 16 + fm) * SP + ks * 32 + quad * 8];
    }
#pragma unroll
    for (int i = 0; i < 2; ++i)
#pragma unroll
      for (int j = 0; j < 2; ++j) {
        acc[i][j] = __builtin_amdgcn_mfma_f32_16x16x32_bf16(aa[i], bv[j],
                                                            acc[i][j], 0, 0, 0);
        acc[i][j] = __builtin_amdgcn_mfma_f32_16x16x32_bf16(aq[i], bs[j],
                                                            acc[i][j], 0, 0, 0);
      }
  }
#pragma unroll
  for (int i = 0; i < 2; ++i)
#pragma unroll
    for (int j = 0; j < 2; ++j) {
      const int m0 = wm2 + i * 16 + quad * 4;
      const int n = wn2 + j * 16 + fm;
#pragma unroll
      for (int rr = 0; rr < 4; ++rr) {
        const size_t idx = base + (size_t)(m0 + rr) * HIDS + n;
        att[idx] = f2bf(acc[i][j][rr] * bf2f(Eb[idx]));
      }
    }
}

// ---------------------------------------------------------------------------
// y = (LayerNorm(att) * gamma + beta) * silu(g), bf16 in/out.
// ---------------------------------------------------------------------------
__global__ __launch_bounds__(256) void ln_gate_kernel(const ushort* __restrict__ att,
                                                      const ushort* __restrict__ g,
                                                      const float* __restrict__ gamma,
                                                      const float* __restrict__ beta,
                                                      ushort* __restrict__ ybf) {
  const int row = blockIdx.x;
  const int tid = threadIdx.x;
  ushort4 au = *(const ushort4*)(att + (size_t)row * HIDS + tid * 4);
  float ax = bf2f(au.x), ay = bf2f(au.y), az = bf2f(au.z), aw = bf2f(au.w);
  float s = ax + ay + az + aw;
  float ss = ax * ax + ay * ay + az * az + aw * aw;
#pragma unroll
  for (int off = 32; off; off >>= 1) {
    s += __shfl_down(s, off);
    ss += __shfl_down(ss, off);
  }
  __shared__ float rs[4], rss[4];
  const int wid = tid >> 6;
  if ((tid & 63) == 0) { rs[wid] = s; rss[wid] = ss; }
  __syncthreads();
  const float mean = (rs[0] + rs[1] + rs[2] + rs[3]) * (1.f / HIDS);
  const float ex2 = (rss[0] + rss[1] + rss[2] + rss[3]) * (1.f / HIDS);
  const float rstd = rsqrtf(ex2 - mean * mean + 1e-5f);

  float4 ga = *(const float4*)(gamma + tid * 4);
  float4 be = *(const float4*)(beta + tid * 4);
  ushort4 gu = *(const ushort4*)(g + (size_t)row * HIDS + tid * 4);
  float gx = bf2f(gu.x), gy = bf2f(gu.y), gz = bf2f(gu.z), gw = bf2f(gu.w);
  float4 o;
  o.x = ((ax - mean) * rstd * ga.x + be.x) * (gx / (1.f + __expf(-gx)));
  o.y = ((ay - mean) * rstd * ga.y + be.y) * (gy / (1.f + __expf(-gy)));
  o.z = ((az - mean) * rstd * ga.z + be.z) * (gz / (1.f + __expf(-gz)));
  o.w = ((aw - mean) * rstd * ga.w + be.w) * (gw / (1.f + __expf(-gw)));
  ushort4 ob;
  ob.x = f2bf(o.x); ob.y = f2bf(o.y); ob.z = f2bf(o.z); ob.w = f2bf(o.w);
  *(ushort4*)(ybf + (size_t)row * HIDS + tid * 4) = ob;
}

// ---------------------------------------------------------------------------
extern "C" void kernel_launch(void* const* d_in, const int* in_sizes, int n_in,
                              void* d_out, int out_size, void* d_ws, size_t ws_size,
                              hipStream_t stream) {
  const float* x     = (const float*)d_in[0];
  const float* Wq    = (const float*)d_in[1];
  const float* Wk    = (const float*)d_in[2];
  const float* Wv    = (const float*)d_in[3];
  const float* Wg    = (const float*)d_in[4];
  const float* Wgk1  = (const float*)d_in[5];
  const float* Wgk2  = (const float*)d_in[6];
  const float* bgk2  = (const float*)d_in[7];
  const float* gamma = (const float*)d_in[8];
  const float* beta  = (const float*)d_in[9];
  const float* Wout  = (const float*)d_in[10];
  float* out = (float*)d_out;

  const size_t SZ = (size_t)NROW * HIDS;  // 4M elements
  float* ws = (float*)d_ws;
  float* Lamb = ws;                         // 64K floats
  ushort* attb   = (ushort*)(ws + 65536);   // bf16 4M
  ushort* Sdelta = attb + SZ;
  ushort* Sprevb = Sdelta + SZ;
  ushort* Vtgb   = Sprevb + SZ;             // V~^T tiles (bf16)
  ushort* Ebb    = Vtgb + SZ;               // e^Gamma (bf16)
  ushort* qbf = Ebb + SZ;                   // qb|kb|vb|gb contiguous
  ushort* kbf = qbf + SZ;
  ushort* vbf = kbf + SZ;
  ushort* gbf = vbf + SZ;
  ushort* xbf = gbf + SZ;
  ushort* Wtq = xbf + SZ;                   // Wtq|Wtk|Wtv|Wtg contiguous
  ushort* Wtk = Wtq + HIDS * HIDS;
  ushort* Wtv = Wtk + HIDS * HIDS;
  ushort* Wtg = Wtv + HIDS * HIDS;
  ushort* Wto = Wtg + HIDS * HIDS;
  float* xrb = (float*)(Wto + HIDS * HIDS);  // [4096][16] f32
  ushort* ybf = vbf;  // vbf dead after sdelta

  prep_kernel<<<4096 + 1280, 256, 0, stream>>>(
      x, xbf, Wq, Wk, Wv, Wg, Wout, Wtq, Wtk, Wtv, Wtg, Wto);

  xr_kernel<<<NROW / 16, 256, 0, stream>>>(xbf, Wgk1, xrb);

  // single 4096x4096x1024 GEMM over concatenated weights / outputs
  proj8_kernel<<<dim3(NROW / 256, NROW / 256), 512, 0, stream>>>(xbf, Wtq, qbf);

  sdelta_kernel<<<BBATCH * NHEAD * NCHUNK, 256, 0, stream>>>(
      kbf, vbf, xrb, Wgk2, bgk2, Sdelta, Lamb, Vtgb, Ebb);
  state_scan_kernel<<<512, 256, 0, stream>>>(Sdelta, Lamb, Sprevb);
  chunk_fused_kernel<<<BBATCH * NHEAD * NCHUNK, 256, 0, stream>>>(
      qbf, kbf, Vtgb, Ebb, Sprevb, attb);

  ln_gate_kernel<<<NROW, 256, 0, stream>>>(attb, gbf, gamma, beta, ybf);
  gemm_out_kernel<<<dim3(HIDS / 64, NROW / 128), 256, 0, stream>>>(ybf, Wto, out);
}

// Round 7
// 195.412 us; speedup vs baseline: 1.1403x; 1.0235x over previous
//
#include <hip/hip_runtime.h>
#include <cstdint>
#include <cstddef>

#define HIDS 1024
#define NHEAD 16
#define HDIM 64
#define LSEQ 2048
#define BBATCH 2
#define NROW (BBATCH * LSEQ)  // 4096
#define CHUNK 64
#define NCHUNK (LSEQ / CHUNK)  // 32
#define RANK 16

typedef short short8 __attribute__((ext_vector_type(8)));
typedef float floatx4 __attribute__((ext_vector_type(4)));

__device__ __forceinline__ ushort f2bf(float f) {
  uint32_t u = __float_as_uint(f);
  uint32_t r = (u + 0x7fffu + ((u >> 16) & 1u)) >> 16;  // RNE
  return (ushort)r;
}
__device__ __forceinline__ float bf2f(ushort u) {
  return __uint_as_float(((uint32_t)u) << 16);
}
// log_sigmoid(z)/16 via native exp/log (arg of log in (1,2] -> accurate)
__device__ __forceinline__ float logsig16(float z) {
  return (fminf(z, 0.f) - __logf(1.f + __expf(-fabsf(z)))) * (1.f / 16.f);
}

__device__ __forceinline__ void async_copy16(const void* g, void* l) {
  __builtin_amdgcn_global_load_lds(
      (const __attribute__((address_space(1))) void*)g,
      (__attribute__((address_space(3))) void*)l, 16, 0, 0);
}

// ---------------------------------------------------------------------------
// prep: fused cvt_x (blocks 0..4095) + transpose_w (4096..5375).
// ---------------------------------------------------------------------------
__global__ __launch_bounds__(256) void prep_kernel(
    const float* __restrict__ x, ushort* __restrict__ xbf,
    const float* __restrict__ W0, const float* __restrict__ W1,
    const float* __restrict__ W2, const float* __restrict__ W3,
    const float* __restrict__ W4, ushort* __restrict__ T0,
    ushort* __restrict__ T1, ushort* __restrict__ T2, ushort* __restrict__ T3,
    ushort* __restrict__ T4) {
  __shared__ float sbuf[64 * 65];
  const int bid = blockIdx.x;
  const int tid = threadIdx.x;

  if (bid < 4096) {  // ---- cvt_x
    const int i = bid * 256 + tid;
    float4 f = *(const float4*)(x + (size_t)i * 4);
    ushort4 o;
    o.x = f2bf(f.x); o.y = f2bf(f.y); o.z = f2bf(f.z); o.w = f2bf(f.w);
    *(ushort4*)(xbf + (size_t)i * 4) = o;
  } else {  // ---- transpose_w
    const int w = bid - 4096;
    const int z = w >> 8, rem = w & 255;
    const float* W = (z == 0) ? W0 : (z == 1) ? W1 : (z == 2) ? W2
                     : (z == 3) ? W3 : W4;
    ushort* T = (z == 0) ? T0 : (z == 1) ? T1 : (z == 2) ? T2
                : (z == 3) ? T3 : T4;
    const int k0 = (rem >> 4) * 64, n0 = (rem & 15) * 64;
    const int r = tid >> 2, c4 = (tid & 3) * 16;
#pragma unroll
    for (int i = 0; i < 4; ++i) {
      float4 f = *(const float4*)(W + (size_t)(k0 + r) * HIDS + n0 + c4 + i * 4);
      sbuf[r * 65 + c4 + i * 4 + 0] = f.x;
      sbuf[r * 65 + c4 + i * 4 + 1] = f.y;
      sbuf[r * 65 + c4 + i * 4 + 2] = f.z;
      sbuf[r * 65 + c4 + i * 4 + 3] = f.w;
    }
    __syncthreads();
    const int n = tid >> 2, kc = (tid & 3) * 16;
#pragma unroll
    for (int i = 0; i < 4; ++i) {
      int kk = kc + i * 4;
      ushort4 o;
      o.x = f2bf(sbuf[(kk + 0) * 65 + n]);
      o.y = f2bf(sbuf[(kk + 1) * 65 + n]);
      o.z = f2bf(sbuf[(kk + 2) * 65 + n]);
      o.w = f2bf(sbuf[(kk + 3) * 65 + n]);
      *(ushort4*)(T + (size_t)(n0 + n) * HIDS + k0 + kk) = o;
    }
  }
}

// ---------------------------------------------------------------------------
// xr = xbf @ Wgk1 : [4096,1024] x [1024,16] -> f32 [4096,16]. 16 rows/block.
// ---------------------------------------------------------------------------
#define XSTR 1040
__global__ __launch_bounds__(256) void xr_kernel(
    const ushort* __restrict__ xbf, const float* __restrict__ Wgk1,
    float* __restrict__ xr) {
  __shared__ float sW1[HIDS * RANK];       // 64 KB, layout [k][16]
  __shared__ ushort sX[16 * XSTR];         // 16 rows, padded
  const int tid = threadIdx.x;
  const int r0 = blockIdx.x * 16;
#pragma unroll
  for (int j = 0; j < 16; ++j) {
    const int idx = j * 1024 + tid * 4;
    *(float4*)&sW1[idx] = *(const float4*)(Wgk1 + idx);
  }
#pragma unroll
  for (int j = 0; j < 8; ++j) {
    const int e = j * 2048 + tid * 8;
    const int rr = e >> 10, kk = e & 1023;
    *(short8*)&sX[rr * XSTR + kk] =
        *(const short8*)(xbf + (size_t)(r0 + rr) * HIDS + kk);
  }
  __syncthreads();
  const int r = tid >> 4, n = tid & 15;
  float acc = 0.f;
  for (int k8 = 0; k8 < HIDS; k8 += 8) {
    short8 xv = *(const short8*)&sX[r * XSTR + k8];
#pragma unroll
    for (int i = 0; i < 8; ++i)
      acc = fmaf(bf2f((ushort)xv[i]), sW1[(k8 + i) * RANK + n], acc);
  }
  xr[(size_t)(r0 + r) * RANK + n] = acc;
}

// ---------------------------------------------------------------------------
// proj8: ONE 4096(M) x 4096(N) x 1024(K) bf16 GEMM over the concatenated
// weights [Wtq|Wtk|Wtv|Wtg], 256x256 tile, BK=64, 8 waves (2Mx4N), 128KB LDS
// double-buffer. Flat per-kt pipeline (frozen at session plateau ~870 TF).
// ---------------------------------------------------------------------------
#define POFF(buf, mat, half) ((((buf)*2 + (mat)) * 2 + (half)) * 8192)

__global__ __launch_bounds__(512, 2) void proj8_kernel(
    const ushort* __restrict__ xbf, const ushort* __restrict__ Wcat,
    ushort* __restrict__ Cq) {
  __shared__ ushort sT[2 * 2 * 2 * 8192];  // [buf][mat][half][256*32] = 128 KB
  const int tid = threadIdx.x;
  const int lane = tid & 63, wid = tid >> 6;
  const int fm = lane & 15, quad = lane >> 4;
  const int sq8 = ((quad + (fm >> 1)) & 3) * 8;  // read slot (XOR chunk swz)
  const int wr = wid >> 2, wc = wid & 3;         // 2Mx4N wave grid
  const int bm = blockIdx.y * 256, bn = blockIdx.x * 256;

  // staging: thread t covers slots t and t+512 of each 256x32 half-buffer
  const int srow = tid >> 2;
  const int qch = ((((tid & 3) - ((tid >> 3) & 3)) & 3)) * 8;  // src k-chunk
  const ushort* Ab = xbf + (size_t)(bm + srow) * HIDS + qch;
  const ushort* Bb = Wcat + (size_t)(bn + srow) * HIDS + qch;

#define STAGE_A(ktn, nb)                                                      \
  do {                                                                        \
    const int kc_ = (ktn) * 64;                                               \
    async_copy16(Ab + kc_, (char*)&sT[POFF(nb, 0, 0)] + tid * 16);            \
    async_copy16(Ab + (size_t)128 * HIDS + kc_,                               \
                 (char*)&sT[POFF(nb, 0, 0)] + tid * 16 + 8192);               \
    async_copy16(Ab + kc_ + 32, (char*)&sT[POFF(nb, 0, 1)] + tid * 16);       \
    async_copy16(Ab + (size_t)128 * HIDS + kc_ + 32,                          \
                 (char*)&sT[POFF(nb, 0, 1)] + tid * 16 + 8192);               \
  } while (0)
#define STAGE_B0(ktn, nb)                                                     \
  do {                                                                        \
    const int kc_ = (ktn) * 64;                                               \
    async_copy16(Bb + kc_, (char*)&sT[POFF(nb, 1, 0)] + tid * 16);            \
    async_copy16(Bb + (size_t)128 * HIDS + kc_,                               \
                 (char*)&sT[POFF(nb, 1, 0)] + tid * 16 + 8192);               \
  } while (0)
#define STAGE_B1(ktn, nb)                                                     \
  do {                                                                        \
    const int kc_ = (ktn) * 64;                                               \
    async_copy16(Bb + kc_ + 32, (char*)&sT[POFF(nb, 1, 1)] + tid * 16);       \
    async_copy16(Bb + (size_t)128 * HIDS + kc_ + 32,                          \
                 (char*)&sT[POFF(nb, 1, 1)] + tid * 16 + 8192);               \
  } while (0)
#define SB() __builtin_amdgcn_sched_barrier(0)
#define LGKM0()                                          \
  do {                                                   \
    SB();                                                \
    asm volatile("s_waitcnt lgkmcnt(0)" ::: "memory");   \
    SB();                                                \
  } while (0)

  const int aoff = (wr * 128 + fm) * 32 + sq8;  // + m*512, half selects buffer
  const int boff = (wc * 64 + fm) * 32 + sq8;   // + n*512

  floatx4 acc[8][4];
#pragma unroll
  for (int i = 0; i < 8; ++i)
#pragma unroll
    for (int j = 0; j < 4; ++j) acc[i][j] = (floatx4){0.f, 0.f, 0.f, 0.f};

  // prologue: stage K-tile 0 into buf 0 (8 loads)
  STAGE_A(0, 0);
  STAGE_B0(0, 0);
  STAGE_B1(0, 0);

  short8 aA[4][2], aB[4][2], bA[2][2], bB[2][2];

  for (int kt = 0; kt < 16; ++kt) {
    const int cur = kt & 1, nxt = cur ^ 1;
    if (kt < 15) {
      STAGE_A(kt + 1, nxt);
      asm volatile("s_waitcnt vmcnt(4)" ::: "memory");
    } else {
      asm volatile("s_waitcnt vmcnt(0)" ::: "memory");
    }
    SB();
    __builtin_amdgcn_s_barrier();
    SB();

    // R0: frags for Q00 (aA m=0..3, bA n=0..1).
#pragma unroll
    for (int m = 0; m < 4; ++m) {
      aA[m][0] = *(const short8*)&sT[POFF(cur, 0, 0) + aoff + m * 512];
      aA[m][1] = *(const short8*)&sT[POFF(cur, 0, 1) + aoff + m * 512];
    }
#pragma unroll
    for (int n = 0; n < 2; ++n) {
      bA[n][0] = *(const short8*)&sT[POFF(cur, 1, 0) + boff + n * 512];
      bA[n][1] = *(const short8*)&sT[POFF(cur, 1, 1) + boff + n * 512];
    }
    LGKM0();
    __builtin_amdgcn_s_setprio(1);
#pragma unroll
    for (int m = 0; m < 4; ++m)
#pragma unroll
      for (int n = 0; n < 2; ++n) {
        acc[m][n] = __builtin_amdgcn_mfma_f32_16x16x32_bf16(aA[m][0], bA[n][0],
                                                            acc[m][n], 0, 0, 0);
        acc[m][n] = __builtin_amdgcn_mfma_f32_16x16x32_bf16(aA[m][1], bA[n][1],
                                                            acc[m][n], 0, 0, 0);
      }
    __builtin_amdgcn_s_setprio(0);

    // R1: bB (n=2..3) under Q00's in-pipe MFMAs; stage B-half0 of kt+1.
#pragma unroll
    for (int j = 0; j < 2; ++j) {
      bB[j][0] = *(const short8*)&sT[POFF(cur, 1, 0) + boff + (j + 2) * 512];
      bB[j][1] = *(const short8*)&sT[POFF(cur, 1, 1) + boff + (j + 2) * 512];
    }
    if (kt < 15) STAGE_B0(kt + 1, nxt);
    LGKM0();
    __builtin_amdgcn_s_setprio(1);
#pragma unroll
    for (int m = 0; m < 4; ++m)
#pragma unroll
      for (int n = 2; n < 4; ++n) {
        acc[m][n] = __builtin_amdgcn_mfma_f32_16x16x32_bf16(
            aA[m][0], bB[n - 2][0], acc[m][n], 0, 0, 0);
        acc[m][n] = __builtin_amdgcn_mfma_f32_16x16x32_bf16(
            aA[m][1], bB[n - 2][1], acc[m][n], 0, 0, 0);
      }
    __builtin_amdgcn_s_setprio(0);

    // R2: aB (m=4..7) under Q01's in-pipe MFMAs; stage B-half1 of kt+1.
#pragma unroll
    for (int m = 0; m < 4; ++m) {
      aB[m][0] = *(const short8*)&sT[POFF(cur, 0, 0) + aoff + (m + 4) * 512];
      aB[m][1] = *(const short8*)&sT[POFF(cur, 0, 1) + aoff + (m + 4) * 512];
    }
    if (kt < 15) STAGE_B1(kt + 1, nxt);
    LGKM0();
    __builtin_amdgcn_s_setprio(1);
#pragma unroll
    for (int m = 0; m < 4; ++m)
#pragma unroll
      for (int n = 0; n < 2; ++n) {
        acc[m + 4][n] = __builtin_amdgcn_mfma_f32_16x16x32_bf16(
            aB[m][0], bA[n][0], acc[m + 4][n], 0, 0, 0);
        acc[m + 4][n] = __builtin_amdgcn_mfma_f32_16x16x32_bf16(
            aB[m][1], bA[n][1], acc[m + 4][n], 0, 0, 0);
      }
#pragma unroll
    for (int m = 0; m < 4; ++m)
#pragma unroll
      for (int n = 2; n < 4; ++n) {
        acc[m + 4][n] = __builtin_amdgcn_mfma_f32_16x16x32_bf16(
            aB[m][0], bB[n - 2][0], acc[m + 4][n], 0, 0, 0);
        acc[m + 4][n] = __builtin_amdgcn_mfma_f32_16x16x32_bf16(
            aB[m][1], bB[n - 2][1], acc[m + 4][n], 0, 0, 0);
      }
    __builtin_amdgcn_s_setprio(0);
  }

  // epilogue: scatter to the z = col>>10 projection buffer (contiguous)
  const int cb = bn + wc * 64;
  const int z = cb >> 10;
  const int ccol = cb & 1023;
  ushort* C = Cq + (size_t)z * ((size_t)NROW * HIDS);
#pragma unroll
  for (int m = 0; m < 8; ++m) {
    const int row0 = bm + wr * 128 + m * 16 + quad * 4;
#pragma unroll
    for (int n = 0; n < 4; ++n) {
      const int col = ccol + n * 16 + fm;
#pragma unroll
      for (int rr = 0; rr < 4; ++rr)
        C[(size_t)(row0 + rr) * HIDS + col] = f2bf(acc[m][n][rr]);
    }
  }
#undef STAGE_A
#undef STAGE_B0
#undef STAGE_B1
#undef SB
#undef LGKM0
}

// ---------------------------------------------------------------------------
// Output GEMM: 128(M) x 64(N) tile, BK=64, swizzled staging, fp32 out.
// 512 blocks = 2 blocks/CU so barrier drains overlap across blocks.
// ---------------------------------------------------------------------------
__global__ __launch_bounds__(256) void gemm_out_kernel(
    const ushort* __restrict__ A, const ushort* __restrict__ Bt,
    float* __restrict__ C) {
  __shared__ ushort As[2][128 * 32];
  __shared__ ushort Bs[2][64 * 32];
  const int tid = threadIdx.x;
  const int wave = tid >> 6, lane = tid & 63;
  const int fm = lane & 15, quad = lane >> 4;
  const int sq8 = ((quad + (fm >> 1)) & 3) * 8;
  const int bm = blockIdx.y * 128, bn = blockIdx.x * 64;
  const int lrow = tid >> 2;
  const int lk8 = ((((tid & 3) - ((tid >> 3) & 3)) & 3)) * 8;
  const ushort* Ag = A + (size_t)(bm + lrow) * HIDS + lk8;
  const ushort* Bg = Bt + (size_t)(bn + lrow) * HIDS + lk8;
  char* A0 = (char*)&As[0][0] + tid * 16;
  char* A1 = (char*)&As[1][0] + tid * 16;
  char* B0 = (char*)&Bs[0][0] + tid * 16;
  char* B1 = (char*)&Bs[1][0] + tid * 16;

  floatx4 acc[2][4];
#pragma unroll
  for (int i = 0; i < 2; ++i)
#pragma unroll
    for (int j = 0; j < 4; ++j) acc[i][j] = (floatx4){0.f, 0.f, 0.f, 0.f};

  for (int k0 = 0; k0 < HIDS; k0 += 64) {
    __syncthreads();
    async_copy16(Ag + k0, A0);
    async_copy16(Ag + (size_t)64 * HIDS + k0, A0 + 4096);
    async_copy16(Ag + k0 + 32, A1);
    async_copy16(Ag + (size_t)64 * HIDS + k0 + 32, A1 + 4096);
    async_copy16(Bg + k0, B0);
    async_copy16(Bg + k0 + 32, B1);
    __syncthreads();

#pragma unroll
    for (int ks = 0; ks < 2; ++ks) {
      short8 af[2], bfr[4];
#pragma unroll
      for (int i = 0; i < 2; ++i)
        af[i] = *(const short8*)&As[ks][(wave * 32 + i * 16 + fm) * 32 + sq8];
#pragma unroll
      for (int j = 0; j < 4; ++j)
        bfr[j] = *(const short8*)&Bs[ks][(j * 16 + fm) * 32 + sq8];
#pragma unroll
      for (int i = 0; i < 2; ++i)
#pragma unroll
        for (int j = 0; j < 4; ++j)
          acc[i][j] = __builtin_amdgcn_mfma_f32_16x16x32_bf16(af[i], bfr[j],
                                                              acc[i][j], 0, 0, 0);
    }
  }

#pragma unroll
  for (int i = 0; i < 2; ++i) {
    const int row0 = bm + wave * 32 + i * 16 + quad * 4;
#pragma unroll
    for (int j = 0; j < 4; ++j) {
      const int col = bn + j * 16 + fm;
#pragma unroll
      for (int r = 0; r < 4; ++r)
        C[(size_t)(row0 + r) * HIDS + col] = acc[i][j][r];
    }
  }
}

#define SP 72   // ushort stride for bf16 LDS tiles (16B-aligned rows)
#define SGS 68  // float stride for Gamma tile
#define SFS 68  // float stride for f32 staging overlay

// ---------------------------------------------------------------------------
// sdelta: z = xr @ Wgk2 + b inline (rank-16, float4 LDS reads);
// Gamma=cumsum(logsig16); Vt~=(e^-G V)^T; Sdelta = Lam.(V~^T K) exported
// via f32 LDS overlay -> coalesced 32B stores. Exports Vtg, Eb.
// ---------------------------------------------------------------------------
__global__ __launch_bounds__(256) void sdelta_kernel(
    const ushort* __restrict__ k, const ushort* __restrict__ v,
    const float* __restrict__ xr, const float* __restrict__ Wgk2,
    const float* __restrict__ bgk2, ushort* __restrict__ Sdelta,
    float* __restrict__ Lam, ushort* __restrict__ Vtg,
    ushort* __restrict__ Eb) {
  const int bid = blockIdx.x;
  const int c = bid & 31, bh = bid >> 5;
  const int b = bh >> 4, h = bh & 15;
  const int tid = threadIdx.x;
  const int lane = tid & 63, wave = tid >> 6;
  const int fm = lane & 15, quad = lane >> 4;
  const int wm2 = (wave >> 1) * 32, wn2 = (wave & 1) * 32;

  __shared__ __align__(16) ushort spool[2 * 64 * SP];  // sKt | sVt
  __shared__ __align__(16) float sG[64 * SGS];
  __shared__ __align__(16) float sW2[RANK * 64];
  ushort* sKt = spool;
  ushort* sVt = spool + 64 * SP;
  float* sF = (float*)spool;  // f32 overlay, valid after MFMA drain

  const size_t base = ((size_t)b * LSEQ + (size_t)c * CHUNK) * HIDS + (size_t)h * HDIM;
  const int r = tid >> 2, c0 = (tid & 3) * 16;
  const size_t gb = base + (size_t)r * HIDS + c0;

  // stage Wgk2 head-slice [16][64] f32
  {
    const int wr = tid >> 4, wc = (tid & 15) * 4;
    *(float4*)&sW2[wr * 64 + wc] =
        *(const float4*)(Wgk2 + (size_t)wr * HIDS + h * HDIM + wc);
  }
  // xr row for this thread's time-step (4 lanes per row share; L2-hot)
  float xrr[16];
  {
    const size_t xrow = ((size_t)b * LSEQ + (size_t)c * CHUNK + r) * RANK;
#pragma unroll
    for (int m = 0; m < 4; ++m)
      *(float4*)&xrr[m * 4] = *(const float4*)(xr + xrow + m * 4);
  }
  float bias[16];
#pragma unroll
  for (int m = 0; m < 4; ++m)
    *(float4*)&bias[m * 4] = *(const float4*)(bgk2 + h * HDIM + c0 + m * 4);
  __syncthreads();

  // z = xr . W2slice + bias (t2-outer, float4 W2 reads: 64 b128 vs 256 b32;
  // per-element accumulation order unchanged -> bit-identical)
  {
    float zacc[16];
#pragma unroll
    for (int i = 0; i < 16; ++i) zacc[i] = bias[i];
#pragma unroll
    for (int t2 = 0; t2 < 16; ++t2) {
      const float xv = xrr[t2];
      const float* wrow = &sW2[t2 * 64 + c0];
#pragma unroll
      for (int m = 0; m < 4; ++m) {
        float4 wv = *(const float4*)(wrow + m * 4);
        zacc[m * 4 + 0] = fmaf(xv, wv.x, zacc[m * 4 + 0]);
        zacc[m * 4 + 1] = fmaf(xv, wv.y, zacc[m * 4 + 1]);
        zacc[m * 4 + 2] = fmaf(xv, wv.z, zacc[m * 4 + 2]);
        zacc[m * 4 + 3] = fmaf(xv, wv.w, zacc[m * 4 + 3]);
      }
    }
#pragma unroll
    for (int i = 0; i < 16; ++i) sG[r * SGS + c0 + i] = logsig16(zacc[i]);
  }
  // pair partition (K, V) — issue loads to overlap with cumsum
  const int pr = (tid >> 3) * 2, pc = (tid & 7) * 8;
  const size_t pb = base + (size_t)pr * HIDS + pc;
  short8 ka = *(const short8*)(k + pb);
  short8 kb2 = *(const short8*)(k + pb + HIDS);
  short8 va = *(const short8*)(v + pb);
  short8 vb2 = *(const short8*)(v + pb + HIDS);
  __syncthreads();

  // inclusive cumsum along t per v column
  const int vcol = tid & 63, qtr = tid >> 6;
  {
    float run = 0.f;
#pragma unroll
    for (int i = 0; i < 16; ++i) {
      int idx = (qtr * 16 + i) * SGS + vcol;
      run += sG[idx];
      sG[idx] = run;
    }
  }
  __syncthreads();
  float pre = 0.f;
  for (int j = 0; j < qtr; ++j) pre += sG[(j * 16 + 15) * SGS + vcol];
  __syncthreads();
#pragma unroll
  for (int i = 0; i < 16; ++i) sG[(qtr * 16 + i) * SGS + vcol] += pre;
  __syncthreads();

  // E = e^Gamma -> global (coalesced 32B/thread)
  {
    ushort eb[16];
#pragma unroll
    for (int i = 0; i < 16; ++i) eb[i] = f2bf(__expf(sG[r * SGS + c0 + i]));
    *(short8*)(Eb + gb) = *(short8*)&eb[0];
    *(short8*)(Eb + gb + 8) = *(short8*)&eb[8];
  }

  // transposed tiles (ushort2 writes)
#pragma unroll
  for (int i = 0; i < 8; ++i) {
    ushort2 kk;
    kk.x = (ushort)ka[i];
    kk.y = (ushort)kb2[i];
    *(ushort2*)&sKt[(pc + i) * SP + pr] = kk;
    float Ga = sG[pr * SGS + pc + i];
    float Gb2 = sG[(pr + 1) * SGS + pc + i];
    ushort2 vv;
    vv.x = f2bf(bf2f((ushort)va[i]) * __expf(-Ga));
    vv.y = f2bf(bf2f((ushort)vb2[i]) * __expf(-Gb2));
    *(ushort2*)&sVt[(pc + i) * SP + pr] = vv;
  }
  __syncthreads();

  // export V~^T tile (coalesced 32B/thread)
  {
    const size_t vb3 = (size_t)(bh * NCHUNK + c) * (HDIM * HDIM);
    *(short8*)(Vtg + vb3 + (size_t)r * HDIM + c0) = *(const short8*)&sVt[r * SP + c0];
    *(short8*)(Vtg + vb3 + (size_t)r * HDIM + c0 + 8) =
        *(const short8*)&sVt[r * SP + c0 + 8];
  }

  if (tid < 64)
    Lam[(size_t)(bh * NCHUNK + c) * HDIM + tid] = __expf(sG[63 * SGS + tid]);

  floatx4 accD[2][2];
#pragma unroll
  for (int i = 0; i < 2; ++i)
#pragma unroll
    for (int j = 0; j < 2; ++j) accD[i][j] = (floatx4){0.f, 0.f, 0.f, 0.f};
#pragma unroll
  for (int ks = 0; ks < 2; ++ks) {
    short8 av[2], bk[2];
#pragma unroll
    for (int i = 0; i < 2; ++i)
      av[i] = *(const short8*)&sVt[(wm2 + i * 16 + fm) * SP + ks * 32 + quad * 8];
#pragma unroll
    for (int j = 0; j < 2; ++j)
      bk[j] = *(const short8*)&sKt[(wn2 + j * 16 + fm) * SP + ks * 32 + quad * 8];
#pragma unroll
    for (int i = 0; i < 2; ++i)
#pragma unroll
      for (int j = 0; j < 2; ++j)
        accD[i][j] = __builtin_amdgcn_mfma_f32_16x16x32_bf16(av[i], bk[j],
                                                             accD[i][j], 0, 0, 0);
  }
  // f32 scatter into overlay (sKt/sVt dead), then coalesced Sdelta export.
  __syncthreads();
#pragma unroll
  for (int i = 0; i < 2; ++i) {
    const int m0 = wm2 + i * 16 + quad * 4;
    float lam[4];
#pragma unroll
    for (int rr = 0; rr < 4; ++rr) lam[rr] = __expf(sG[63 * SGS + m0 + rr]);
#pragma unroll
    for (int j = 0; j < 2; ++j) {
      const int n = wn2 + j * 16 + fm;
#pragma unroll
      for (int rr = 0; rr < 4; ++rr)
        sF[(m0 + rr) * SFS + n] = accD[i][j][rr] * lam[rr];
    }
  }
  __syncthreads();
  {
    const size_t sbase = (size_t)(bh * NCHUNK + c) * (HDIM * HDIM);
    ushort ob[16];
#pragma unroll
    for (int m = 0; m < 4; ++m) {
      float4 f = *(const float4*)&sF[r * SFS + c0 + m * 4];
      ob[m * 4 + 0] = f2bf(f.x);
      ob[m * 4 + 1] = f2bf(f.y);
      ob[m * 4 + 2] = f2bf(f.z);
      ob[m * 4 + 3] = f2bf(f.w);
    }
    *(short8*)(Sdelta + sbase + (size_t)r * HDIM + c0) = *(short8*)&ob[0];
    *(short8*)(Sdelta + sbase + (size_t)r * HDIM + c0 + 8) = *(short8*)&ob[8];
  }
}

// ---------------------------------------------------------------------------
// state_scan: 512 blocks (2/CU), 1 state element per thread, prefetch 4 ahead.
// ---------------------------------------------------------------------------
__global__ __launch_bounds__(256) void state_scan_kernel(
    const ushort* __restrict__ Sdelta, const float* __restrict__ Lam,
    ushort* __restrict__ Sprev) {
  const int bh = blockIdx.x >> 4;   // 32 (b,h) pairs
  const int sl = blockIdx.x & 15;   // 16 slices of 256 elements
  const int e0 = sl * 256 + threadIdx.x;
  float S = 0.f;

  float pd[4], pl[4];
#pragma unroll
  for (int s = 0; s < 4; ++s) {
    size_t nb = (size_t)(bh * NCHUNK + s) * (HDIM * HDIM);
    pd[s] = bf2f(Sdelta[nb + e0]);
    pl[s] = Lam[(size_t)(bh * NCHUNK + s) * HDIM + (e0 >> 6)];
  }

  for (int c = 0; c < NCHUNK; ++c) {
    const int s = c & 3;
    float cd = pd[s], cl = pl[s];
    if (c + 4 < NCHUNK) {
      size_t nb = (size_t)(bh * NCHUNK + c + 4) * (HDIM * HDIM);
      pd[s] = bf2f(Sdelta[nb + e0]);
      pl[s] = Lam[(size_t)(bh * NCHUNK + c + 4) * HDIM + (e0 >> 6)];
    }
    Sprev[(size_t)(bh * NCHUNK + c) * (HDIM * HDIM) + e0] = f2bf(S);
    S = fmaf(S, cl, cd);
  }
}

// ---------------------------------------------------------------------------
// chunk_fused: att(bf16) = E . ( tril(QK^T) @ V~ + Q @ Sprev^T )
// epilogue via f32 LDS overlay -> coalesced Eb reads + att stores.
// ---------------------------------------------------------------------------
__global__ __launch_bounds__(256) void chunk_fused_kernel(
    const ushort* __restrict__ q, const ushort* __restrict__ k,
    const ushort* __restrict__ Vtg, const ushort* __restrict__ Eb,
    const ushort* __restrict__ Sprev, ushort* __restrict__ att) {
  const int bid = blockIdx.x;
  const int c = bid & 31, bh = bid >> 5;
  const int b = bh >> 4, h = bh & 15;
  const int tid = threadIdx.x;
  const int lane = tid & 63, wave = tid >> 6;
  const int fm = lane & 15, quad = lane >> 4;
  const int wm2 = (wave >> 1) * 32, wn2 = (wave & 1) * 32;

  __shared__ __align__(16) ushort cpool[4 * 64 * SP];  // sQ|sK|sVt|sA
  ushort* sQ = cpool;
  ushort* sK = cpool + 64 * SP;   // reused as sSp after scores
  ushort* sVt = cpool + 2 * 64 * SP;
  ushort* sA = cpool + 3 * 64 * SP;
  ushort* sSp = sK;
  float* sF = (float*)cpool;      // f32 overlay on sQ|sK after MFMA drain

  const size_t base = ((size_t)b * LSEQ + (size_t)c * CHUNK) * HIDS + (size_t)h * HDIM;
  const size_t sbase = (size_t)(bh * NCHUNK + c) * (HDIM * HDIM);
  const int r = tid >> 2, c0 = (tid & 3) * 16;
  const size_t gb = base + (size_t)r * HIDS + c0;
  short8 sp0 = *(const short8*)(Sprev + sbase + (size_t)r * HDIM + c0);
  short8 sp1 = *(const short8*)(Sprev + sbase + (size_t)r * HDIM + c0 + 8);
  *(short8*)&sQ[r * SP + c0] = *(const short8*)(q + gb);
  *(short8*)&sQ[r * SP + c0 + 8] = *(const short8*)(q + gb + 8);
  *(short8*)&sK[r * SP + c0] = *(const short8*)(k + gb);
  *(short8*)&sK[r * SP + c0 + 8] = *(const short8*)(k + gb + 8);
  *(short8*)&sVt[r * SP + c0] = *(const short8*)(Vtg + sbase + (size_t)r * HDIM + c0);
  *(short8*)&sVt[r * SP + c0 + 8] =
      *(const short8*)(Vtg + sbase + (size_t)r * HDIM + c0 + 8);
  __syncthreads();

  // scores = tril(Q K^T)
  floatx4 accS[2][2];
#pragma unroll
  for (int i = 0; i < 2; ++i)
#pragma unroll
    for (int j = 0; j < 2; ++j) accS[i][j] = (floatx4){0.f, 0.f, 0.f, 0.f};
#pragma unroll
  for (int ks = 0; ks < 2; ++ks) {
    short8 a[2], bb[2];
#pragma unroll
    for (int i = 0; i < 2; ++i)
      a[i] = *(const short8*)&sQ[(wm2 + i * 16 + fm) * SP + ks * 32 + quad * 8];
#pragma unroll
    for (int j = 0; j < 2; ++j)
      bb[j] = *(const short8*)&sK[(wn2 + j * 16 + fm) * SP + ks * 32 + quad * 8];
#pragma unroll
    for (int i = 0; i < 2; ++i)
#pragma unroll
      for (int j = 0; j < 2; ++j)
        accS[i][j] = __builtin_amdgcn_mfma_f32_16x16x32_bf16(a[i], bb[j],
                                                             accS[i][j], 0, 0, 0);
  }
  __syncthreads();  // all waves done reading sK

  // write sA (tril) and sSp (into sK space)
#pragma unroll
  for (int i = 0; i < 2; ++i)
#pragma unroll
    for (int j = 0; j < 2; ++j) {
      const int t0 = wm2 + i * 16 + quad * 4;
      const int s = wn2 + j * 16 + fm;
#pragma unroll
      for (int rr = 0; rr < 4; ++rr) {
        float val = (s <= t0 + rr) ? accS[i][j][rr] : 0.f;
        sA[(t0 + rr) * SP + s] = f2bf(val);
      }
    }
  *(short8*)&sSp[r * SP + c0] = sp0;
  *(short8*)&sSp[r * SP + c0 + 8] = sp1;
  __syncthreads();

  // att = E . (sA @ V~  +  Q @ Sprev^T)
  floatx4 acc[2][2];
#pragma unroll
  for (int i = 0; i < 2; ++i)
#pragma unroll
    for (int j = 0; j < 2; ++j) acc[i][j] = (floatx4){0.f, 0.f, 0.f, 0.f};
#pragma unroll
  for (int ks = 0; ks < 2; ++ks) {
    short8 aa[2], aq[2], bv[2], bs[2];
#pragma unroll
    for (int i = 0; i < 2; ++i) {
      aa[i] = *(const short8*)&sA[(wm2 + i * 16 + fm) * SP + ks * 32 + quad * 8];
      aq[i] = *(const short8*)&sQ[(wm2 + i * 16 + fm) * SP + ks * 32 + quad * 8];
    }
#pragma unroll
    for (int j = 0; j < 2; ++j) {
      bv[j] = *(const short8*)&sVt[(wn2 + j * 16 + fm) * SP + ks * 32 + quad * 8];
      bs[j] = *(const short8*)&sSp[(wn2 + j * 16 + fm) * SP + ks * 32 + quad * 8];
    }
#pragma unroll
    for (int i = 0; i < 2; ++i)
#pragma unroll
      for (int j = 0; j < 2; ++j) {
        acc[i][j] = __builtin_amdgcn_mfma_f32_16x16x32_bf16(aa[i], bv[j],
                                                            acc[i][j], 0, 0, 0);
        acc[i][j] = __builtin_amdgcn_mfma_f32_16x16x32_bf16(aq[i], bs[j],
                                                            acc[i][j], 0, 0, 0);
      }
  }
  // f32 scatter into overlay (sQ/sK dead), then coalesced E-multiply + store.
  __syncthreads();
#pragma unroll
  for (int i = 0; i < 2; ++i)
#pragma unroll
    for (int j = 0; j < 2; ++j) {
      const int m0 = wm2 + i * 16 + quad * 4;
      const int n = wn2 + j * 16 + fm;
#pragma unroll
      for (int rr = 0; rr < 4; ++rr) sF[(m0 + rr) * SFS + n] = acc[i][j][rr];
    }
  __syncthreads();
  {
    short8 e0 = *(const short8*)(Eb + gb);
    short8 e1 = *(const short8*)(Eb + gb + 8);
    ushort ob[16];
#pragma unroll
    for (int m = 0; m < 4; ++m) {
      float4 f = *(const float4*)&sF[r * SFS + c0 + m * 4];
      const int i0 = m * 4;
      ob[i0 + 0] = f2bf(f.x * bf2f((ushort)(i0 + 0 < 8 ? e0[i0 + 0] : e1[i0 - 8])));
      ob[i0 + 1] = f2bf(f.y * bf2f((ushort)(i0 + 1 < 8 ? e0[i0 + 1] : e1[i0 - 7])));
      ob[i0 + 2] = f2bf(f.z * bf2f((ushort)(i0 + 2 < 8 ? e0[i0 + 2] : e1[i0 - 6])));
      ob[i0 + 3] = f2bf(f.w * bf2f((ushort)(i0 + 3 < 8 ? e0[i0 + 3] : e1[i0 - 5])));
    }
    *(short8*)(att + gb) = *(short8*)&ob[0];
    *(short8*)(att + gb + 8) = *(short8*)&ob[8];
  }
}

// ---------------------------------------------------------------------------
// y = (LayerNorm(att) * gamma + beta) * silu(g), bf16 in/out.
// ---------------------------------------------------------------------------
__global__ __launch_bounds__(256) void ln_gate_kernel(const ushort* __restrict__ att,
                                                      const ushort* __restrict__ g,
                                                      const float* __restrict__ gamma,
                                                      const float* __restrict__ beta,
                                                      ushort* __restrict__ ybf) {
  const int row = blockIdx.x;
  const int tid = threadIdx.x;
  ushort4 au = *(const ushort4*)(att + (size_t)row * HIDS + tid * 4);
  float ax = bf2f(au.x), ay = bf2f(au.y), az = bf2f(au.z), aw = bf2f(au.w);
  float s = ax + ay + az + aw;
  float ss = ax * ax + ay * ay + az * az + aw * aw;
#pragma unroll
  for (int off = 32; off; off >>= 1) {
    s += __shfl_down(s, off);
    ss += __shfl_down(ss, off);
  }
  __shared__ float rs[4], rss[4];
  const int wid = tid >> 6;
  if ((tid & 63) == 0) { rs[wid] = s; rss[wid] = ss; }
  __syncthreads();
  const float mean = (rs[0] + rs[1] + rs[2] + rs[3]) * (1.f / HIDS);
  const float ex2 = (rss[0] + rss[1] + rss[2] + rss[3]) * (1.f / HIDS);
  const float rstd = rsqrtf(ex2 - mean * mean + 1e-5f);

  float4 ga = *(const float4*)(gamma + tid * 4);
  float4 be = *(const float4*)(beta + tid * 4);
  ushort4 gu = *(const ushort4*)(g + (size_t)row * HIDS + tid * 4);
  float gx = bf2f(gu.x), gy = bf2f(gu.y), gz = bf2f(gu.z), gw = bf2f(gu.w);
  float4 o;
  o.x = ((ax - mean) * rstd * ga.x + be.x) * (gx / (1.f + __expf(-gx)));
  o.y = ((ay - mean) * rstd * ga.y + be.y) * (gy / (1.f + __expf(-gy)));
  o.z = ((az - mean) * rstd * ga.z + be.z) * (gz / (1.f + __expf(-gz)));
  o.w = ((aw - mean) * rstd * ga.w + be.w) * (gw / (1.f + __expf(-gw)));
  ushort4 ob;
  ob.x = f2bf(o.x); ob.y = f2bf(o.y); ob.z = f2bf(o.z); ob.w = f2bf(o.w);
  *(ushort4*)(ybf + (size_t)row * HIDS + tid * 4) = ob;
}

// ---------------------------------------------------------------------------
extern "C" void kernel_launch(void* const* d_in, const int* in_sizes, int n_in,
                              void* d_out, int out_size, void* d_ws, size_t ws_size,
                              hipStream_t stream) {
  const float* x     = (const float*)d_in[0];
  const float* Wq    = (const float*)d_in[1];
  const float* Wk    = (const float*)d_in[2];
  const float* Wv    = (const float*)d_in[3];
  const float* Wg    = (const float*)d_in[4];
  const float* Wgk1  = (const float*)d_in[5];
  const float* Wgk2  = (const float*)d_in[6];
  const float* bgk2  = (const float*)d_in[7];
  const float* gamma = (const float*)d_in[8];
  const float* beta  = (const float*)d_in[9];
  const float* Wout  = (const float*)d_in[10];
  float* out = (float*)d_out;

  const size_t SZ = (size_t)NROW * HIDS;  // 4M elements
  float* ws = (float*)d_ws;
  float* Lamb = ws;                         // 64K floats
  ushort* attb   = (ushort*)(ws + 65536);   // bf16 4M
  ushort* Sdelta = attb + SZ;
  ushort* Sprevb = Sdelta + SZ;
  ushort* Vtgb   = Sprevb + SZ;             // V~^T tiles (bf16)
  ushort* Ebb    = Vtgb + SZ;               // e^Gamma (bf16)
  ushort* qbf = Ebb + SZ;                   // qb|kb|vb|gb contiguous
  ushort* kbf = qbf + SZ;
  ushort* vbf = kbf + SZ;
  ushort* gbf = vbf + SZ;
  ushort* xbf = gbf + SZ;
  ushort* Wtq = xbf + SZ;                   // Wtq|Wtk|Wtv|Wtg contiguous
  ushort* Wtk = Wtq + HIDS * HIDS;
  ushort* Wtv = Wtk + HIDS * HIDS;
  ushort* Wtg = Wtv + HIDS * HIDS;
  ushort* Wto = Wtg + HIDS * HIDS;
  float* xrb = (float*)(Wto + HIDS * HIDS);  // [4096][16] f32
  ushort* ybf = vbf;  // vbf dead after sdelta

  prep_kernel<<<4096 + 1280, 256, 0, stream>>>(
      x, xbf, Wq, Wk, Wv, Wg, Wout, Wtq, Wtk, Wtv, Wtg, Wto);

  xr_kernel<<<NROW / 16, 256, 0, stream>>>(xbf, Wgk1, xrb);

  // single 4096x4096x1024 GEMM over concatenated weights / outputs
  proj8_kernel<<<dim3(NROW / 256, NROW / 256), 512, 0, stream>>>(xbf, Wtq, qbf);

  sdelta_kernel<<<BBATCH * NHEAD * NCHUNK, 256, 0, stream>>>(
      kbf, vbf, xrb, Wgk2, bgk2, Sdelta, Lamb, Vtgb, Ebb);
  state_scan_kernel<<<512, 256, 0, stream>>>(Sdelta, Lamb, Sprevb);
  chunk_fused_kernel<<<BBATCH * NHEAD * NCHUNK, 256, 0, stream>>>(
      qbf, kbf, Vtgb, Ebb, Sprevb, attb);

  ln_gate_kernel<<<NROW, 256, 0, stream>>>(attb, gbf, gamma, beta, ybf);
  gemm_out_kernel<<<dim3(HIDS / 64, NROW / 128), 256, 0, stream>>>(ybf, Wto, out);
}